// Round 3
// baseline (743.243 us; speedup 1.0000x reference)
//
#include <hip/hip_runtime.h>
#include <cstdint>
#include <cstddef>

// ---------------------------------------------------------------------------
// GCN: 3 layers.  out = A_hat @ (h @ W) + b, A_hat = D^-1/2 (A+I) D^-1/2
// R2: 128x128-tile fp32 GEMM (8x8 microtile, reg load-ahead); CSR pull agg.
// ---------------------------------------------------------------------------

static inline int cdiv_i(long a, long b) { return (int)((a + b - 1) / b); }

__global__ void detect_fmt_kernel(const unsigned int* __restrict__ raw, int n_nodes,
                                  int* __restrict__ flag) {
    if (blockIdx.x == 0 && threadIdx.x == 0) {
        int is64 = 1;
        for (int i = 0; i < 64; ++i) {
            unsigned lo = raw[2 * i], hi = raw[2 * i + 1];
            if (hi != 0u || lo >= (unsigned)n_nodes) { is64 = 0; break; }
        }
        *flag = is64;
    }
}

__global__ void edges_to_i32_kernel(const void* __restrict__ raw, int* __restrict__ out,
                                    int twoE, const int* __restrict__ flag) {
    const int f = *flag;
    for (long i = blockIdx.x * (long)blockDim.x + threadIdx.x; i < twoE;
         i += (long)gridDim.x * blockDim.x) {
        out[i] = f ? (int)(((const long long*)raw)[i]) : ((const int*)raw)[i];
    }
}

__global__ void zero_i32_kernel(int* __restrict__ p, int n) {
    for (long i = blockIdx.x * (long)blockDim.x + threadIdx.x; i < n;
         i += (long)gridDim.x * blockDim.x)
        p[i] = 0;
}

__global__ void hist_kernel(const int* __restrict__ dst, int* __restrict__ cnt, int E) {
    for (long i = blockIdx.x * (long)blockDim.x + threadIdx.x; i < E;
         i += (long)gridDim.x * blockDim.x)
        atomicAdd(&cnt[dst[i]], 1);
}

__global__ void dinv_kernel(const int* __restrict__ cnt, float* __restrict__ dinv, int n) {
    for (long i = blockIdx.x * (long)blockDim.x + threadIdx.x; i < n;
         i += (long)gridDim.x * blockDim.x)
        dinv[i] = rsqrtf((float)cnt[i] + 1.0f);  // +1 self-loop
}

// ---- exclusive scan over n ints: 1024 elems / block ----
__global__ __launch_bounds__(256) void scan1_kernel(const int* __restrict__ in,
                                                    int* __restrict__ out,
                                                    int* __restrict__ bsum, int n) {
    __shared__ int tsum[256];
    const int tid = threadIdx.x;
    const long base = (long)blockIdx.x * 1024 + (long)tid * 4;
    int v[4];
#pragma unroll
    for (int i = 0; i < 4; ++i) v[i] = (base + i < n) ? in[base + i] : 0;
    const int s = v[0] + v[1] + v[2] + v[3];
    tsum[tid] = s;
    __syncthreads();
    for (int off = 1; off < 256; off <<= 1) {
        int add = (tid >= off) ? tsum[tid - off] : 0;
        __syncthreads();
        tsum[tid] += add;
        __syncthreads();
    }
    int run = tsum[tid] - s;
#pragma unroll
    for (int i = 0; i < 4; ++i) {
        if (base + i < n) out[base + i] = run;
        run += v[i];
    }
    if (tid == 255) bsum[blockIdx.x] = tsum[255];
}

__global__ void scan2_kernel(int* __restrict__ bsum, int nb) {
    __shared__ int lds[256];
    const int tid = threadIdx.x;
    int v = (tid < nb) ? bsum[tid] : 0;
    lds[tid] = v;
    __syncthreads();
    for (int off = 1; off < 256; off <<= 1) {
        int add = (tid >= off) ? lds[tid - off] : 0;
        __syncthreads();
        lds[tid] += add;
        __syncthreads();
    }
    if (tid < nb) bsum[tid] = lds[tid] - v;
}

__global__ __launch_bounds__(256) void scan3_kernel(int* __restrict__ out,
                                                    const int* __restrict__ bsum, int n) {
    const long base = (long)blockIdx.x * 1024 + (long)threadIdx.x * 4;
    const int add = bsum[blockIdx.x];
#pragma unroll
    for (int i = 0; i < 4; ++i)
        if (base + i < n) out[base + i] += add;
}

__global__ void set_int_kernel(int* __restrict__ p, int idx, int val) {
    if (blockIdx.x == 0 && threadIdx.x == 0) p[idx] = val;
}

__global__ void scatter_kernel(const int* __restrict__ src, const int* __restrict__ dst,
                               const int* __restrict__ row_ptr, int* __restrict__ fill,
                               int* __restrict__ col, int E) {
    for (long i = blockIdx.x * (long)blockDim.x + threadIdx.x; i < E;
         i += (long)gridDim.x * blockDim.x) {
        int d = dst[i];
        int p = row_ptr[d] + atomicAdd(&fill[d], 1);
        col[p] = src[i];
    }
}

// ---------------------------------------------------------------------------
// C[M,Nn] = A[M,K] @ B[K,Nn].  BM=128, BN in {128,64}, BK=16, 256 threads,
// 8x(4*BN/64) microtile.  K%16==0, Nn%BN==0; M tail guarded.
// ---------------------------------------------------------------------------
template <int BN>
__global__ __launch_bounds__(256) void gemm128_kernel(const float* __restrict__ A,
                                                      const float* __restrict__ B,
                                                      float* __restrict__ C,
                                                      int M, int K, int Nn) {
    __shared__ float As[16][132];       // [k][m] transposed
    __shared__ float Bs[16][BN + 4];    // [k][n]
    constexpr int NC = BN / 64;         // 2 or 1 column groups of float4
    const int tid = threadIdx.x;
    const int bm = blockIdx.y * 128;
    const int bn = blockIdx.x * BN;
    const int tr = tid >> 4, tc = tid & 15;

    // A loader: row alm (0..127), k cols alk..alk+7
    const int alm = tid >> 1;
    const int alk = (tid & 1) * 8;
    const int agm = bm + alm;
    const float* Arow = A + (size_t)agm * K + alk;

    // B loader
    const int blk = (BN == 128) ? (tid >> 5) : (tid >> 4);
    const int bln = (BN == 128) ? ((tid & 31) * 4) : ((tid & 15) * 4);
    const float* Bp = B + (size_t)blk * Nn + bn + bln;

    float acc[8][4 * NC];
#pragma unroll
    for (int i = 0; i < 8; ++i)
#pragma unroll
        for (int j = 0; j < 4 * NC; ++j) acc[i][j] = 0.f;

    float4 a0 = make_float4(0.f, 0.f, 0.f, 0.f), a1 = a0, b0 = a0, b1 = a0;
    if (agm < M) {
        a0 = *(const float4*)(Arow + 0);
        a1 = *(const float4*)(Arow + 4);
    }
    b0 = *(const float4*)(Bp);
    if (BN == 128) b1 = *(const float4*)(Bp + (size_t)8 * Nn);

    for (int kk = 0; kk < K; kk += 16) {
        __syncthreads();
        As[alk + 0][alm] = a0.x; As[alk + 1][alm] = a0.y;
        As[alk + 2][alm] = a0.z; As[alk + 3][alm] = a0.w;
        As[alk + 4][alm] = a1.x; As[alk + 5][alm] = a1.y;
        As[alk + 6][alm] = a1.z; As[alk + 7][alm] = a1.w;
        *(float4*)&Bs[blk][bln] = b0;
        if (BN == 128) *(float4*)&Bs[blk + 8][bln] = b1;
        __syncthreads();

        const int kn = kk + 16;
        if (kn < K) {  // load-ahead: in flight during compute below
            if (agm < M) {
                a0 = *(const float4*)(Arow + kn);
                a1 = *(const float4*)(Arow + kn + 4);
            }
            b0 = *(const float4*)(Bp + (size_t)kn * Nn);
            if (BN == 128) b1 = *(const float4*)(Bp + (size_t)(kn + 8) * Nn);
        }

#pragma unroll
        for (int k = 0; k < 16; ++k) {
            float ar[8], br[4 * NC];
            *(float4*)&ar[0] = *(const float4*)&As[k][tr * 4];
            *(float4*)&ar[4] = *(const float4*)&As[k][64 + tr * 4];
            *(float4*)&br[0] = *(const float4*)&Bs[k][tc * 4];
            if (BN == 128) *(float4*)&br[4] = *(const float4*)&Bs[k][64 + tc * 4];
#pragma unroll
            for (int i = 0; i < 8; ++i)
#pragma unroll
                for (int j = 0; j < 4 * NC; ++j)
                    acc[i][j] = fmaf(ar[i], br[j], acc[i][j]);
        }
    }

#pragma unroll
    for (int i = 0; i < 8; ++i) {
        const int row = bm + (i >> 2) * 64 + tr * 4 + (i & 3);
        if (row < M) {
            float* Cp = C + (size_t)row * Nn + bn;
            *(float4*)(Cp + tc * 4) =
                make_float4(acc[i][0], acc[i][1], acc[i][2], acc[i][3]);
            if (BN == 128)
                *(float4*)(Cp + 64 + tc * 4) =
                    make_float4(acc[i][4], acc[i][5], acc[i][6], acc[i][7]);
        }
    }
}

__device__ __forceinline__ float elu1(float v) { return v > 0.f ? v : expm1f(v); }

// Pull aggregation, one wave per node. VEC floats per lane (64*VEC = Hdim).
// MODE 0: y=elu(conv)  MODE 1: y=elu(conv+res)  MODE 2: y=conv
template <int VEC, int MODE>
__global__ __launch_bounds__(256) void agg_pull_kernel(
    const int* __restrict__ row_ptr, const int* __restrict__ col,
    const float* __restrict__ dinv, const float* __restrict__ t,
    const float* __restrict__ bias, const float* __restrict__ res,
    float* __restrict__ y, int Nn, int Hdim) {
    const int node = blockIdx.x * (blockDim.x >> 6) + (threadIdx.x >> 6);
    if (node >= Nn) return;
    const int lane = threadIdx.x & 63;
    const int f = lane * VEC;

    float acc[VEC];
#pragma unroll
    for (int i = 0; i < VEC; ++i) acc[i] = 0.f;

    const int s0 = row_ptr[node], s1 = row_ptr[node + 1];
    for (int e = s0; e < s1; ++e) {
        const int s = col[e];
        const float w = dinv[s];
        const float* ts = t + (size_t)s * Hdim + f;
        if (VEC == 4) {
            float4 v = *(const float4*)ts;
            acc[0] = fmaf(v.x, w, acc[0]);
            acc[1] = fmaf(v.y, w, acc[1]);
            acc[2] = fmaf(v.z, w, acc[2]);
            acc[3] = fmaf(v.w, w, acc[3]);
        } else {
            acc[0] = fmaf(*ts, w, acc[0]);
        }
    }

    const float dn = dinv[node];
    const float* tn = t + (size_t)node * Hdim + f;
    float o[VEC];
#pragma unroll
    for (int i = 0; i < VEC; ++i)
        o[i] = (acc[i] + tn[i] * dn) * dn + bias[f + i];

    if (MODE == 1) {
        const float* rn = res + (size_t)node * Hdim + f;
#pragma unroll
        for (int i = 0; i < VEC; ++i) o[i] += rn[i];
    }
    if (MODE <= 1) {
#pragma unroll
        for (int i = 0; i < VEC; ++i) o[i] = elu1(o[i]);
    }

    float* yn = y + (size_t)node * Hdim + f;
    if (VEC == 4) {
        *(float4*)yn = make_float4(o[0], o[1], o[2], o[3]);
    } else {
        *yn = o[0];
    }
}

extern "C" void kernel_launch(void* const* d_in, const int* in_sizes, int n_in,
                              void* d_out, int out_size, void* d_ws, size_t ws_size,
                              hipStream_t stream) {
    const float* x = (const float*)d_in[0];
    const void* ei_raw = d_in[1];
    const float* W1 = (const float*)d_in[2];
    const float* b1 = (const float*)d_in[3];
    const float* W2 = (const float*)d_in[4];
    const float* b2 = (const float*)d_in[5];
    const float* W3 = (const float*)d_in[6];
    const float* b3 = (const float*)d_in[7];
    float* out = (float*)d_out;

    const int H = in_sizes[3];       // 256
    const int F = in_sizes[2] / H;   // 512
    const int N = in_sizes[0] / F;   // 50000
    const int C = in_sizes[7];       // 64
    const int E = in_sizes[1] / 2;   // 800000

    // workspace layout
    char* ws = (char*)d_ws;
    size_t off = 0;
    auto take = [&](size_t bytes) -> char* {
        char* p = ws + off;
        off += (bytes + 255) & ~(size_t)255;
        return p;
    };
    float* dinv = (float*)take((size_t)N * 4);
    int* flag = (int*)take(4);
    float* t = (float*)take((size_t)N * H * 4);
    float* h1 = (float*)take((size_t)N * H * 4);
    float* h2 = (float*)take((size_t)N * H * 4);
    int* e32 = (int*)take((size_t)2 * E * 4);
    int* srcI = e32;
    int* dstI = e32 + E;
    int* col = (int*)take((size_t)E * 4);
    int* cnt = (int*)take((size_t)N * 4);
    int* row_ptr = (int*)take((size_t)(N + 1) * 4);
    int* fill = (int*)take((size_t)N * 4);
    int* bsum = (int*)take(256 * 4);
    (void)ws_size; (void)n_in; (void)out_size;

    const int nScanBlk = cdiv_i(N, 1024);

    // ---- edges + degrees + CSR ----
    detect_fmt_kernel<<<1, 64, 0, stream>>>((const unsigned*)ei_raw, N, flag);
    edges_to_i32_kernel<<<cdiv_i(2L * E, 256), 256, 0, stream>>>(ei_raw, e32, 2 * E, flag);
    zero_i32_kernel<<<cdiv_i(N, 256), 256, 0, stream>>>(cnt, N);
    hist_kernel<<<cdiv_i(E, 256), 256, 0, stream>>>(dstI, cnt, E);
    dinv_kernel<<<cdiv_i(N, 256), 256, 0, stream>>>(cnt, dinv, N);
    scan1_kernel<<<nScanBlk, 256, 0, stream>>>(cnt, row_ptr, bsum, N);
    scan2_kernel<<<1, 256, 0, stream>>>(bsum, nScanBlk);
    scan3_kernel<<<nScanBlk, 256, 0, stream>>>(row_ptr, bsum, N);
    set_int_kernel<<<1, 1, 0, stream>>>(row_ptr, N, E);
    zero_i32_kernel<<<cdiv_i(N, 256), 256, 0, stream>>>(fill, N);
    scatter_kernel<<<cdiv_i(E, 256), 256, 0, stream>>>(srcI, dstI, row_ptr, fill, col, E);

    const int aggGridH = cdiv_i(N, 4);
    const int mt = cdiv_i(N, 128);

    // ---- layer 1: h1 = elu(A_hat @ (x @ W1) + b1)
    gemm128_kernel<128><<<dim3(H / 128, mt), 256, 0, stream>>>(x, W1, t, N, F, H);
    agg_pull_kernel<4, 0><<<aggGridH, 256, 0, stream>>>(row_ptr, col, dinv, t, b1,
                                                        nullptr, h1, N, H);

    // ---- layer 2: h2 = elu(A_hat @ (h1 @ W2) + b2 + h1)
    gemm128_kernel<128><<<dim3(H / 128, mt), 256, 0, stream>>>(h1, W2, t, N, H, H);
    agg_pull_kernel<4, 1><<<aggGridH, 256, 0, stream>>>(row_ptr, col, dinv, t, b2,
                                                        h1, h2, N, H);

    // ---- layer 3: out = A_hat @ (h2 @ W3) + b3
    gemm128_kernel<64><<<dim3(C / 64, mt), 256, 0, stream>>>(h2, W3, t, N, H, C);
    agg_pull_kernel<1, 2><<<aggGridH, 256, 0, stream>>>(row_ptr, col, dinv, t, b3,
                                                        nullptr, out, N, C);
}

// Round 4
// 672.695 us; speedup vs baseline: 1.1049x; 1.1049x over previous
//
#include <hip/hip_runtime.h>
#include <cstdint>
#include <cstddef>

// ---------------------------------------------------------------------------
// GCN: 3 layers.  out = A_hat @ (h @ W) + b, A_hat = D^-1/2 (A+I) D^-1/2
// R3: MFMA fp16 split-precision GEMM (fp32-grade accuracy), CSR pull agg
//     with 4-way unrolled gathers.
// ---------------------------------------------------------------------------

static inline int cdiv_i(long a, long b) { return (int)((a + b - 1) / b); }

using half4 = __attribute__((ext_vector_type(4))) _Float16;
using half8 = __attribute__((ext_vector_type(8))) _Float16;
using f32x4 = __attribute__((ext_vector_type(4))) float;

__global__ void detect_fmt_kernel(const unsigned int* __restrict__ raw, int n_nodes,
                                  int* __restrict__ flag) {
    if (blockIdx.x == 0 && threadIdx.x == 0) {
        int is64 = 1;
        for (int i = 0; i < 64; ++i) {
            unsigned lo = raw[2 * i], hi = raw[2 * i + 1];
            if (hi != 0u || lo >= (unsigned)n_nodes) { is64 = 0; break; }
        }
        *flag = is64;
    }
}

__global__ void edges_to_i32_kernel(const void* __restrict__ raw, int* __restrict__ out,
                                    int twoE, const int* __restrict__ flag) {
    const int f = *flag;
    for (long i = blockIdx.x * (long)blockDim.x + threadIdx.x; i < twoE;
         i += (long)gridDim.x * blockDim.x) {
        out[i] = f ? (int)(((const long long*)raw)[i]) : ((const int*)raw)[i];
    }
}

__global__ void zero_i32_kernel(int* __restrict__ p, int n) {
    for (long i = blockIdx.x * (long)blockDim.x + threadIdx.x; i < n;
         i += (long)gridDim.x * blockDim.x)
        p[i] = 0;
}

__global__ void hist_kernel(const int* __restrict__ dst, int* __restrict__ cnt, int E) {
    for (long i = blockIdx.x * (long)blockDim.x + threadIdx.x; i < E;
         i += (long)gridDim.x * blockDim.x)
        atomicAdd(&cnt[dst[i]], 1);
}

__global__ void dinv_kernel(const int* __restrict__ cnt, float* __restrict__ dinv, int n) {
    for (long i = blockIdx.x * (long)blockDim.x + threadIdx.x; i < n;
         i += (long)gridDim.x * blockDim.x)
        dinv[i] = rsqrtf((float)cnt[i] + 1.0f);  // +1 self-loop
}

// ---- exclusive scan over n ints: 1024 elems / block ----
__global__ __launch_bounds__(256) void scan1_kernel(const int* __restrict__ in,
                                                    int* __restrict__ out,
                                                    int* __restrict__ bsum, int n) {
    __shared__ int tsum[256];
    const int tid = threadIdx.x;
    const long base = (long)blockIdx.x * 1024 + (long)tid * 4;
    int v[4];
#pragma unroll
    for (int i = 0; i < 4; ++i) v[i] = (base + i < n) ? in[base + i] : 0;
    const int s = v[0] + v[1] + v[2] + v[3];
    tsum[tid] = s;
    __syncthreads();
    for (int off = 1; off < 256; off <<= 1) {
        int add = (tid >= off) ? tsum[tid - off] : 0;
        __syncthreads();
        tsum[tid] += add;
        __syncthreads();
    }
    int run = tsum[tid] - s;
#pragma unroll
    for (int i = 0; i < 4; ++i) {
        if (base + i < n) out[base + i] = run;
        run += v[i];
    }
    if (tid == 255) bsum[blockIdx.x] = tsum[255];
}

__global__ void scan2_kernel(int* __restrict__ bsum, int nb) {
    __shared__ int lds[256];
    const int tid = threadIdx.x;
    int v = (tid < nb) ? bsum[tid] : 0;
    lds[tid] = v;
    __syncthreads();
    for (int off = 1; off < 256; off <<= 1) {
        int add = (tid >= off) ? lds[tid - off] : 0;
        __syncthreads();
        lds[tid] += add;
        __syncthreads();
    }
    if (tid < nb) bsum[tid] = lds[tid] - v;
}

__global__ __launch_bounds__(256) void scan3_kernel(int* __restrict__ out,
                                                    const int* __restrict__ bsum, int n) {
    const long base = (long)blockIdx.x * 1024 + (long)threadIdx.x * 4;
    const int add = bsum[blockIdx.x];
#pragma unroll
    for (int i = 0; i < 4; ++i)
        if (base + i < n) out[base + i] += add;
}

__global__ void set_int_kernel(int* __restrict__ p, int idx, int val) {
    if (blockIdx.x == 0 && threadIdx.x == 0) p[idx] = val;
}

__global__ void scatter_kernel(const int* __restrict__ src, const int* __restrict__ dst,
                               const int* __restrict__ row_ptr, int* __restrict__ fill,
                               int* __restrict__ col, int E) {
    for (long i = blockIdx.x * (long)blockDim.x + threadIdx.x; i < E;
         i += (long)gridDim.x * blockDim.x) {
        int d = dst[i];
        int p = row_ptr[d] + atomicAdd(&fill[d], 1);
        col[p] = src[i];
    }
}

// ---------------------------------------------------------------------------
// Pack W (fp32 [K][Nn]) into MFMA-fragment-major fp16 hi/lo pairs.
// Layout: per (nt, ks) chunk: [split(2)][colgrp(BN/16)][lane(64)][8 halfs]
// lane l -> col = nt*BN + cg*16 + (l&15), k = ks*32 + (l>>4)*8 + j
// lo is scaled by 4096 to stay in fp16 normal range.
// ---------------------------------------------------------------------------
__global__ void pack_w_kernel(const float* __restrict__ W, _Float16* __restrict__ P,
                              int K, int Nn, int BN, int total) {
    int id = blockIdx.x * 256 + threadIdx.x;
    if (id >= total) return;
    const int CG = BN / 16, KS = K >> 5;
    const int l = id & 63;
    int r = id >> 6;
    const int cg = r % CG; r /= CG;
    const int ks = r % KS;
    const int nt = r / KS;
    const int c = nt * BN + cg * 16 + (l & 15);
    const int kb = ks * 32 + (l >> 4) * 8;
    const size_t CHUNK = (size_t)2 * CG * 64 * 8;
    _Float16* base = P + (size_t)(nt * KS + ks) * CHUNK + (size_t)(cg * 64 + l) * 8;
    half8 hi, lo;
#pragma unroll
    for (int j = 0; j < 8; ++j) {
        float w = W[(size_t)(kb + j) * Nn + c];
        _Float16 h = (_Float16)w;
        hi[j] = h;
        lo[j] = (_Float16)((w - (float)h) * 4096.0f);
    }
    *(half8*)base = hi;
    *(half8*)(base + CHUNK / 2) = lo;
}

// ---------------------------------------------------------------------------
// C[M,Nn] = A[M,K] @ B[K,Nn] via fp16 split MFMA. BM=128, BN in {128,64},
// BK=32, 256 threads. K%32==0, Nn%BN==0, M tail guarded.
// ---------------------------------------------------------------------------
template <int BN>
__global__ __launch_bounds__(256) void gemm_mfma_kernel(
    const float* __restrict__ A, const _Float16* __restrict__ Bp,
    float* __restrict__ C, int M, int K, int Nn) {
    constexpr int WC = (BN == 128) ? 2 : 1;      // wave grid cols
    constexpr int WR = 4 / WC;                   // wave grid rows
    constexpr int WROWS = 128 / WR;              // 64 or 32 rows per wave
    constexpr int MI = WROWS / 16;               // 4 or 2
    constexpr int NI = 4;                        // wave covers 64 cols
    constexpr int CG = BN / 16;
    constexpr int BREP = BN / 32;                // B copy reps (4 or 2)

    __shared__ _Float16 smA[2][8][64][8];        // 16 KB
    __shared__ _Float16 smB[2][CG][64][8];       // 16/8 KB

    const int tid = threadIdx.x;
    const int wid = tid >> 6, lane = tid & 63;
    const int wr = wid / WC, wc = wid % WC;
    const int bm = blockIdx.y * 128, bn = blockIdx.x * BN;
    const int KS = K >> 5;
    const size_t CHUNK = (size_t)2 * CG * 64 * 8;
    const _Float16* bchunk = Bp + (size_t)blockIdx.x * KS * CHUNK;

    f32x4 acc1[MI][NI] = {};
    f32x4 acc2[MI][NI] = {};

    for (int ks = 0; ks < KS; ++ks) {
        // ---- stage A (fp32 -> regs) and B (packed -> regs) ----
        float4 av[4];
#pragma unroll
        for (int r = 0; r < 4; ++r) {
            const int idx = r * 256 + tid;
            const int mr = idx >> 3, kq = idx & 7;
            const int gm = bm + mr;
            av[r] = (gm < M) ? *(const float4*)(A + (size_t)gm * K + ks * 32 + kq * 4)
                             : make_float4(0.f, 0.f, 0.f, 0.f);
        }
        uint4 bv[BREP];
        const _Float16* bc = bchunk + (size_t)ks * CHUNK;
#pragma unroll
        for (int r = 0; r < BREP; ++r)
            bv[r] = *(const uint4*)(bc + (size_t)(r * 256 + tid) * 8);

        __syncthreads();  // previous iteration's reads complete

        // ---- convert + write A to LDS (fragment-major) ----
#pragma unroll
        for (int r = 0; r < 4; ++r) {
            const int idx = r * 256 + tid;
            const int mr = idx >> 3, kq = idx & 7;
            const int rg = mr >> 4;
            const int l = ((kq >> 1) << 4) + (mr & 15);
            const int hb = (kq & 1) << 2;
            const float4 v = av[r];
            half4 hi, lo;
            hi[0] = (_Float16)v.x; hi[1] = (_Float16)v.y;
            hi[2] = (_Float16)v.z; hi[3] = (_Float16)v.w;
            lo[0] = (_Float16)((v.x - (float)hi[0]) * 4096.0f);
            lo[1] = (_Float16)((v.y - (float)hi[1]) * 4096.0f);
            lo[2] = (_Float16)((v.z - (float)hi[2]) * 4096.0f);
            lo[3] = (_Float16)((v.w - (float)hi[3]) * 4096.0f);
            *(half4*)&smA[0][rg][l][hb] = hi;
            *(half4*)&smA[1][rg][l][hb] = lo;
        }
        // ---- write B to LDS (already fragment-major; linear copy) ----
        _Float16* smBf = &smB[0][0][0][0];
#pragma unroll
        for (int r = 0; r < BREP; ++r)
            *(uint4*)(smBf + (size_t)(r * 256 + tid) * 8) = bv[r];

        __syncthreads();

        // ---- MFMA ----
        half8 afh[MI], afl[MI];
#pragma unroll
        for (int mi = 0; mi < MI; ++mi) {
            afh[mi] = *(const half8*)&smA[0][wr * MI + mi][lane][0];
            afl[mi] = *(const half8*)&smA[1][wr * MI + mi][lane][0];
        }
#pragma unroll
        for (int ni = 0; ni < NI; ++ni) {
            const half8 bh = *(const half8*)&smB[0][wc * 4 + ni][lane][0];
            const half8 bl = *(const half8*)&smB[1][wc * 4 + ni][lane][0];
#pragma unroll
            for (int mi = 0; mi < MI; ++mi) {
                acc1[mi][ni] = __builtin_amdgcn_mfma_f32_16x16x32_f16(
                    afh[mi], bh, acc1[mi][ni], 0, 0, 0);
                acc2[mi][ni] = __builtin_amdgcn_mfma_f32_16x16x32_f16(
                    afl[mi], bh, acc2[mi][ni], 0, 0, 0);
                acc2[mi][ni] = __builtin_amdgcn_mfma_f32_16x16x32_f16(
                    afh[mi], bl, acc2[mi][ni], 0, 0, 0);
            }
        }
    }

    // ---- epilogue: C = acc1 + acc2/4096 ----
    const float inv = 1.0f / 4096.0f;
#pragma unroll
    for (int mi = 0; mi < MI; ++mi) {
#pragma unroll
        for (int ni = 0; ni < NI; ++ni) {
            const int row0 = bm + wr * WROWS + mi * 16 + ((lane >> 4) << 2);
            const int colx = bn + wc * 64 + ni * 16 + (lane & 15);
#pragma unroll
            for (int i = 0; i < 4; ++i) {
                const int row = row0 + i;
                if (row < M)
                    C[(size_t)row * Nn + colx] = acc1[mi][ni][i] + acc2[mi][ni][i] * inv;
            }
        }
    }
}

__device__ __forceinline__ float elu1(float v) { return v > 0.f ? v : expm1f(v); }

// Pull aggregation, one wave per node, 4-way unrolled edge loop.
// MODE 0: y=elu(conv)  MODE 1: y=elu(conv+res)  MODE 2: y=conv
template <int VEC, int MODE>
__global__ __launch_bounds__(256) void agg_pull_kernel(
    const int* __restrict__ row_ptr, const int* __restrict__ col,
    const float* __restrict__ dinv, const float* __restrict__ t,
    const float* __restrict__ bias, const float* __restrict__ res,
    float* __restrict__ y, int Nn, int Hdim) {
    const int node = blockIdx.x * (blockDim.x >> 6) + (threadIdx.x >> 6);
    if (node >= Nn) return;
    const int lane = threadIdx.x & 63;
    const int f = lane * VEC;

    float acc[VEC];
#pragma unroll
    for (int i = 0; i < VEC; ++i) acc[i] = 0.f;

    const int s0 = row_ptr[node], s1 = row_ptr[node + 1];
    int e = s0;
    for (; e + 3 < s1; e += 4) {
        const int sa = col[e], sb = col[e + 1], sc = col[e + 2], sd = col[e + 3];
        const float wa = dinv[sa], wb = dinv[sb], wc = dinv[sc], wd = dinv[sd];
        if (VEC == 4) {
            const float4 va = *(const float4*)(t + (size_t)sa * Hdim + f);
            const float4 vb = *(const float4*)(t + (size_t)sb * Hdim + f);
            const float4 vc = *(const float4*)(t + (size_t)sc * Hdim + f);
            const float4 vd = *(const float4*)(t + (size_t)sd * Hdim + f);
            acc[0] = fmaf(va.x, wa, fmaf(vb.x, wb, fmaf(vc.x, wc, fmaf(vd.x, wd, acc[0]))));
            acc[1] = fmaf(va.y, wa, fmaf(vb.y, wb, fmaf(vc.y, wc, fmaf(vd.y, wd, acc[1]))));
            acc[2] = fmaf(va.z, wa, fmaf(vb.z, wb, fmaf(vc.z, wc, fmaf(vd.z, wd, acc[2]))));
            acc[3] = fmaf(va.w, wa, fmaf(vb.w, wb, fmaf(vc.w, wc, fmaf(vd.w, wd, acc[3]))));
        } else {
            const float va = t[(size_t)sa * Hdim + f], vb = t[(size_t)sb * Hdim + f];
            const float vc2 = t[(size_t)sc * Hdim + f], vd = t[(size_t)sd * Hdim + f];
            acc[0] = fmaf(va, wa, fmaf(vb, wb, fmaf(vc2, wc, fmaf(vd, wd, acc[0]))));
        }
    }
    for (; e < s1; ++e) {
        const int s = col[e];
        const float w = dinv[s];
        const float* ts = t + (size_t)s * Hdim + f;
        if (VEC == 4) {
            float4 v = *(const float4*)ts;
            acc[0] = fmaf(v.x, w, acc[0]);
            acc[1] = fmaf(v.y, w, acc[1]);
            acc[2] = fmaf(v.z, w, acc[2]);
            acc[3] = fmaf(v.w, w, acc[3]);
        } else {
            acc[0] = fmaf(*ts, w, acc[0]);
        }
    }

    const float dn = dinv[node];
    const float* tn = t + (size_t)node * Hdim + f;
    float o[VEC];
#pragma unroll
    for (int i = 0; i < VEC; ++i)
        o[i] = (acc[i] + tn[i] * dn) * dn + bias[f + i];

    if (MODE == 1) {
        const float* rn = res + (size_t)node * Hdim + f;
#pragma unroll
        for (int i = 0; i < VEC; ++i) o[i] += rn[i];
    }
    if (MODE <= 1) {
#pragma unroll
        for (int i = 0; i < VEC; ++i) o[i] = elu1(o[i]);
    }

    float* yn = y + (size_t)node * Hdim + f;
    if (VEC == 4) {
        *(float4*)yn = make_float4(o[0], o[1], o[2], o[3]);
    } else {
        *yn = o[0];
    }
}

extern "C" void kernel_launch(void* const* d_in, const int* in_sizes, int n_in,
                              void* d_out, int out_size, void* d_ws, size_t ws_size,
                              hipStream_t stream) {
    const float* x = (const float*)d_in[0];
    const void* ei_raw = d_in[1];
    const float* W1 = (const float*)d_in[2];
    const float* b1 = (const float*)d_in[3];
    const float* W2 = (const float*)d_in[4];
    const float* b2 = (const float*)d_in[5];
    const float* W3 = (const float*)d_in[6];
    const float* b3 = (const float*)d_in[7];
    float* out = (float*)d_out;

    const int H = in_sizes[3];       // 256
    const int F = in_sizes[2] / H;   // 512
    const int N = in_sizes[0] / F;   // 50000
    const int C = in_sizes[7];       // 64
    const int E = in_sizes[1] / 2;   // 800000

    // workspace layout
    char* ws = (char*)d_ws;
    size_t off = 0;
    auto take = [&](size_t bytes) -> char* {
        char* p = ws + off;
        off += (bytes + 255) & ~(size_t)255;
        return p;
    };
    float* dinv = (float*)take((size_t)N * 4);
    int* flag = (int*)take(4);
    float* t = (float*)take((size_t)N * H * 4);
    float* h1 = (float*)take((size_t)N * H * 4);
    float* h2 = (float*)take((size_t)N * H * 4);
    int* e32 = (int*)take((size_t)2 * E * 4);
    int* srcI = e32;
    int* dstI = e32 + E;
    int* col = (int*)take((size_t)E * 4);
    int* cnt = (int*)take((size_t)N * 4);
    int* row_ptr = (int*)take((size_t)(N + 1) * 4);
    int* fill = (int*)take((size_t)N * 4);
    int* bsum = (int*)take(256 * 4);
    _Float16* pW1 = (_Float16*)take((size_t)F * H * 2 * 2);
    _Float16* pW2 = (_Float16*)take((size_t)H * H * 2 * 2);
    _Float16* pW3 = (_Float16*)take((size_t)H * C * 2 * 2);
    (void)ws_size; (void)n_in; (void)out_size;

    const int nScanBlk = cdiv_i(N, 1024);

    // ---- edges + degrees + CSR ----
    detect_fmt_kernel<<<1, 64, 0, stream>>>((const unsigned*)ei_raw, N, flag);
    edges_to_i32_kernel<<<cdiv_i(2L * E, 256), 256, 0, stream>>>(ei_raw, e32, 2 * E, flag);
    zero_i32_kernel<<<cdiv_i(N, 256), 256, 0, stream>>>(cnt, N);
    hist_kernel<<<cdiv_i(E, 256), 256, 0, stream>>>(dstI, cnt, E);
    dinv_kernel<<<cdiv_i(N, 256), 256, 0, stream>>>(cnt, dinv, N);
    scan1_kernel<<<nScanBlk, 256, 0, stream>>>(cnt, row_ptr, bsum, N);
    scan2_kernel<<<1, 256, 0, stream>>>(bsum, nScanBlk);
    scan3_kernel<<<nScanBlk, 256, 0, stream>>>(row_ptr, bsum, N);
    set_int_kernel<<<1, 1, 0, stream>>>(row_ptr, N, E);
    zero_i32_kernel<<<cdiv_i(N, 256), 256, 0, stream>>>(fill, N);
    scatter_kernel<<<cdiv_i(E, 256), 256, 0, stream>>>(srcI, dstI, row_ptr, fill, col, E);

    // ---- pack weights (fragment-major fp16 hi/lo) ----
    const int tot1 = (H / 128) * (F / 32) * (128 / 16) * 64;
    const int tot2 = (H / 128) * (H / 32) * (128 / 16) * 64;
    const int tot3 = (C / 64) * (H / 32) * (64 / 16) * 64;
    pack_w_kernel<<<cdiv_i(tot1, 256), 256, 0, stream>>>(W1, pW1, F, H, 128, tot1);
    pack_w_kernel<<<cdiv_i(tot2, 256), 256, 0, stream>>>(W2, pW2, H, H, 128, tot2);
    pack_w_kernel<<<cdiv_i(tot3, 256), 256, 0, stream>>>(W3, pW3, H, C, 64, tot3);

    const int aggGridH = cdiv_i(N, 4);
    const int mt = cdiv_i(N, 128);

    // ---- layer 1: h1 = elu(A_hat @ (x @ W1) + b1)
    gemm_mfma_kernel<128><<<dim3(H / 128, mt), 256, 0, stream>>>(x, pW1, t, N, F, H);
    agg_pull_kernel<4, 0><<<aggGridH, 256, 0, stream>>>(row_ptr, col, dinv, t, b1,
                                                        nullptr, h1, N, H);

    // ---- layer 2: h2 = elu(A_hat @ (h1 @ W2) + b2 + h1)
    gemm_mfma_kernel<128><<<dim3(H / 128, mt), 256, 0, stream>>>(h1, pW2, t, N, H, H);
    agg_pull_kernel<4, 1><<<aggGridH, 256, 0, stream>>>(row_ptr, col, dinv, t, b2,
                                                        h1, h2, N, H);

    // ---- layer 3: out = A_hat @ (h2 @ W3) + b3
    gemm_mfma_kernel<64><<<dim3(C / 64, mt), 256, 0, stream>>>(h2, pW3, t, N, H, C);
    agg_pull_kernel<1, 2><<<aggGridH, 256, 0, stream>>>(row_ptr, col, dinv, t, b3,
                                                        nullptr, out, N, C);
}

// Round 5
// 533.298 us; speedup vs baseline: 1.3937x; 1.2614x over previous
//
#include <hip/hip_runtime.h>
#include <cstdint>
#include <cstddef>

// ---------------------------------------------------------------------------
// GCN: 3 layers.  out = A_hat @ (h @ W) + b, A_hat = D^-1/2 (A+I) D^-1/2
// R4: MFMA split-fp16 GEMM re-tiled for occupancy (64x128 block, 4 waves,
//     32x64 wave tile, reg load-ahead); GEMM output t stored as fp16 so
//     aggregation gathers half the bytes. CSR pull agg, 4-way unrolled.
// ---------------------------------------------------------------------------

static inline int cdiv_i(long a, long b) { return (int)((a + b - 1) / b); }

using half4v = __attribute__((ext_vector_type(4))) _Float16;
using half8 = __attribute__((ext_vector_type(8))) _Float16;
using f32x4 = __attribute__((ext_vector_type(4))) float;

__global__ void detect_fmt_kernel(const unsigned int* __restrict__ raw, int n_nodes,
                                  int* __restrict__ flag) {
    if (blockIdx.x == 0 && threadIdx.x == 0) {
        int is64 = 1;
        for (int i = 0; i < 64; ++i) {
            unsigned lo = raw[2 * i], hi = raw[2 * i + 1];
            if (hi != 0u || lo >= (unsigned)n_nodes) { is64 = 0; break; }
        }
        *flag = is64;
    }
}

__global__ void edges_to_i32_kernel(const void* __restrict__ raw, int* __restrict__ out,
                                    int twoE, const int* __restrict__ flag) {
    const int f = *flag;
    for (long i = blockIdx.x * (long)blockDim.x + threadIdx.x; i < twoE;
         i += (long)gridDim.x * blockDim.x) {
        out[i] = f ? (int)(((const long long*)raw)[i]) : ((const int*)raw)[i];
    }
}

__global__ void zero_i32_kernel(int* __restrict__ p, int n) {
    for (long i = blockIdx.x * (long)blockDim.x + threadIdx.x; i < n;
         i += (long)gridDim.x * blockDim.x)
        p[i] = 0;
}

__global__ void hist_kernel(const int* __restrict__ dst, int* __restrict__ cnt, int E) {
    for (long i = blockIdx.x * (long)blockDim.x + threadIdx.x; i < E;
         i += (long)gridDim.x * blockDim.x)
        atomicAdd(&cnt[dst[i]], 1);
}

__global__ void dinv_kernel(const int* __restrict__ cnt, float* __restrict__ dinv, int n) {
    for (long i = blockIdx.x * (long)blockDim.x + threadIdx.x; i < n;
         i += (long)gridDim.x * blockDim.x)
        dinv[i] = rsqrtf((float)cnt[i] + 1.0f);  // +1 self-loop
}

// ---- exclusive scan over n ints: 1024 elems / block ----
__global__ __launch_bounds__(256) void scan1_kernel(const int* __restrict__ in,
                                                    int* __restrict__ out,
                                                    int* __restrict__ bsum, int n) {
    __shared__ int tsum[256];
    const int tid = threadIdx.x;
    const long base = (long)blockIdx.x * 1024 + (long)tid * 4;
    int v[4];
#pragma unroll
    for (int i = 0; i < 4; ++i) v[i] = (base + i < n) ? in[base + i] : 0;
    const int s = v[0] + v[1] + v[2] + v[3];
    tsum[tid] = s;
    __syncthreads();
    for (int off = 1; off < 256; off <<= 1) {
        int add = (tid >= off) ? tsum[tid - off] : 0;
        __syncthreads();
        tsum[tid] += add;
        __syncthreads();
    }
    int run = tsum[tid] - s;
#pragma unroll
    for (int i = 0; i < 4; ++i) {
        if (base + i < n) out[base + i] = run;
        run += v[i];
    }
    if (tid == 255) bsum[blockIdx.x] = tsum[255];
}

__global__ void scan2_kernel(int* __restrict__ bsum, int nb) {
    __shared__ int lds[256];
    const int tid = threadIdx.x;
    int v = (tid < nb) ? bsum[tid] : 0;
    lds[tid] = v;
    __syncthreads();
    for (int off = 1; off < 256; off <<= 1) {
        int add = (tid >= off) ? lds[tid - off] : 0;
        __syncthreads();
        lds[tid] += add;
        __syncthreads();
    }
    if (tid < nb) bsum[tid] = lds[tid] - v;
}

__global__ __launch_bounds__(256) void scan3_kernel(int* __restrict__ out,
                                                    const int* __restrict__ bsum, int n) {
    const long base = (long)blockIdx.x * 1024 + (long)threadIdx.x * 4;
    const int add = bsum[blockIdx.x];
#pragma unroll
    for (int i = 0; i < 4; ++i)
        if (base + i < n) out[base + i] += add;
}

__global__ void set_int_kernel(int* __restrict__ p, int idx, int val) {
    if (blockIdx.x == 0 && threadIdx.x == 0) p[idx] = val;
}

__global__ void scatter_kernel(const int* __restrict__ src, const int* __restrict__ dst,
                               const int* __restrict__ row_ptr, int* __restrict__ fill,
                               int* __restrict__ col, int E) {
    for (long i = blockIdx.x * (long)blockDim.x + threadIdx.x; i < E;
         i += (long)gridDim.x * blockDim.x) {
        int d = dst[i];
        int p = row_ptr[d] + atomicAdd(&fill[d], 1);
        col[p] = src[i];
    }
}

// ---------------------------------------------------------------------------
// Pack W (fp32 [K][Nn]) into MFMA-fragment-major fp16 hi/lo pairs.
// Per (nt, ks) chunk: [split(2)][colgrp(BN/16)][lane(64)][8 halfs]
// lane l -> col = nt*BN + cg*16 + (l&15), k = ks*32 + (l>>4)*8 + j
// ---------------------------------------------------------------------------
__global__ void pack_w_kernel(const float* __restrict__ W, _Float16* __restrict__ P,
                              int K, int Nn, int BN, int total) {
    int id = blockIdx.x * 256 + threadIdx.x;
    if (id >= total) return;
    const int CG = BN / 16, KS = K >> 5;
    const int l = id & 63;
    int r = id >> 6;
    const int cg = r % CG; r /= CG;
    const int ks = r % KS;
    const int nt = r / KS;
    const int c = nt * BN + cg * 16 + (l & 15);
    const int kb = ks * 32 + (l >> 4) * 8;
    const size_t CHUNK = (size_t)2 * CG * 64 * 8;
    _Float16* base = P + (size_t)(nt * KS + ks) * CHUNK + (size_t)(cg * 64 + l) * 8;
    half8 hi, lo;
#pragma unroll
    for (int j = 0; j < 8; ++j) {
        float w = W[(size_t)(kb + j) * Nn + c];
        _Float16 h = (_Float16)w;
        hi[j] = h;
        lo[j] = (_Float16)((w - (float)h) * 4096.0f);
    }
    *(half8*)base = hi;
    *(half8*)(base + CHUNK / 2) = lo;
}

// ---------------------------------------------------------------------------
// Ch[M,Nn](fp16) = A[M,K](fp32) @ B[K,Nn] via split-fp16 MFMA.
// BM=64, BN in {128,64}, BK=32, 256 threads = 4 waves.
// BN=128: wave grid 2x2, wave tile 32x64 (MI=2). BN=64: 4x1, 16x64 (MI=1).
// K%32==0, Nn%BN==0, M tail guarded.
// ---------------------------------------------------------------------------
template <int BN>
__global__ __launch_bounds__(256, 3) void gemm_mfma_kernel(
    const float* __restrict__ A, const _Float16* __restrict__ Bp,
    _Float16* __restrict__ Ch, int M, int K, int Nn) {
    constexpr int WC = BN / 64;              // wave cols: 2 or 1
    constexpr int WR = 4 / WC;               // wave rows: 2 or 4
    constexpr int MI = 64 / (WR * 16);       // 2 or 1
    constexpr int NI = 4;
    constexpr int CG = BN / 16;              // 8 or 4
    constexpr int BREP = CG / 2;             // 4 or 2 (uint4 per thread)
    constexpr int CHUNKH = 2 * CG * 64 * 8;  // halfs per k-chunk

    __shared__ _Float16 smA[2][4][64][8];    // 8 KB  (fragment-major)
    __shared__ _Float16 smB[2][CG][64][8];   // 16/8 KB

    const int tid = threadIdx.x;
    const int wid = tid >> 6, lane = tid & 63;
    const int wr = wid / WC, wc = wid % WC;
    const int bm = blockIdx.y * 64, bn = blockIdx.x * BN;
    const int KS = K >> 5;
    const _Float16* bchunk = Bp + (size_t)blockIdx.x * KS * CHUNKH;

    // A loader: row = tid>>2 (0..63), 8 consecutive k at kq8
    const int arow = tid >> 2;
    const int kq8 = (tid & 3) * 8;
    const int gm = bm + arow;
    const float* Arow = A + (size_t)gm * K + kq8;
    const int argp = arow >> 4;                       // fragment row group
    const int al = (arow & 15) + (tid & 3) * 16;      // lane slot in fragment

    f32x4 acc1[MI][NI] = {};
    f32x4 acc2[MI][NI] = {};

    float4 a0 = make_float4(0.f, 0.f, 0.f, 0.f), a1 = a0;
    uint4 bv[BREP];

    // preload ks=0
    if (gm < M) {
        a0 = *(const float4*)(Arow);
        a1 = *(const float4*)(Arow + 4);
    }
#pragma unroll
    for (int r = 0; r < BREP; ++r)
        bv[r] = *(const uint4*)(bchunk + (size_t)(r * 256 + tid) * 8);

    for (int ks = 0; ks < KS; ++ks) {
        __syncthreads();  // previous iteration's LDS reads complete
        {
            half8 hi, lo;
            hi[0] = (_Float16)a0.x; hi[1] = (_Float16)a0.y;
            hi[2] = (_Float16)a0.z; hi[3] = (_Float16)a0.w;
            hi[4] = (_Float16)a1.x; hi[5] = (_Float16)a1.y;
            hi[6] = (_Float16)a1.z; hi[7] = (_Float16)a1.w;
            lo[0] = (_Float16)((a0.x - (float)hi[0]) * 4096.0f);
            lo[1] = (_Float16)((a0.y - (float)hi[1]) * 4096.0f);
            lo[2] = (_Float16)((a0.z - (float)hi[2]) * 4096.0f);
            lo[3] = (_Float16)((a0.w - (float)hi[3]) * 4096.0f);
            lo[4] = (_Float16)((a1.x - (float)hi[4]) * 4096.0f);
            lo[5] = (_Float16)((a1.y - (float)hi[5]) * 4096.0f);
            lo[6] = (_Float16)((a1.z - (float)hi[6]) * 4096.0f);
            lo[7] = (_Float16)((a1.w - (float)hi[7]) * 4096.0f);
            *(half8*)&smA[0][argp][al][0] = hi;
            *(half8*)&smA[1][argp][al][0] = lo;
            _Float16* smBf = &smB[0][0][0][0];
#pragma unroll
            for (int r = 0; r < BREP; ++r)
                *(uint4*)(smBf + (size_t)(r * 256 + tid) * 8) = bv[r];
        }
        __syncthreads();

        // load-ahead ks+1 (in flight during MFMA below)
        if (ks + 1 < KS) {
            const int ko = (ks + 1) * 32;
            if (gm < M) {
                a0 = *(const float4*)(Arow + ko);
                a1 = *(const float4*)(Arow + ko + 4);
            }
            const _Float16* bc = bchunk + (size_t)(ks + 1) * CHUNKH;
#pragma unroll
            for (int r = 0; r < BREP; ++r)
                bv[r] = *(const uint4*)(bc + (size_t)(r * 256 + tid) * 8);
        }

        half8 afh[MI], afl[MI];
#pragma unroll
        for (int mi = 0; mi < MI; ++mi) {
            afh[mi] = *(const half8*)&smA[0][wr * MI + mi][lane][0];
            afl[mi] = *(const half8*)&smA[1][wr * MI + mi][lane][0];
        }
#pragma unroll
        for (int ni = 0; ni < NI; ++ni) {
            const half8 bh = *(const half8*)&smB[0][wc * 4 + ni][lane][0];
            const half8 bl = *(const half8*)&smB[1][wc * 4 + ni][lane][0];
#pragma unroll
            for (int mi = 0; mi < MI; ++mi) {
                acc1[mi][ni] = __builtin_amdgcn_mfma_f32_16x16x32_f16(
                    afh[mi], bh, acc1[mi][ni], 0, 0, 0);
                acc2[mi][ni] = __builtin_amdgcn_mfma_f32_16x16x32_f16(
                    afl[mi], bh, acc2[mi][ni], 0, 0, 0);
                acc2[mi][ni] = __builtin_amdgcn_mfma_f32_16x16x32_f16(
                    afh[mi], bl, acc2[mi][ni], 0, 0, 0);
            }
        }
    }

    // ---- epilogue: Ch = fp16(acc1 + acc2/4096) ----
    const float inv = 1.0f / 4096.0f;
#pragma unroll
    for (int mi = 0; mi < MI; ++mi) {
#pragma unroll
        for (int ni = 0; ni < NI; ++ni) {
            const int row0 = bm + wr * (MI * 16) + mi * 16 + ((lane >> 4) << 2);
            const int colx = bn + wc * 64 + ni * 16 + (lane & 15);
#pragma unroll
            for (int i = 0; i < 4; ++i) {
                const int row = row0 + i;
                if (row < M)
                    Ch[(size_t)row * Nn + colx] =
                        (_Float16)(acc1[mi][ni][i] + acc2[mi][ni][i] * inv);
            }
        }
    }
}

__device__ __forceinline__ float elu1(float v) { return v > 0.f ? v : expm1f(v); }

// Pull aggregation over fp16 t, one wave per node, 4-way unrolled edges.
// MODE 0: y=elu(conv)  MODE 1: y=elu(conv+res)  MODE 2: y=conv
template <int VEC, int MODE>
__global__ __launch_bounds__(256) void agg_pull_kernel(
    const int* __restrict__ row_ptr, const int* __restrict__ col,
    const float* __restrict__ dinv, const _Float16* __restrict__ t,
    const float* __restrict__ bias, const float* __restrict__ res,
    float* __restrict__ y, int Nn, int Hdim) {
    const int node = blockIdx.x * (blockDim.x >> 6) + (threadIdx.x >> 6);
    if (node >= Nn) return;
    const int lane = threadIdx.x & 63;
    const int f = lane * VEC;

    float acc[VEC];
#pragma unroll
    for (int i = 0; i < VEC; ++i) acc[i] = 0.f;

    const int s0 = row_ptr[node], s1 = row_ptr[node + 1];
    int e = s0;
    for (; e + 3 < s1; e += 4) {
        const int sa = col[e], sb = col[e + 1], sc = col[e + 2], sd = col[e + 3];
        const float wa = dinv[sa], wb = dinv[sb], wc = dinv[sc], wd = dinv[sd];
        if (VEC == 4) {
            const half4v va = *(const half4v*)(t + (size_t)sa * Hdim + f);
            const half4v vb = *(const half4v*)(t + (size_t)sb * Hdim + f);
            const half4v vc = *(const half4v*)(t + (size_t)sc * Hdim + f);
            const half4v vd = *(const half4v*)(t + (size_t)sd * Hdim + f);
#pragma unroll
            for (int i = 0; i < VEC; ++i)
                acc[i] = fmaf((float)va[i], wa,
                         fmaf((float)vb[i], wb,
                         fmaf((float)vc[i], wc,
                         fmaf((float)vd[i], wd, acc[i]))));
        } else {
            const float va = (float)t[(size_t)sa * Hdim + f];
            const float vb = (float)t[(size_t)sb * Hdim + f];
            const float vc2 = (float)t[(size_t)sc * Hdim + f];
            const float vd = (float)t[(size_t)sd * Hdim + f];
            acc[0] = fmaf(va, wa, fmaf(vb, wb, fmaf(vc2, wc, fmaf(vd, wd, acc[0]))));
        }
    }
    for (; e < s1; ++e) {
        const int s = col[e];
        const float w = dinv[s];
        if (VEC == 4) {
            const half4v v = *(const half4v*)(t + (size_t)s * Hdim + f);
#pragma unroll
            for (int i = 0; i < VEC; ++i) acc[i] = fmaf((float)v[i], w, acc[i]);
        } else {
            acc[0] = fmaf((float)t[(size_t)s * Hdim + f], w, acc[0]);
        }
    }

    const float dn = dinv[node];
    float o[VEC];
    if (VEC == 4) {
        const half4v tn = *(const half4v*)(t + (size_t)node * Hdim + f);
#pragma unroll
        for (int i = 0; i < VEC; ++i)
            o[i] = (acc[i] + (float)tn[i] * dn) * dn + bias[f + i];
    } else {
        o[0] = (acc[0] + (float)t[(size_t)node * Hdim + f] * dn) * dn + bias[f];
    }

    if (MODE == 1) {
        const float* rn = res + (size_t)node * Hdim + f;
#pragma unroll
        for (int i = 0; i < VEC; ++i) o[i] += rn[i];
    }
    if (MODE <= 1) {
#pragma unroll
        for (int i = 0; i < VEC; ++i) o[i] = elu1(o[i]);
    }

    float* yn = y + (size_t)node * Hdim + f;
    if (VEC == 4) {
        *(float4*)yn = make_float4(o[0], o[1], o[2], o[3]);
    } else {
        *yn = o[0];
    }
}

extern "C" void kernel_launch(void* const* d_in, const int* in_sizes, int n_in,
                              void* d_out, int out_size, void* d_ws, size_t ws_size,
                              hipStream_t stream) {
    const float* x = (const float*)d_in[0];
    const void* ei_raw = d_in[1];
    const float* W1 = (const float*)d_in[2];
    const float* b1 = (const float*)d_in[3];
    const float* W2 = (const float*)d_in[4];
    const float* b2 = (const float*)d_in[5];
    const float* W3 = (const float*)d_in[6];
    const float* b3 = (const float*)d_in[7];
    float* out = (float*)d_out;

    const int H = in_sizes[3];       // 256
    const int F = in_sizes[2] / H;   // 512
    const int N = in_sizes[0] / F;   // 50000
    const int C = in_sizes[7];       // 64
    const int E = in_sizes[1] / 2;   // 800000

    // workspace layout
    char* ws = (char*)d_ws;
    size_t off = 0;
    auto take = [&](size_t bytes) -> char* {
        char* p = ws + off;
        off += (bytes + 255) & ~(size_t)255;
        return p;
    };
    float* dinv = (float*)take((size_t)N * 4);
    int* flag = (int*)take(4);
    _Float16* th = (_Float16*)take((size_t)N * H * 2);   // fp16 GEMM output
    float* h1 = (float*)take((size_t)N * H * 4);
    float* h2 = (float*)take((size_t)N * H * 4);
    int* e32 = (int*)take((size_t)2 * E * 4);
    int* srcI = e32;
    int* dstI = e32 + E;
    int* col = (int*)take((size_t)E * 4);
    int* cnt = (int*)take((size_t)N * 4);
    int* row_ptr = (int*)take((size_t)(N + 1) * 4);
    int* fill = (int*)take((size_t)N * 4);
    int* bsum = (int*)take(256 * 4);
    _Float16* pW1 = (_Float16*)take((size_t)F * H * 2 * 2);
    _Float16* pW2 = (_Float16*)take((size_t)H * H * 2 * 2);
    _Float16* pW3 = (_Float16*)take((size_t)H * C * 2 * 2);
    (void)ws_size; (void)n_in; (void)out_size;

    const int nScanBlk = cdiv_i(N, 1024);

    // ---- edges + degrees + CSR ----
    detect_fmt_kernel<<<1, 64, 0, stream>>>((const unsigned*)ei_raw, N, flag);
    edges_to_i32_kernel<<<cdiv_i(2L * E, 256), 256, 0, stream>>>(ei_raw, e32, 2 * E, flag);
    zero_i32_kernel<<<cdiv_i(N, 256), 256, 0, stream>>>(cnt, N);
    hist_kernel<<<cdiv_i(E, 256), 256, 0, stream>>>(dstI, cnt, E);
    dinv_kernel<<<cdiv_i(N, 256), 256, 0, stream>>>(cnt, dinv, N);
    scan1_kernel<<<nScanBlk, 256, 0, stream>>>(cnt, row_ptr, bsum, N);
    scan2_kernel<<<1, 256, 0, stream>>>(bsum, nScanBlk);
    scan3_kernel<<<nScanBlk, 256, 0, stream>>>(row_ptr, bsum, N);
    set_int_kernel<<<1, 1, 0, stream>>>(row_ptr, N, E);
    zero_i32_kernel<<<cdiv_i(N, 256), 256, 0, stream>>>(fill, N);
    scatter_kernel<<<cdiv_i(E, 256), 256, 0, stream>>>(srcI, dstI, row_ptr, fill, col, E);

    // ---- pack weights (fragment-major fp16 hi/lo) ----
    const int tot1 = (H / 128) * (F / 32) * (128 / 16) * 64;
    const int tot2 = (H / 128) * (H / 32) * (128 / 16) * 64;
    const int tot3 = (C / 64) * (H / 32) * (64 / 16) * 64;
    pack_w_kernel<<<cdiv_i(tot1, 256), 256, 0, stream>>>(W1, pW1, F, H, 128, tot1);
    pack_w_kernel<<<cdiv_i(tot2, 256), 256, 0, stream>>>(W2, pW2, H, H, 128, tot2);
    pack_w_kernel<<<cdiv_i(tot3, 256), 256, 0, stream>>>(W3, pW3, H, C, 64, tot3);

    const int aggGridH = cdiv_i(N, 4);
    const int mt = cdiv_i(N, 64);

    // ---- layer 1: h1 = elu(A_hat @ (x @ W1) + b1)
    gemm_mfma_kernel<128><<<dim3(H / 128, mt), 256, 0, stream>>>(x, pW1, th, N, F, H);
    agg_pull_kernel<4, 0><<<aggGridH, 256, 0, stream>>>(row_ptr, col, dinv, th, b1,
                                                        nullptr, h1, N, H);

    // ---- layer 2: h2 = elu(A_hat @ (h1 @ W2) + b2 + h1)
    gemm_mfma_kernel<128><<<dim3(H / 128, mt), 256, 0, stream>>>(h1, pW2, th, N, H, H);
    agg_pull_kernel<4, 1><<<aggGridH, 256, 0, stream>>>(row_ptr, col, dinv, th, b2,
                                                        h1, h2, N, H);

    // ---- layer 3: out = A_hat @ (h2 @ W3) + b3
    gemm_mfma_kernel<64><<<dim3(C / 64, mt), 256, 0, stream>>>(h2, pW3, th, N, H, C);
    agg_pull_kernel<1, 2><<<aggGridH, 256, 0, stream>>>(row_ptr, col, dinv, th, b3,
                                                        nullptr, out, N, C);
}

// Round 6
// 446.020 us; speedup vs baseline: 1.6664x; 1.1957x over previous
//
#include <hip/hip_runtime.h>
#include <cstdint>
#include <cstddef>

// ---------------------------------------------------------------------------
// GCN: 3 layers.  out = A_hat @ (h @ W) + b, A_hat = D^-1/2 (A+I) D^-1/2
// R5: A pre-split to fragment-major fp16 hi/lo (pack_a); GEMM k-loop uses
//     global_load_lds staging + conflict-free lane-linear ds_read_b128 +
//     split-fp16 MFMA; epilogue transposed through LDS for full-line stores.
// ---------------------------------------------------------------------------

static inline int cdiv_i(long a, long b) { return (int)((a + b - 1) / b); }

using half4v = __attribute__((ext_vector_type(4))) _Float16;
using half8 = __attribute__((ext_vector_type(8))) _Float16;
using f32x4 = __attribute__((ext_vector_type(4))) float;

__device__ __forceinline__ void gload_lds16(const void* g, void* l) {
    __builtin_amdgcn_global_load_lds(
        (const __attribute__((address_space(1))) unsigned int*)g,
        (__attribute__((address_space(3))) unsigned int*)l, 16, 0, 0);
}

__global__ void detect_fmt_kernel(const unsigned int* __restrict__ raw, int n_nodes,
                                  int* __restrict__ flag) {
    if (blockIdx.x == 0 && threadIdx.x == 0) {
        int is64 = 1;
        for (int i = 0; i < 64; ++i) {
            unsigned lo = raw[2 * i], hi = raw[2 * i + 1];
            if (hi != 0u || lo >= (unsigned)n_nodes) { is64 = 0; break; }
        }
        *flag = is64;
    }
}

__global__ void edges_to_i32_kernel(const void* __restrict__ raw, int* __restrict__ out,
                                    int twoE, const int* __restrict__ flag) {
    const int f = *flag;
    for (long i = blockIdx.x * (long)blockDim.x + threadIdx.x; i < twoE;
         i += (long)gridDim.x * blockDim.x) {
        out[i] = f ? (int)(((const long long*)raw)[i]) : ((const int*)raw)[i];
    }
}

__global__ void zero_i32_kernel(int* __restrict__ p, int n) {
    for (long i = blockIdx.x * (long)blockDim.x + threadIdx.x; i < n;
         i += (long)gridDim.x * blockDim.x)
        p[i] = 0;
}

__global__ void hist_kernel(const int* __restrict__ dst, int* __restrict__ cnt, int E) {
    for (long i = blockIdx.x * (long)blockDim.x + threadIdx.x; i < E;
         i += (long)gridDim.x * blockDim.x)
        atomicAdd(&cnt[dst[i]], 1);
}

__global__ void dinv_kernel(const int* __restrict__ cnt, float* __restrict__ dinv, int n) {
    for (long i = blockIdx.x * (long)blockDim.x + threadIdx.x; i < n;
         i += (long)gridDim.x * blockDim.x)
        dinv[i] = rsqrtf((float)cnt[i] + 1.0f);  // +1 self-loop
}

// ---- exclusive scan over n ints: 1024 elems / block ----
__global__ __launch_bounds__(256) void scan1_kernel(const int* __restrict__ in,
                                                    int* __restrict__ out,
                                                    int* __restrict__ bsum, int n) {
    __shared__ int tsum[256];
    const int tid = threadIdx.x;
    const long base = (long)blockIdx.x * 1024 + (long)tid * 4;
    int v[4];
#pragma unroll
    for (int i = 0; i < 4; ++i) v[i] = (base + i < n) ? in[base + i] : 0;
    const int s = v[0] + v[1] + v[2] + v[3];
    tsum[tid] = s;
    __syncthreads();
    for (int off = 1; off < 256; off <<= 1) {
        int add = (tid >= off) ? tsum[tid - off] : 0;
        __syncthreads();
        tsum[tid] += add;
        __syncthreads();
    }
    int run = tsum[tid] - s;
#pragma unroll
    for (int i = 0; i < 4; ++i) {
        if (base + i < n) out[base + i] = run;
        run += v[i];
    }
    if (tid == 255) bsum[blockIdx.x] = tsum[255];
}

__global__ void scan2_kernel(int* __restrict__ bsum, int nb) {
    __shared__ int lds[256];
    const int tid = threadIdx.x;
    int v = (tid < nb) ? bsum[tid] : 0;
    lds[tid] = v;
    __syncthreads();
    for (int off = 1; off < 256; off <<= 1) {
        int add = (tid >= off) ? lds[tid - off] : 0;
        __syncthreads();
        lds[tid] += add;
        __syncthreads();
    }
    if (tid < nb) bsum[tid] = lds[tid] - v;
}

__global__ __launch_bounds__(256) void scan3_kernel(int* __restrict__ out,
                                                    const int* __restrict__ bsum, int n) {
    const long base = (long)blockIdx.x * 1024 + (long)threadIdx.x * 4;
    const int add = bsum[blockIdx.x];
#pragma unroll
    for (int i = 0; i < 4; ++i)
        if (base + i < n) out[base + i] += add;
}

__global__ void set_int_kernel(int* __restrict__ p, int idx, int val) {
    if (blockIdx.x == 0 && threadIdx.x == 0) p[idx] = val;
}

__global__ void scatter_kernel(const int* __restrict__ src, const int* __restrict__ dst,
                               const int* __restrict__ row_ptr, int* __restrict__ fill,
                               int* __restrict__ col, int E) {
    for (long i = blockIdx.x * (long)blockDim.x + threadIdx.x; i < E;
         i += (long)gridDim.x * blockDim.x) {
        int d = dst[i];
        int p = row_ptr[d] + atomicAdd(&fill[d], 1);
        col[p] = src[i];
    }
}

__device__ __forceinline__ void split8(const float4& a0, const float4& a1,
                                       half8& hi, half8& lo) {
    float v[8] = {a0.x, a0.y, a0.z, a0.w, a1.x, a1.y, a1.z, a1.w};
#pragma unroll
    for (int j = 0; j < 8; ++j) {
        _Float16 h = (_Float16)v[j];
        hi[j] = h;
        lo[j] = (_Float16)((v[j] - (float)h) * 4096.0f);
    }
}

// ---------------------------------------------------------------------------
// Pack W (fp32 [K][Nn]) into fragment-major fp16 hi/lo.
// Per (nt, ks) chunk: [split(2)][colgrp(BN/16)][lane(64)][8 halfs]
// lane l -> col = nt*BN + cg*16 + (l&15), k = ks*32 + (l>>4)*8 + j
// ---------------------------------------------------------------------------
__global__ void pack_w_kernel(const float* __restrict__ W, _Float16* __restrict__ P,
                              int K, int Nn, int BN, int total) {
    int id = blockIdx.x * 256 + threadIdx.x;
    if (id >= total) return;
    const int CG = BN / 16, KS = K >> 5;
    const int l = id & 63;
    int r = id >> 6;
    const int cg = r % CG; r /= CG;
    const int ks = r % KS;
    const int nt = r / KS;
    const int c = nt * BN + cg * 16 + (l & 15);
    const int kb = ks * 32 + (l >> 4) * 8;
    const size_t CHUNK = (size_t)2 * CG * 64 * 8;
    _Float16* base = P + (size_t)(nt * KS + ks) * CHUNK + (size_t)(cg * 64 + l) * 8;
    float4 w0, w1;
#pragma unroll
    for (int j = 0; j < 4; ++j) ((float*)&w0)[j] = W[(size_t)(kb + j) * Nn + c];
#pragma unroll
    for (int j = 0; j < 4; ++j) ((float*)&w1)[j] = W[(size_t)(kb + 4 + j) * Nn + c];
    half8 hi, lo;
    split8(w0, w1, hi, lo);
    *(half8*)base = hi;
    *(half8*)(base + CHUNK / 2) = lo;
}

// ---------------------------------------------------------------------------
// Pack A (fp32 [M][K], M tail zero-padded) into fragment-major fp16 hi/lo.
// Per (mt, ks) chunk (4096 halfs): [split(2)][rowgrp(4)][lane(64)][8 halfs]
// lane l -> row = mt*64 + rg*16 + (l&15), k = ks*32 + (l>>4)*8 + j
// Each thread's hi8/lo8 is one contiguous 16B slot; wave covers a 1KB span.
// ---------------------------------------------------------------------------
__global__ __launch_bounds__(256) void pack_a_kernel(const float* __restrict__ A,
                                                     _Float16* __restrict__ P,
                                                     int M, int K) {
    const int tid = threadIdx.x;
    const int ks = blockIdx.x, mt = blockIdx.y;
    const int KS = K >> 5;
    const int r = tid >> 2, kq = (tid & 3) << 3;
    const int gm = mt * 64 + r;
    float4 a0 = make_float4(0.f, 0.f, 0.f, 0.f), a1 = a0;
    if (gm < M) {
        const float* Ar = A + (size_t)gm * K + ks * 32 + kq;
        a0 = *(const float4*)Ar;
        a1 = *(const float4*)(Ar + 4);
    }
    half8 hi, lo;
    split8(a0, a1, hi, lo);
    const int rg = r >> 4;
    const int l = (r & 15) + ((tid & 3) << 4);
    _Float16* base = P + ((size_t)mt * KS + ks) * 4096 + (size_t)((rg * 64 + l) << 3);
    *(half8*)base = hi;
    *(half8*)(base + 2048) = lo;
}

// ---------------------------------------------------------------------------
// Ch[M,Nn](fp16) = A @ B from packed hi/lo operands, split-fp16 MFMA.
// BM=64, BN in {128,64}, BK=32, 256 threads = 4 waves, m97-style
// global_load_lds staging, LDS-transposed coalesced epilogue.
// ---------------------------------------------------------------------------
template <int BN>
__global__ __launch_bounds__(256) void gemm_mfma_kernel(
    const _Float16* __restrict__ Ap, const _Float16* __restrict__ Bp,
    _Float16* __restrict__ Ch, int M, int K, int Nn) {
    constexpr int WC = BN / 64;              // wave cols: 2 or 1
    constexpr int WR = 4 / WC;               // wave rows: 2 or 4
    constexpr int MI = 64 / (WR * 16);       // 2 or 1
    constexpr int NI = 4;
    constexpr int ACH = 4096;                // halfs per A chunk (8 KB)
    constexpr int BCH = 2 * (BN / 16) * 64 * 8;  // halfs per B chunk
    constexpr int BU = BCH / 2048;           // B 1KB-units per wave (4 or 2)
    constexpr int SMH = (ACH + BCH > 64 * BN) ? (ACH + BCH) : (64 * BN);

    __shared__ __align__(16) _Float16 sm[SMH];
    _Float16* smA = sm;
    _Float16* smB = sm + ACH;

    const int tid = threadIdx.x;
    const int lane = tid & 63;
    const int wid = __builtin_amdgcn_readfirstlane(tid >> 6);
    const int wr = wid / WC, wc = wid % WC;
    const int bm = blockIdx.y * 64, bn = blockIdx.x * BN;
    const int KS = K >> 5;
    const _Float16* achunk = Ap + (size_t)blockIdx.y * KS * ACH;
    const _Float16* bchunk = Bp + (size_t)blockIdx.x * KS * BCH;

    f32x4 acc1[MI][NI] = {};
    f32x4 acc2[MI][NI] = {};

    for (int ks = 0; ks < KS; ++ks) {
        if (ks) __syncthreads();  // prior compute done before overwrite
        const _Float16* ac = achunk + (size_t)ks * ACH;
        const _Float16* bc = bchunk + (size_t)ks * BCH;
#pragma unroll
        for (int r = 0; r < 2; ++r)
            gload_lds16(ac + (size_t)(((wid * 2 + r) * 64 + lane) << 3),
                        smA + ((wid * 2 + r) << 9));
#pragma unroll
        for (int r = 0; r < BU; ++r)
            gload_lds16(bc + (size_t)(((wid * BU + r) * 64 + lane) << 3),
                        smB + ((wid * BU + r) << 9));
        __syncthreads();  // vmcnt drained by compiler before barrier

        half8 afh[MI], afl[MI];
#pragma unroll
        for (int mi = 0; mi < MI; ++mi) {
            afh[mi] = *(const half8*)(smA + (((wr * MI + mi) * 64 + lane) << 3));
            afl[mi] = *(const half8*)(smA + 2048 + (((wr * MI + mi) * 64 + lane) << 3));
        }
#pragma unroll
        for (int ni = 0; ni < NI; ++ni) {
            const half8 bh = *(const half8*)(smB + (((wc * 4 + ni) * 64 + lane) << 3));
            const half8 bl = *(const half8*)(smB + BCH / 2 + (((wc * 4 + ni) * 64 + lane) << 3));
#pragma unroll
            for (int mi = 0; mi < MI; ++mi) {
                acc1[mi][ni] = __builtin_amdgcn_mfma_f32_16x16x32_f16(
                    afh[mi], bh, acc1[mi][ni], 0, 0, 0);
                acc2[mi][ni] = __builtin_amdgcn_mfma_f32_16x16x32_f16(
                    afl[mi], bh, acc2[mi][ni], 0, 0, 0);
                acc2[mi][ni] = __builtin_amdgcn_mfma_f32_16x16x32_f16(
                    afh[mi], bl, acc2[mi][ni], 0, 0, 0);
            }
        }
    }

    // ---- epilogue: stage fp16 tile in LDS, store full coalesced lines ----
    __syncthreads();
    const float inv = 1.0f / 4096.0f;
#pragma unroll
    for (int mi = 0; mi < MI; ++mi) {
#pragma unroll
        for (int ni = 0; ni < NI; ++ni) {
            const int row0 = wr * (MI * 16) + mi * 16 + ((lane >> 4) << 2);
            const int colx = wc * 64 + ni * 16 + (lane & 15);
#pragma unroll
            for (int i = 0; i < 4; ++i)
                sm[(row0 + i) * BN + colx] =
                    (_Float16)(acc1[mi][ni][i] + acc2[mi][ni][i] * inv);
        }
    }
    __syncthreads();
    constexpr int UPR = BN / 8;  // 16B units per row
#pragma unroll
    for (int r = 0; r < BN / 32; ++r) {
        const int u = r * 256 + tid;
        const int row = u / UPR, cu = u % UPR;
        const int grow = bm + row;
        if (grow < M)
            *(uint4*)(Ch + (size_t)grow * Nn + bn + cu * 8) =
                *(const uint4*)(sm + row * BN + cu * 8);
    }
}

__device__ __forceinline__ float elu1(float v) { return v > 0.f ? v : expm1f(v); }

// Pull aggregation over fp16 t, one wave per node, 4-way unrolled edges.
// MODE 0: y=elu(conv)  MODE 1: y=elu(conv+res)  MODE 2: y=conv
template <int VEC, int MODE>
__global__ __launch_bounds__(256) void agg_pull_kernel(
    const int* __restrict__ row_ptr, const int* __restrict__ col,
    const float* __restrict__ dinv, const _Float16* __restrict__ t,
    const float* __restrict__ bias, const float* __restrict__ res,
    float* __restrict__ y, int Nn, int Hdim) {
    const int node = blockIdx.x * (blockDim.x >> 6) + (threadIdx.x >> 6);
    if (node >= Nn) return;
    const int lane = threadIdx.x & 63;
    const int f = lane * VEC;

    float acc[VEC];
#pragma unroll
    for (int i = 0; i < VEC; ++i) acc[i] = 0.f;

    const int s0 = row_ptr[node], s1 = row_ptr[node + 1];
    int e = s0;
    for (; e + 3 < s1; e += 4) {
        const int sa = col[e], sb = col[e + 1], sc = col[e + 2], sd = col[e + 3];
        const float wa = dinv[sa], wb = dinv[sb], wc = dinv[sc], wd = dinv[sd];
        if (VEC == 4) {
            const half4v va = *(const half4v*)(t + (size_t)sa * Hdim + f);
            const half4v vb = *(const half4v*)(t + (size_t)sb * Hdim + f);
            const half4v vc = *(const half4v*)(t + (size_t)sc * Hdim + f);
            const half4v vd = *(const half4v*)(t + (size_t)sd * Hdim + f);
#pragma unroll
            for (int i = 0; i < VEC; ++i)
                acc[i] = fmaf((float)va[i], wa,
                         fmaf((float)vb[i], wb,
                         fmaf((float)vc[i], wc,
                         fmaf((float)vd[i], wd, acc[i]))));
        } else {
            const float va = (float)t[(size_t)sa * Hdim + f];
            const float vb = (float)t[(size_t)sb * Hdim + f];
            const float vc2 = (float)t[(size_t)sc * Hdim + f];
            const float vd = (float)t[(size_t)sd * Hdim + f];
            acc[0] = fmaf(va, wa, fmaf(vb, wb, fmaf(vc2, wc, fmaf(vd, wd, acc[0]))));
        }
    }
    for (; e < s1; ++e) {
        const int s = col[e];
        const float w = dinv[s];
        if (VEC == 4) {
            const half4v v = *(const half4v*)(t + (size_t)s * Hdim + f);
#pragma unroll
            for (int i = 0; i < VEC; ++i) acc[i] = fmaf((float)v[i], w, acc[i]);
        } else {
            acc[0] = fmaf((float)t[(size_t)s * Hdim + f], w, acc[0]);
        }
    }

    const float dn = dinv[node];
    float o[VEC];
    if (VEC == 4) {
        const half4v tn = *(const half4v*)(t + (size_t)node * Hdim + f);
#pragma unroll
        for (int i = 0; i < VEC; ++i)
            o[i] = (acc[i] + (float)tn[i] * dn) * dn + bias[f + i];
    } else {
        o[0] = (acc[0] + (float)t[(size_t)node * Hdim + f] * dn) * dn + bias[f];
    }

    if (MODE == 1) {
        const float* rn = res + (size_t)node * Hdim + f;
#pragma unroll
        for (int i = 0; i < VEC; ++i) o[i] += rn[i];
    }
    if (MODE <= 1) {
#pragma unroll
        for (int i = 0; i < VEC; ++i) o[i] = elu1(o[i]);
    }

    float* yn = y + (size_t)node * Hdim + f;
    if (VEC == 4) {
        *(float4*)yn = make_float4(o[0], o[1], o[2], o[3]);
    } else {
        *yn = o[0];
    }
}

extern "C" void kernel_launch(void* const* d_in, const int* in_sizes, int n_in,
                              void* d_out, int out_size, void* d_ws, size_t ws_size,
                              hipStream_t stream) {
    const float* x = (const float*)d_in[0];
    const void* ei_raw = d_in[1];
    const float* W1 = (const float*)d_in[2];
    const float* b1 = (const float*)d_in[3];
    const float* W2 = (const float*)d_in[4];
    const float* b2 = (const float*)d_in[5];
    const float* W3 = (const float*)d_in[6];
    const float* b3 = (const float*)d_in[7];
    float* out = (float*)d_out;

    const int H = in_sizes[3];       // 256
    const int F = in_sizes[2] / H;   // 512
    const int N = in_sizes[0] / F;   // 50000
    const int C = in_sizes[7];       // 64
    const int E = in_sizes[1] / 2;   // 800000
    const int Mt = cdiv_i(N, 64);    // 782 row tiles

    // workspace layout
    char* ws = (char*)d_ws;
    size_t off = 0;
    auto take = [&](size_t bytes) -> char* {
        char* p = ws + off;
        off += (bytes + 255) & ~(size_t)255;
        return p;
    };
    float* dinv = (float*)take((size_t)N * 4);
    int* flag = (int*)take(4);
    _Float16* th = (_Float16*)take((size_t)N * H * 2);        // GEMM output (fp16)
    float* h1 = (float*)take((size_t)N * H * 4);
    float* h2 = (float*)take((size_t)N * H * 4);
    _Float16* as = (_Float16*)take((size_t)Mt * 64 * F * 4);  // packed A hi/lo (shared)
    int* e32 = (int*)take((size_t)2 * E * 4);
    int* srcI = e32;
    int* dstI = e32 + E;
    int* col = (int*)take((size_t)E * 4);
    int* cnt = (int*)take((size_t)N * 4);
    int* row_ptr = (int*)take((size_t)(N + 1) * 4);
    int* fill = (int*)take((size_t)N * 4);
    int* bsum = (int*)take(256 * 4);
    _Float16* pW1 = (_Float16*)take((size_t)F * H * 2 * 2);
    _Float16* pW2 = (_Float16*)take((size_t)H * H * 2 * 2);
    _Float16* pW3 = (_Float16*)take((size_t)H * C * 2 * 2);
    (void)ws_size; (void)n_in; (void)out_size;

    const int nScanBlk = cdiv_i(N, 1024);

    // ---- edges + degrees + CSR ----
    detect_fmt_kernel<<<1, 64, 0, stream>>>((const unsigned*)ei_raw, N, flag);
    edges_to_i32_kernel<<<cdiv_i(2L * E, 256), 256, 0, stream>>>(ei_raw, e32, 2 * E, flag);
    zero_i32_kernel<<<cdiv_i(N, 256), 256, 0, stream>>>(cnt, N);
    hist_kernel<<<cdiv_i(E, 256), 256, 0, stream>>>(dstI, cnt, E);
    dinv_kernel<<<cdiv_i(N, 256), 256, 0, stream>>>(cnt, dinv, N);
    scan1_kernel<<<nScanBlk, 256, 0, stream>>>(cnt, row_ptr, bsum, N);
    scan2_kernel<<<1, 256, 0, stream>>>(bsum, nScanBlk);
    scan3_kernel<<<nScanBlk, 256, 0, stream>>>(row_ptr, bsum, N);
    set_int_kernel<<<1, 1, 0, stream>>>(row_ptr, N, E);
    zero_i32_kernel<<<cdiv_i(N, 256), 256, 0, stream>>>(fill, N);
    scatter_kernel<<<cdiv_i(E, 256), 256, 0, stream>>>(srcI, dstI, row_ptr, fill, col, E);

    // ---- pack weights (fragment-major fp16 hi/lo) ----
    const int tot1 = (H / 128) * (F / 32) * (128 / 16) * 64;
    const int tot2 = (H / 128) * (H / 32) * (128 / 16) * 64;
    const int tot3 = (C / 64) * (H / 32) * (64 / 16) * 64;
    pack_w_kernel<<<cdiv_i(tot1, 256), 256, 0, stream>>>(W1, pW1, F, H, 128, tot1);
    pack_w_kernel<<<cdiv_i(tot2, 256), 256, 0, stream>>>(W2, pW2, H, H, 128, tot2);
    pack_w_kernel<<<cdiv_i(tot3, 256), 256, 0, stream>>>(W3, pW3, H, C, 64, tot3);

    const int aggGridH = cdiv_i(N, 4);

    // ---- layer 1: h1 = elu(A_hat @ (x @ W1) + b1)
    pack_a_kernel<<<dim3(F / 32, Mt), 256, 0, stream>>>(x, as, N, F);
    gemm_mfma_kernel<128><<<dim3(H / 128, Mt), 256, 0, stream>>>(as, pW1, th, N, F, H);
    agg_pull_kernel<4, 0><<<aggGridH, 256, 0, stream>>>(row_ptr, col, dinv, th, b1,
                                                        nullptr, h1, N, H);

    // ---- layer 2: h2 = elu(A_hat @ (h1 @ W2) + b2 + h1)
    pack_a_kernel<<<dim3(H / 32, Mt), 256, 0, stream>>>(h1, as, N, H);
    gemm_mfma_kernel<128><<<dim3(H / 128, Mt), 256, 0, stream>>>(as, pW2, th, N, H, H);
    agg_pull_kernel<4, 1><<<aggGridH, 256, 0, stream>>>(row_ptr, col, dinv, th, b2,
                                                        h1, h2, N, H);

    // ---- layer 3: out = A_hat @ (h2 @ W3) + b3
    pack_a_kernel<<<dim3(H / 32, Mt), 256, 0, stream>>>(h2, as, N, H);
    gemm_mfma_kernel<64><<<dim3(C / 64, Mt), 256, 0, stream>>>(as, pW3, th, N, H, C);
    agg_pull_kernel<1, 2><<<aggGridH, 256, 0, stream>>>(row_ptr, col, dinv, th, b3,
                                                        nullptr, out, N, C);
}

// Round 7
// 395.376 us; speedup vs baseline: 1.8798x; 1.1281x over previous
//
#include <hip/hip_runtime.h>
#include <cstdint>
#include <cstddef>

// ---------------------------------------------------------------------------
// GCN: 3 layers.  out = A_hat @ (h @ W) + b, A_hat = D^-1/2 (A+I) D^-1/2
// R6: pack_a deleted -- GEMM stages fp32 A via per-lane-source global_load_lds
//     (DMA does the fragment permutation), splits to fp16 hi/lo in-loop.
//     agg H-layers unrolled 8-deep; layer-3 agg uses 2-edges-per-wave half2.
// ---------------------------------------------------------------------------

static inline int cdiv_i(long a, long b) { return (int)((a + b - 1) / b); }

using half2v = __attribute__((ext_vector_type(2))) _Float16;
using half4v = __attribute__((ext_vector_type(4))) _Float16;
using half8 = __attribute__((ext_vector_type(8))) _Float16;
using f32x4 = __attribute__((ext_vector_type(4))) float;

__device__ __forceinline__ void gload_lds16(const void* g, void* l) {
    __builtin_amdgcn_global_load_lds(
        (const __attribute__((address_space(1))) unsigned int*)g,
        (__attribute__((address_space(3))) unsigned int*)l, 16, 0, 0);
}

__global__ void detect_fmt_kernel(const unsigned int* __restrict__ raw, int n_nodes,
                                  int* __restrict__ flag) {
    if (blockIdx.x == 0 && threadIdx.x == 0) {
        int is64 = 1;
        for (int i = 0; i < 64; ++i) {
            unsigned lo = raw[2 * i], hi = raw[2 * i + 1];
            if (hi != 0u || lo >= (unsigned)n_nodes) { is64 = 0; break; }
        }
        *flag = is64;
    }
}

__global__ void edges_to_i32_kernel(const void* __restrict__ raw, int* __restrict__ out,
                                    int twoE, const int* __restrict__ flag) {
    const int f = *flag;
    for (long i = blockIdx.x * (long)blockDim.x + threadIdx.x; i < twoE;
         i += (long)gridDim.x * blockDim.x) {
        out[i] = f ? (int)(((const long long*)raw)[i]) : ((const int*)raw)[i];
    }
}

__global__ void zero_i32_kernel(int* __restrict__ p, int n) {
    for (long i = blockIdx.x * (long)blockDim.x + threadIdx.x; i < n;
         i += (long)gridDim.x * blockDim.x)
        p[i] = 0;
}

__global__ void hist_kernel(const int* __restrict__ dst, int* __restrict__ cnt, int E) {
    for (long i = blockIdx.x * (long)blockDim.x + threadIdx.x; i < E;
         i += (long)gridDim.x * blockDim.x)
        atomicAdd(&cnt[dst[i]], 1);
}

__global__ void dinv_kernel(const int* __restrict__ cnt, float* __restrict__ dinv, int n) {
    for (long i = blockIdx.x * (long)blockDim.x + threadIdx.x; i < n;
         i += (long)gridDim.x * blockDim.x)
        dinv[i] = rsqrtf((float)cnt[i] + 1.0f);  // +1 self-loop
}

// ---- exclusive scan over n ints: 1024 elems / block ----
__global__ __launch_bounds__(256) void scan1_kernel(const int* __restrict__ in,
                                                    int* __restrict__ out,
                                                    int* __restrict__ bsum, int n) {
    __shared__ int tsum[256];
    const int tid = threadIdx.x;
    const long base = (long)blockIdx.x * 1024 + (long)tid * 4;
    int v[4];
#pragma unroll
    for (int i = 0; i < 4; ++i) v[i] = (base + i < n) ? in[base + i] : 0;
    const int s = v[0] + v[1] + v[2] + v[3];
    tsum[tid] = s;
    __syncthreads();
    for (int off = 1; off < 256; off <<= 1) {
        int add = (tid >= off) ? tsum[tid - off] : 0;
        __syncthreads();
        tsum[tid] += add;
        __syncthreads();
    }
    int run = tsum[tid] - s;
#pragma unroll
    for (int i = 0; i < 4; ++i) {
        if (base + i < n) out[base + i] = run;
        run += v[i];
    }
    if (tid == 255) bsum[blockIdx.x] = tsum[255];
}

__global__ void scan2_kernel(int* __restrict__ bsum, int nb) {
    __shared__ int lds[256];
    const int tid = threadIdx.x;
    int v = (tid < nb) ? bsum[tid] : 0;
    lds[tid] = v;
    __syncthreads();
    for (int off = 1; off < 256; off <<= 1) {
        int add = (tid >= off) ? lds[tid - off] : 0;
        __syncthreads();
        lds[tid] += add;
        __syncthreads();
    }
    if (tid < nb) bsum[tid] = lds[tid] - v;
}

__global__ __launch_bounds__(256) void scan3_kernel(int* __restrict__ out,
                                                    const int* __restrict__ bsum, int n) {
    const long base = (long)blockIdx.x * 1024 + (long)threadIdx.x * 4;
    const int add = bsum[blockIdx.x];
#pragma unroll
    for (int i = 0; i < 4; ++i)
        if (base + i < n) out[base + i] += add;
}

__global__ void set_int_kernel(int* __restrict__ p, int idx, int val) {
    if (blockIdx.x == 0 && threadIdx.x == 0) p[idx] = val;
}

__global__ void scatter_kernel(const int* __restrict__ src, const int* __restrict__ dst,
                               const int* __restrict__ row_ptr, int* __restrict__ fill,
                               int* __restrict__ col, int E) {
    for (long i = blockIdx.x * (long)blockDim.x + threadIdx.x; i < E;
         i += (long)gridDim.x * blockDim.x) {
        int d = dst[i];
        int p = row_ptr[d] + atomicAdd(&fill[d], 1);
        col[p] = src[i];
    }
}

__device__ __forceinline__ void split8f(const float v[8], half8& hi, half8& lo) {
#pragma unroll
    for (int j = 0; j < 8; ++j) {
        _Float16 h = (_Float16)v[j];
        hi[j] = h;
        lo[j] = (_Float16)((v[j] - (float)h) * 4096.0f);
    }
}

// ---------------------------------------------------------------------------
// Pack W (fp32 [K][Nn]) into fragment-major fp16 hi/lo.
// Per (nt, ks) chunk: [split(2)][colgrp(BN/16)][lane(64)][8 halfs]
// lane l -> col = nt*BN + cg*16 + (l&15), k = ks*32 + (l>>4)*8 + j
// ---------------------------------------------------------------------------
__global__ void pack_w_kernel(const float* __restrict__ W, _Float16* __restrict__ P,
                              int K, int Nn, int BN, int total) {
    int id = blockIdx.x * 256 + threadIdx.x;
    if (id >= total) return;
    const int CG = BN / 16, KS = K >> 5;
    const int l = id & 63;
    int r = id >> 6;
    const int cg = r % CG; r /= CG;
    const int ks = r % KS;
    const int nt = r / KS;
    const int c = nt * BN + cg * 16 + (l & 15);
    const int kb = ks * 32 + (l >> 4) * 8;
    const size_t CHUNK = (size_t)2 * CG * 64 * 8;
    _Float16* base = P + (size_t)(nt * KS + ks) * CHUNK + (size_t)(cg * 64 + l) * 8;
    float v[8];
#pragma unroll
    for (int j = 0; j < 8; ++j) v[j] = W[(size_t)(kb + j) * Nn + c];
    half8 hi, lo;
    split8f(v, hi, lo);
    *(half8*)base = hi;
    *(half8*)(base + CHUNK / 2) = lo;
}

// ---------------------------------------------------------------------------
// Ch[M,Nn](fp16) = A[M,K](fp32) @ Bpacked, split-fp16 MFMA.
// BM=64, BN in {128,64}, BK=32, 256 threads = 4 waves.
// A staged via per-lane-source global_load_lds into fragment-permuted LDS
// (slot (rg,h,lane) <- A[bm+rg*16+(lane&15)][ks*32+(lane>>4)*8+h*4], 16B),
// then split to fp16 hi/lo in registers. B as in R5 (packed, linear DMA).
// ---------------------------------------------------------------------------
template <int BN>
__global__ __launch_bounds__(256) void gemm_mfma_kernel(
    const float* __restrict__ A, const _Float16* __restrict__ Bp,
    _Float16* __restrict__ Ch, int M, int K, int Nn,
    const float* __restrict__ zbuf) {
    constexpr int WC = BN / 64;              // wave cols: 2 or 1
    constexpr int WR = 4 / WC;               // wave rows: 2 or 4
    constexpr int MI = 64 / (WR * 16);       // 2 or 1
    constexpr int NI = 4;
    constexpr int BCH = 2 * (BN / 16) * 64 * 8;  // halfs per B chunk
    constexpr int BU = BCH / 2048;           // 1KB units per wave (4 or 2)
    constexpr int ABYTES = 8192;             // 64x32 fp32
    constexpr int SMB = (ABYTES + BCH * 2 > 64 * BN * 2) ? (ABYTES + BCH * 2)
                                                         : (64 * BN * 2);

    __shared__ __align__(16) char smraw[SMB];
    float* smA32 = (float*)smraw;
    _Float16* smB = (_Float16*)(smraw + ABYTES);

    const int tid = threadIdx.x;
    const int lane = tid & 63;
    const int wid = __builtin_amdgcn_readfirstlane(tid >> 6);
    const int wr = wid / WC, wc = wid % WC;
    const int bm = blockIdx.y * 64, bn = blockIdx.x * BN;
    const int KS = K >> 5;
    const _Float16* bchunk = Bp + (size_t)blockIdx.x * KS * BCH;

    // A stage source (two 16B slots per thread): slot s=tid and s=tid+256.
    // s -> l=s&63, rgh=s>>6 (wave-uniform), row=(rgh>>1)*16+(l&15),
    //      k-quad=(l>>4)*8+(rgh&1)*4
    const int r1 = ((tid >> 6) >> 1) * 16 + (lane & 15);
    const int kq1 = ((lane >> 4) << 3) + (((tid >> 6) & 1) << 2);
    const int gm1 = bm + r1;
    const int gm2 = gm1 + 32;  // slot2: rgh+4 -> row+32, same k-quad
    const float* base1 = (gm1 < M) ? (A + (size_t)gm1 * K + kq1) : nullptr;
    const float* base2 = (gm2 < M) ? (A + (size_t)gm2 * K + kq1) : nullptr;

    f32x4 acc1[MI][NI] = {};
    f32x4 acc2[MI][NI] = {};

    for (int ks = 0; ks < KS; ++ks) {
        if (ks) __syncthreads();  // prior iteration's LDS reads complete
        const int ko = ks * 32;
        gload_lds16(base1 ? (const void*)(base1 + ko) : (const void*)zbuf,
                    smraw + wid * 1024);
        gload_lds16(base2 ? (const void*)(base2 + ko) : (const void*)zbuf,
                    smraw + (wid + 4) * 1024);
        const _Float16* bc = bchunk + (size_t)ks * BCH;
#pragma unroll
        for (int rr = 0; rr < BU; ++rr)
            gload_lds16(bc + (size_t)(((wid * BU + rr) * 64 + lane) << 3),
                        smB + ((wid * BU + rr) << 9));
        __syncthreads();  // vmcnt drained by compiler before barrier

        half8 afh[MI], afl[MI];
#pragma unroll
        for (int mi = 0; mi < MI; ++mi) {
            const int rg = wr * MI + mi;
            f32x4 vlo = *(const f32x4*)(smA32 + (((rg * 2 + 0) * 64 + lane) << 2));
            f32x4 vhi = *(const f32x4*)(smA32 + (((rg * 2 + 1) * 64 + lane) << 2));
            float v[8] = {vlo[0], vlo[1], vlo[2], vlo[3],
                          vhi[0], vhi[1], vhi[2], vhi[3]};
            split8f(v, afh[mi], afl[mi]);
        }
#pragma unroll
        for (int ni = 0; ni < NI; ++ni) {
            const half8 bh = *(const half8*)(smB + (((wc * 4 + ni) * 64 + lane) << 3));
            const half8 bl = *(const half8*)(smB + BCH / 2 + (((wc * 4 + ni) * 64 + lane) << 3));
#pragma unroll
            for (int mi = 0; mi < MI; ++mi) {
                acc1[mi][ni] = __builtin_amdgcn_mfma_f32_16x16x32_f16(
                    afh[mi], bh, acc1[mi][ni], 0, 0, 0);
                acc2[mi][ni] = __builtin_amdgcn_mfma_f32_16x16x32_f16(
                    afl[mi], bh, acc2[mi][ni], 0, 0, 0);
                acc2[mi][ni] = __builtin_amdgcn_mfma_f32_16x16x32_f16(
                    afh[mi], bl, acc2[mi][ni], 0, 0, 0);
            }
        }
    }

    // ---- epilogue: stage fp16 tile in LDS, store full coalesced lines ----
    __syncthreads();
    _Float16* smC = (_Float16*)smraw;
    const float inv = 1.0f / 4096.0f;
#pragma unroll
    for (int mi = 0; mi < MI; ++mi) {
#pragma unroll
        for (int ni = 0; ni < NI; ++ni) {
            const int row0 = wr * (MI * 16) + mi * 16 + ((lane >> 4) << 2);
            const int colx = wc * 64 + ni * 16 + (lane & 15);
#pragma unroll
            for (int i = 0; i < 4; ++i)
                smC[(row0 + i) * BN + colx] =
                    (_Float16)(acc1[mi][ni][i] + acc2[mi][ni][i] * inv);
        }
    }
    __syncthreads();
    constexpr int UPR = BN / 8;  // 16B units per row
#pragma unroll
    for (int r = 0; r < BN / 32; ++r) {
        const int u = r * 256 + tid;
        const int row = u / UPR, cu = u % UPR;
        const int grow = bm + row;
        if (grow < M)
            *(uint4*)(Ch + (size_t)grow * Nn + bn + cu * 8) =
                *(const uint4*)(smC + row * BN + cu * 8);
    }
}

__device__ __forceinline__ float elu1(float v) { return v > 0.f ? v : expm1f(v); }

// Pull aggregation over fp16 t (Hdim = 256 = 64 lanes x 4), one wave/node,
// 8-way unrolled gathers.  MODE 0: y=elu(conv)  MODE 1: y=elu(conv+res)
template <int MODE>
__global__ __launch_bounds__(256) void agg_pull_kernel(
    const int* __restrict__ row_ptr, const int* __restrict__ col,
    const float* __restrict__ dinv, const _Float16* __restrict__ t,
    const float* __restrict__ bias, const float* __restrict__ res,
    float* __restrict__ y, int Nn, int Hdim) {
    const int node = blockIdx.x * (blockDim.x >> 6) + (threadIdx.x >> 6);
    if (node >= Nn) return;
    const int lane = threadIdx.x & 63;
    const int f = lane * 4;

    float acc[4] = {0.f, 0.f, 0.f, 0.f};

    const int s0 = row_ptr[node], s1 = row_ptr[node + 1];
    int e = s0;
    for (; e + 7 < s1; e += 8) {
        int ss[8];
        float w[8];
        half4v v[8];
#pragma unroll
        for (int u = 0; u < 8; ++u) ss[u] = col[e + u];
#pragma unroll
        for (int u = 0; u < 8; ++u) w[u] = dinv[ss[u]];
#pragma unroll
        for (int u = 0; u < 8; ++u)
            v[u] = *(const half4v*)(t + (size_t)ss[u] * Hdim + f);
#pragma unroll
        for (int u = 0; u < 8; ++u)
#pragma unroll
            for (int i = 0; i < 4; ++i)
                acc[i] = fmaf((float)v[u][i], w[u], acc[i]);
    }
    for (; e < s1; ++e) {
        const int s = col[e];
        const float w = dinv[s];
        const half4v v = *(const half4v*)(t + (size_t)s * Hdim + f);
#pragma unroll
        for (int i = 0; i < 4; ++i) acc[i] = fmaf((float)v[i], w, acc[i]);
    }

    const float dn = dinv[node];
    const half4v tn = *(const half4v*)(t + (size_t)node * Hdim + f);
    float o[4];
#pragma unroll
    for (int i = 0; i < 4; ++i)
        o[i] = (acc[i] + (float)tn[i] * dn) * dn + bias[f + i];

    if (MODE == 1) {
        const float* rn = res + (size_t)node * Hdim + f;
#pragma unroll
        for (int i = 0; i < 4; ++i) o[i] += rn[i];
    }
#pragma unroll
    for (int i = 0; i < 4; ++i) o[i] = elu1(o[i]);

    *(float4*)(y + (size_t)node * Hdim + f) = make_float4(o[0], o[1], o[2], o[3]);
}

// Layer-3 aggregation: Cdim=64 fp16 t, one wave/node, 2 edges per iteration
// (lane>>5 selects edge), 4-way unrolled, cross-half shfl reduce. y=conv+b.
__global__ __launch_bounds__(256) void agg_pull64_kernel(
    const int* __restrict__ row_ptr, const int* __restrict__ col,
    const float* __restrict__ dinv, const _Float16* __restrict__ t,
    const float* __restrict__ bias, float* __restrict__ y, int Nn) {
    const int node = blockIdx.x * (blockDim.x >> 6) + (threadIdx.x >> 6);
    if (node >= Nn) return;
    const int lane = threadIdx.x & 63;
    const int sub = lane >> 5;
    const int f = (lane & 31) * 2;

    float acc0 = 0.f, acc1 = 0.f;
    const int s0 = row_ptr[node], s1 = row_ptr[node + 1];
    int e = s0 + sub;
    for (; e + 6 < s1; e += 8) {
        int ss[4];
        float w[4];
        half2v v[4];
#pragma unroll
        for (int u = 0; u < 4; ++u) ss[u] = col[e + 2 * u];
#pragma unroll
        for (int u = 0; u < 4; ++u) w[u] = dinv[ss[u]];
#pragma unroll
        for (int u = 0; u < 4; ++u)
            v[u] = *(const half2v*)(t + (size_t)ss[u] * 64 + f);
#pragma unroll
        for (int u = 0; u < 4; ++u) {
            acc0 = fmaf((float)v[u][0], w[u], acc0);
            acc1 = fmaf((float)v[u][1], w[u], acc1);
        }
    }
    for (; e < s1; e += 2) {
        const int s = col[e];
        const float w = dinv[s];
        const half2v v = *(const half2v*)(t + (size_t)s * 64 + f);
        acc0 = fmaf((float)v[0], w, acc0);
        acc1 = fmaf((float)v[1], w, acc1);
    }

    acc0 += __shfl_xor(acc0, 32);
    acc1 += __shfl_xor(acc1, 32);

    const float dn = dinv[node];
    const half2v tn = *(const half2v*)(t + (size_t)node * 64 + f);
    const float o0 = (acc0 + (float)tn[0] * dn) * dn + bias[f];
    const float o1 = (acc1 + (float)tn[1] * dn) * dn + bias[f + 1];

    if (lane < 32) {
        float2 ov = make_float2(o0, o1);
        *(float2*)(y + (size_t)node * 64 + f) = ov;
    }
}

extern "C" void kernel_launch(void* const* d_in, const int* in_sizes, int n_in,
                              void* d_out, int out_size, void* d_ws, size_t ws_size,
                              hipStream_t stream) {
    const float* x = (const float*)d_in[0];
    const void* ei_raw = d_in[1];
    const float* W1 = (const float*)d_in[2];
    const float* b1 = (const float*)d_in[3];
    const float* W2 = (const float*)d_in[4];
    const float* b2 = (const float*)d_in[5];
    const float* W3 = (const float*)d_in[6];
    const float* b3 = (const float*)d_in[7];
    float* out = (float*)d_out;

    const int H = in_sizes[3];       // 256
    const int F = in_sizes[2] / H;   // 512
    const int N = in_sizes[0] / F;   // 50000
    const int C = in_sizes[7];       // 64
    const int E = in_sizes[1] / 2;   // 800000
    const int Mt = cdiv_i(N, 64);    // 782 row tiles

    // workspace layout
    char* ws = (char*)d_ws;
    size_t off = 0;
    auto take = [&](size_t bytes) -> char* {
        char* p = ws + off;
        off += (bytes + 255) & ~(size_t)255;
        return p;
    };
    float* dinv = (float*)take((size_t)N * 4);
    int* flag = (int*)take(4);
    float* zbuf = (float*)take(64);
    _Float16* th = (_Float16*)take((size_t)N * H * 2);   // GEMM output (fp16)
    float* h1 = (float*)take((size_t)N * H * 4);
    float* h2 = (float*)take((size_t)N * H * 4);
    int* e32 = (int*)take((size_t)2 * E * 4);
    int* srcI = e32;
    int* dstI = e32 + E;
    int* col = (int*)take((size_t)E * 4);
    int* cnt = (int*)take((size_t)N * 4);
    int* row_ptr = (int*)take((size_t)(N + 1) * 4);
    int* fill = (int*)take((size_t)N * 4);
    int* bsum = (int*)take(256 * 4);
    _Float16* pW1 = (_Float16*)take((size_t)F * H * 2 * 2);
    _Float16* pW2 = (_Float16*)take((size_t)H * H * 2 * 2);
    _Float16* pW3 = (_Float16*)take((size_t)H * C * 2 * 2);
    (void)ws_size; (void)n_in; (void)out_size;

    const int nScanBlk = cdiv_i(N, 1024);

    // ---- edges + degrees + CSR (+ zero page for GEMM OOB rows) ----
    detect_fmt_kernel<<<1, 64, 0, stream>>>((const unsigned*)ei_raw, N, flag);
    edges_to_i32_kernel<<<cdiv_i(2L * E, 256), 256, 0, stream>>>(ei_raw, e32, 2 * E, flag);
    zero_i32_kernel<<<1, 64, 0, stream>>>((int*)zbuf, 16);
    zero_i32_kernel<<<cdiv_i(N, 256), 256, 0, stream>>>(cnt, N);
    hist_kernel<<<cdiv_i(E, 256), 256, 0, stream>>>(dstI, cnt, E);
    dinv_kernel<<<cdiv_i(N, 256), 256, 0, stream>>>(cnt, dinv, N);
    scan1_kernel<<<nScanBlk, 256, 0, stream>>>(cnt, row_ptr, bsum, N);
    scan2_kernel<<<1, 256, 0, stream>>>(bsum, nScanBlk);
    scan3_kernel<<<nScanBlk, 256, 0, stream>>>(row_ptr, bsum, N);
    set_int_kernel<<<1, 1, 0, stream>>>(row_ptr, N, E);
    zero_i32_kernel<<<cdiv_i(N, 256), 256, 0, stream>>>(fill, N);
    scatter_kernel<<<cdiv_i(E, 256), 256, 0, stream>>>(srcI, dstI, row_ptr, fill, col, E);

    // ---- pack weights (fragment-major fp16 hi/lo) ----
    const int tot1 = (H / 128) * (F / 32) * (128 / 16) * 64;
    const int tot2 = (H / 128) * (H / 32) * (128 / 16) * 64;
    const int tot3 = (C / 64) * (H / 32) * (64 / 16) * 64;
    pack_w_kernel<<<cdiv_i(tot1, 256), 256, 0, stream>>>(W1, pW1, F, H, 128, tot1);
    pack_w_kernel<<<cdiv_i(tot2, 256), 256, 0, stream>>>(W2, pW2, H, H, 128, tot2);
    pack_w_kernel<<<cdiv_i(tot3, 256), 256, 0, stream>>>(W3, pW3, H, C, 64, tot3);

    const int aggGridH = cdiv_i(N, 4);

    // ---- layer 1: h1 = elu(A_hat @ (x @ W1) + b1)
    gemm_mfma_kernel<128><<<dim3(H / 128, Mt), 256, 0, stream>>>(x, pW1, th, N, F, H, zbuf);
    agg_pull_kernel<0><<<aggGridH, 256, 0, stream>>>(row_ptr, col, dinv, th, b1,
                                                     nullptr, h1, N, H);

    // ---- layer 2: h2 = elu(A_hat @ (h1 @ W2) + b2 + h1)
    gemm_mfma_kernel<128><<<dim3(H / 128, Mt), 256, 0, stream>>>(h1, pW2, th, N, H, H, zbuf);
    agg_pull_kernel<1><<<aggGridH, 256, 0, stream>>>(row_ptr, col, dinv, th, b2,
                                                     h1, h2, N, H);

    // ---- layer 3: out = A_hat @ (h2 @ W3) + b3
    gemm_mfma_kernel<64><<<dim3(C / 64, Mt), 256, 0, stream>>>(h2, pW3, th, N, H, C, zbuf);
    agg_pull64_kernel<<<aggGridH, 256, 0, stream>>>(row_ptr, col, dinv, th, b3, out, N);
}

// Round 8
// 381.425 us; speedup vs baseline: 1.9486x; 1.0366x over previous
//
#include <hip/hip_runtime.h>
#include <cstdint>
#include <cstddef>

// ---------------------------------------------------------------------------
// GCN: 3 layers.  out = A_hat @ (h @ W) + b, A_hat = D^-1/2 (A+I) D^-1/2
// R7: GEMM k-loop double-buffered (stage next tile before compute, single
//     raw s_barrier + vmcnt(0) per step -- loads fly across compute phase).
//     agg H-layers: 32-lane half8 rows, 2 edges/wave-iter, 4-pair unroll.
// ---------------------------------------------------------------------------

static inline int cdiv_i(long a, long b) { return (int)((a + b - 1) / b); }

using half2v = __attribute__((ext_vector_type(2))) _Float16;
using half8 = __attribute__((ext_vector_type(8))) _Float16;
using f32x4 = __attribute__((ext_vector_type(4))) float;

__device__ __forceinline__ void gload_lds16(const void* g, void* l) {
    __builtin_amdgcn_global_load_lds(
        (const __attribute__((address_space(1))) unsigned int*)g,
        (__attribute__((address_space(3))) unsigned int*)l, 16, 0, 0);
}

__global__ void detect_fmt_kernel(const unsigned int* __restrict__ raw, int n_nodes,
                                  int* __restrict__ flag) {
    if (blockIdx.x == 0 && threadIdx.x == 0) {
        int is64 = 1;
        for (int i = 0; i < 64; ++i) {
            unsigned lo = raw[2 * i], hi = raw[2 * i + 1];
            if (hi != 0u || lo >= (unsigned)n_nodes) { is64 = 0; break; }
        }
        *flag = is64;
    }
}

__global__ void edges_to_i32_kernel(const void* __restrict__ raw, int* __restrict__ out,
                                    int twoE, const int* __restrict__ flag) {
    const int f = *flag;
    for (long i = blockIdx.x * (long)blockDim.x + threadIdx.x; i < twoE;
         i += (long)gridDim.x * blockDim.x) {
        out[i] = f ? (int)(((const long long*)raw)[i]) : ((const int*)raw)[i];
    }
}

__global__ void zero_i32_kernel(int* __restrict__ p, int n) {
    for (long i = blockIdx.x * (long)blockDim.x + threadIdx.x; i < n;
         i += (long)gridDim.x * blockDim.x)
        p[i] = 0;
}

__global__ void hist_kernel(const int* __restrict__ dst, int* __restrict__ cnt, int E) {
    for (long i = blockIdx.x * (long)blockDim.x + threadIdx.x; i < E;
         i += (long)gridDim.x * blockDim.x)
        atomicAdd(&cnt[dst[i]], 1);
}

__global__ void dinv_kernel(const int* __restrict__ cnt, float* __restrict__ dinv, int n) {
    for (long i = blockIdx.x * (long)blockDim.x + threadIdx.x; i < n;
         i += (long)gridDim.x * blockDim.x)
        dinv[i] = rsqrtf((float)cnt[i] + 1.0f);  // +1 self-loop
}

// ---- exclusive scan over n ints: 1024 elems / block ----
__global__ __launch_bounds__(256) void scan1_kernel(const int* __restrict__ in,
                                                    int* __restrict__ out,
                                                    int* __restrict__ bsum, int n) {
    __shared__ int tsum[256];
    const int tid = threadIdx.x;
    const long base = (long)blockIdx.x * 1024 + (long)tid * 4;
    int v[4];
#pragma unroll
    for (int i = 0; i < 4; ++i) v[i] = (base + i < n) ? in[base + i] : 0;
    const int s = v[0] + v[1] + v[2] + v[3];
    tsum[tid] = s;
    __syncthreads();
    for (int off = 1; off < 256; off <<= 1) {
        int add = (tid >= off) ? tsum[tid - off] : 0;
        __syncthreads();
        tsum[tid] += add;
        __syncthreads();
    }
    int run = tsum[tid] - s;
#pragma unroll
    for (int i = 0; i < 4; ++i) {
        if (base + i < n) out[base + i] = run;
        run += v[i];
    }
    if (tid == 255) bsum[blockIdx.x] = tsum[255];
}

__global__ void scan2_kernel(int* __restrict__ bsum, int nb) {
    __shared__ int lds[256];
    const int tid = threadIdx.x;
    int v = (tid < nb) ? bsum[tid] : 0;
    lds[tid] = v;
    __syncthreads();
    for (int off = 1; off < 256; off <<= 1) {
        int add = (tid >= off) ? lds[tid - off] : 0;
        __syncthreads();
        lds[tid] += add;
        __syncthreads();
    }
    if (tid < nb) bsum[tid] = lds[tid] - v;
}

__global__ __launch_bounds__(256) void scan3_kernel(int* __restrict__ out,
                                                    const int* __restrict__ bsum, int n) {
    const long base = (long)blockIdx.x * 1024 + (long)threadIdx.x * 4;
    const int add = bsum[blockIdx.x];
#pragma unroll
    for (int i = 0; i < 4; ++i)
        if (base + i < n) out[base + i] += add;
}

__global__ void set_int_kernel(int* __restrict__ p, int idx, int val) {
    if (blockIdx.x == 0 && threadIdx.x == 0) p[idx] = val;
}

__global__ void scatter_kernel(const int* __restrict__ src, const int* __restrict__ dst,
                               const int* __restrict__ row_ptr, int* __restrict__ fill,
                               int* __restrict__ col, int E) {
    for (long i = blockIdx.x * (long)blockDim.x + threadIdx.x; i < E;
         i += (long)gridDim.x * blockDim.x) {
        int d = dst[i];
        int p = row_ptr[d] + atomicAdd(&fill[d], 1);
        col[p] = src[i];
    }
}

__device__ __forceinline__ void split8f(const float v[8], half8& hi, half8& lo) {
#pragma unroll
    for (int j = 0; j < 8; ++j) {
        _Float16 h = (_Float16)v[j];
        hi[j] = h;
        lo[j] = (_Float16)((v[j] - (float)h) * 4096.0f);
    }
}

// ---------------------------------------------------------------------------
// Pack W (fp32 [K][Nn]) into fragment-major fp16 hi/lo.
// Per (nt, ks) chunk: [split(2)][colgrp(BN/16)][lane(64)][8 halfs]
// lane l -> col = nt*BN + cg*16 + (l&15), k = ks*32 + (l>>4)*8 + j
// ---------------------------------------------------------------------------
__global__ void pack_w_kernel(const float* __restrict__ W, _Float16* __restrict__ P,
                              int K, int Nn, int BN, int total) {
    int id = blockIdx.x * 256 + threadIdx.x;
    if (id >= total) return;
    const int CG = BN / 16, KS = K >> 5;
    const int l = id & 63;
    int r = id >> 6;
    const int cg = r % CG; r /= CG;
    const int ks = r % KS;
    const int nt = r / KS;
    const int c = nt * BN + cg * 16 + (l & 15);
    const int kb = ks * 32 + (l >> 4) * 8;
    const size_t CHUNK = (size_t)2 * CG * 64 * 8;
    _Float16* base = P + (size_t)(nt * KS + ks) * CHUNK + (size_t)(cg * 64 + l) * 8;
    float v[8];
#pragma unroll
    for (int j = 0; j < 8; ++j) v[j] = W[(size_t)(kb + j) * Nn + c];
    half8 hi, lo;
    split8f(v, hi, lo);
    *(half8*)base = hi;
    *(half8*)(base + CHUNK / 2) = lo;
}

// ---------------------------------------------------------------------------
// Ch[M,Nn](fp16) = A[M,K](fp32) @ Bpacked, split-fp16 MFMA.
// BM=64, BN in {128,64}, BK=32, 256 threads = 4 waves.
// Double-buffered: stage tile ks+1 (per-lane-source global_load_lds) before
// computing tile ks; ONE raw s_barrier + vmcnt(0) per k-step so staging
// latency hides under the MFMA phase.
// ---------------------------------------------------------------------------
template <int BN>
__global__ __launch_bounds__(256) void gemm_mfma_kernel(
    const float* __restrict__ A, const _Float16* __restrict__ Bp,
    _Float16* __restrict__ Ch, int M, int K, int Nn,
    const float* __restrict__ zbuf) {
    constexpr int WC = BN / 64;              // wave cols: 2 or 1
    constexpr int WR = 4 / WC;               // wave rows: 2 or 4
    constexpr int MI = 64 / (WR * 16);       // 2 or 1
    constexpr int NI = 4;
    constexpr int BCH = 2 * (BN / 16) * 64 * 8;  // halfs per B chunk
    constexpr int BU = BCH / 2048;           // 1KB units per wave (4 or 2)
    constexpr int ABYTES = 8192;             // 64x32 fp32
    constexpr int BUFB = ABYTES + BCH * 2;   // bytes per pipeline buffer
    constexpr int EPIB = 64 * BN * 2;        // epilogue fp16 tile
    constexpr int SMB = (2 * BUFB > EPIB) ? 2 * BUFB : EPIB;

    __shared__ __align__(16) char smraw[SMB];

    const int tid = threadIdx.x;
    const int lane = tid & 63;
    const int wid = __builtin_amdgcn_readfirstlane(tid >> 6);
    const int wr = wid / WC, wc = wid % WC;
    const int bm = blockIdx.y * 64, bn = blockIdx.x * BN;
    const int KS = K >> 5;
    const _Float16* bchunk = Bp + (size_t)blockIdx.x * KS * BCH;

    // A stage source (two 16B slots per thread):
    // slot1: row=(wid>>1)*16+(lane&15), kq=(lane>>4)*8+(wid&1)*4; slot2: row+32
    const int r1 = ((tid >> 6) >> 1) * 16 + (lane & 15);
    const int kq1 = ((lane >> 4) << 3) + (((tid >> 6) & 1) << 2);
    const int gm1 = bm + r1;
    const int gm2 = gm1 + 32;
    const bool ok1 = gm1 < M, ok2 = gm2 < M;
    const float* base1 = ok1 ? (A + (size_t)gm1 * K + kq1) : zbuf;
    const float* base2 = ok2 ? (A + (size_t)gm2 * K + kq1) : zbuf;

    f32x4 acc1[MI][NI] = {};
    f32x4 acc2[MI][NI] = {};

    auto stagef = [&](int buf, int ks) {
        char* sA = smraw + buf * BUFB;
        _Float16* sB = (_Float16*)(sA + ABYTES);
        const int ko = ks * 32;
        gload_lds16(ok1 ? (const void*)(base1 + ko) : (const void*)zbuf,
                    sA + wid * 1024);
        gload_lds16(ok2 ? (const void*)(base2 + ko) : (const void*)zbuf,
                    sA + (wid + 4) * 1024);
        const _Float16* bc = bchunk + (size_t)ks * BCH;
#pragma unroll
        for (int rr = 0; rr < BU; ++rr)
            gload_lds16(bc + (size_t)(((wid * BU + rr) * 64 + lane) << 3),
                        sB + ((wid * BU + rr) << 9));
    };

    stagef(0, 0);
    asm volatile("s_waitcnt vmcnt(0)" ::: "memory");
    __builtin_amdgcn_s_barrier();

    int cur = 0;
    for (int ks = 0; ks < KS; ++ks) {
        if (ks + 1 < KS) stagef(cur ^ 1, ks + 1);  // in flight during compute

        const float* smA32 = (const float*)(smraw + cur * BUFB);
        const _Float16* smB = (const _Float16*)(smraw + cur * BUFB + ABYTES);

        half8 afh[MI], afl[MI];
#pragma unroll
        for (int mi = 0; mi < MI; ++mi) {
            const int rg = wr * MI + mi;
            f32x4 vlo = *(const f32x4*)(smA32 + (((rg * 2 + 0) * 64 + lane) << 2));
            f32x4 vhi = *(const f32x4*)(smA32 + (((rg * 2 + 1) * 64 + lane) << 2));
            float v[8] = {vlo[0], vlo[1], vlo[2], vlo[3],
                          vhi[0], vhi[1], vhi[2], vhi[3]};
            split8f(v, afh[mi], afl[mi]);
        }
#pragma unroll
        for (int ni = 0; ni < NI; ++ni) {
            const half8 bh = *(const half8*)(smB + (((wc * 4 + ni) * 64 + lane) << 3));
            const half8 bl = *(const half8*)(smB + BCH / 2 + (((wc * 4 + ni) * 64 + lane) << 3));
#pragma unroll
            for (int mi = 0; mi < MI; ++mi) {
                acc1[mi][ni] = __builtin_amdgcn_mfma_f32_16x16x32_f16(
                    afh[mi], bh, acc1[mi][ni], 0, 0, 0);
                acc2[mi][ni] = __builtin_amdgcn_mfma_f32_16x16x32_f16(
                    afl[mi], bh, acc2[mi][ni], 0, 0, 0);
                acc2[mi][ni] = __builtin_amdgcn_mfma_f32_16x16x32_f16(
                    afh[mi], bl, acc2[mi][ni], 0, 0, 0);
            }
        }
        asm volatile("s_waitcnt vmcnt(0)" ::: "memory");
        __builtin_amdgcn_s_barrier();
        cur ^= 1;
    }

    // ---- epilogue: stage fp16 tile in LDS, store full coalesced lines ----
    _Float16* smC = (_Float16*)smraw;
    const float inv = 1.0f / 4096.0f;
#pragma unroll
    for (int mi = 0; mi < MI; ++mi) {
#pragma unroll
        for (int ni = 0; ni < NI; ++ni) {
            const int row0 = wr * (MI * 16) + mi * 16 + ((lane >> 4) << 2);
            const int colx = wc * 64 + ni * 16 + (lane & 15);
#pragma unroll
            for (int i = 0; i < 4; ++i)
                smC[(row0 + i) * BN + colx] =
                    (_Float16)(acc1[mi][ni][i] + acc2[mi][ni][i] * inv);
        }
    }
    __syncthreads();
    constexpr int UPR = BN / 8;  // 16B units per row
#pragma unroll
    for (int r = 0; r < BN / 32; ++r) {
        const int u = r * 256 + tid;
        const int row = u / UPR, cu = u % UPR;
        const int grow = bm + row;
        if (grow < M)
            *(uint4*)(Ch + (size_t)grow * Nn + bn + cu * 8) =
                *(const uint4*)(smC + row * BN + cu * 8);
    }
}

__device__ __forceinline__ float elu1(float v) { return v > 0.f ? v : expm1f(v); }

// Pull aggregation over fp16 t (Hdim=256): one wave per node, 32 lanes x
// half8 (16B) per row, 2 edges per wave-iteration, 4-pair unroll.
// MODE 0: y=elu(conv)  MODE 1: y=elu(conv+res)
template <int MODE>
__global__ __launch_bounds__(256) void agg_pull_kernel(
    const int* __restrict__ row_ptr, const int* __restrict__ col,
    const float* __restrict__ dinv, const _Float16* __restrict__ t,
    const float* __restrict__ bias, const float* __restrict__ res,
    float* __restrict__ y, int Nn, int Hdim) {
    const int node = blockIdx.x * (blockDim.x >> 6) + (threadIdx.x >> 6);
    if (node >= Nn) return;
    const int lane = threadIdx.x & 63;
    const int sub = lane >> 5;         // which edge of the pair
    const int f = (lane & 31) * 8;     // feature base (32 lanes x 8 = 256)

    float acc[8] = {0.f, 0.f, 0.f, 0.f, 0.f, 0.f, 0.f, 0.f};

    const int s0 = row_ptr[node], s1 = row_ptr[node + 1];
    int e = s0 + sub;
    for (; e + 7 < s1; e += 8) {
        int ss[4];
        float w[4];
        half8 v[4];
#pragma unroll
        for (int u = 0; u < 4; ++u) ss[u] = col[e + 2 * u];
#pragma unroll
        for (int u = 0; u < 4; ++u) w[u] = dinv[ss[u]];
#pragma unroll
        for (int u = 0; u < 4; ++u)
            v[u] = *(const half8*)(t + (size_t)ss[u] * Hdim + f);
#pragma unroll
        for (int u = 0; u < 4; ++u)
#pragma unroll
            for (int i = 0; i < 8; ++i)
                acc[i] = fmaf((float)v[u][i], w[u], acc[i]);
    }
    for (; e < s1; e += 2) {
        const int s = col[e];
        const float w = dinv[s];
        const half8 v = *(const half8*)(t + (size_t)s * Hdim + f);
#pragma unroll
        for (int i = 0; i < 8; ++i) acc[i] = fmaf((float)v[i], w, acc[i]);
    }

#pragma unroll
    for (int i = 0; i < 8; ++i) acc[i] += __shfl_xor(acc[i], 32);

    if (sub == 0) {
        const float dn = dinv[node];
        const half8 tn = *(const half8*)(t + (size_t)node * Hdim + f);
        float o[8];
#pragma unroll
        for (int i = 0; i < 8; ++i)
            o[i] = (acc[i] + (float)tn[i] * dn) * dn + bias[f + i];
        if (MODE == 1) {
            const float4 r0 = *(const float4*)(res + (size_t)node * Hdim + f);
            const float4 r1 = *(const float4*)(res + (size_t)node * Hdim + f + 4);
            o[0] += r0.x; o[1] += r0.y; o[2] += r0.z; o[3] += r0.w;
            o[4] += r1.x; o[5] += r1.y; o[6] += r1.z; o[7] += r1.w;
        }
#pragma unroll
        for (int i = 0; i < 8; ++i) o[i] = elu1(o[i]);
        float* yn = y + (size_t)node * Hdim + f;
        *(float4*)yn = make_float4(o[0], o[1], o[2], o[3]);
        *(float4*)(yn + 4) = make_float4(o[4], o[5], o[6], o[7]);
    }
}

// Layer-3 aggregation: Cdim=64 fp16 t, one wave/node, 2 edges per iteration
// (lane>>5 selects edge), 4-way unrolled, cross-half shfl reduce. y=conv+b.
__global__ __launch_bounds__(256) void agg_pull64_kernel(
    const int* __restrict__ row_ptr, const int* __restrict__ col,
    const float* __restrict__ dinv, const _Float16* __restrict__ t,
    const float* __restrict__ bias, float* __restrict__ y, int Nn) {
    const int node = blockIdx.x * (blockDim.x >> 6) + (threadIdx.x >> 6);
    if (node >= Nn) return;
    const int lane = threadIdx.x & 63;
    const int sub = lane >> 5;
    const int f = (lane & 31) * 2;

    float acc0 = 0.f, acc1 = 0.f;
    const int s0 = row_ptr[node], s1 = row_ptr[node + 1];
    int e = s0 + sub;
    for (; e + 6 < s1; e += 8) {
        int ss[4];
        float w[4];
        half2v v[4];
#pragma unroll
        for (int u = 0; u < 4; ++u) ss[u] = col[e + 2 * u];
#pragma unroll
        for (int u = 0; u < 4; ++u) w[u] = dinv[ss[u]];
#pragma unroll
        for (int u = 0; u < 4; ++u)
            v[u] = *(const half2v*)(t + (size_t)ss[u] * 64 + f);
#pragma unroll
        for (int u = 0; u < 4; ++u) {
            acc0 = fmaf((float)v[u][0], w[u], acc0);
            acc1 = fmaf((float)v[u][1], w[u], acc1);
        }
    }
    for (; e < s1; e += 2) {
        const int s = col[e];
        const float w = dinv[s];
        const half2v v = *(const half2v*)(t + (size_t)s * 64 + f);
        acc0 = fmaf((float)v[0], w, acc0);
        acc1 = fmaf((float)v[1], w, acc1);
    }

    acc0 += __shfl_xor(acc0, 32);
    acc1 += __shfl_xor(acc1, 32);

    const float dn = dinv[node];
    const half2v tn = *(const half2v*)(t + (size_t)node * 64 + f);
    const float o0 = (acc0 + (float)tn[0] * dn) * dn + bias[f];
    const float o1 = (acc1 + (float)tn[1] * dn) * dn + bias[f + 1];

    if (lane < 32) {
        float2 ov = make_float2(o0, o1);
        *(float2*)(y + (size_t)node * 64 + f) = ov;
    }
}

extern "C" void kernel_launch(void* const* d_in, const int* in_sizes, int n_in,
                              void* d_out, int out_size, void* d_ws, size_t ws_size,
                              hipStream_t stream) {
    const float* x = (const float*)d_in[0];
    const void* ei_raw = d_in[1];
    const float* W1 = (const float*)d_in[2];
    const float* b1 = (const float*)d_in[3];
    const float* W2 = (const float*)d_in[4];
    const float* b2 = (const float*)d_in[5];
    const float* W3 = (const float*)d_in[6];
    const float* b3 = (const float*)d_in[7];
    float* out = (float*)d_out;

    const int H = in_sizes[3];       // 256
    const int F = in_sizes[2] / H;   // 512
    const int N = in_sizes[0] / F;   // 50000
    const int C = in_sizes[7];       // 64
    const int E = in_sizes[1] / 2;   // 800000
    const int Mt = cdiv_i(N, 64);    // 782 row tiles

    // workspace layout
    char* ws = (char*)d_ws;
    size_t off = 0;
    auto take = [&](size_t bytes) -> char* {
        char* p = ws + off;
        off += (bytes + 255) & ~(size_t)255;
        return p;
    };
    float* dinv = (float*)take((size_t)N * 4);
    int* flag = (int*)take(4);
    float* zbuf = (float*)take(64);
    _Float16* th = (_Float16*)take((size_t)N * H * 2);   // GEMM output (fp16)
    float* h1 = (float*)take((size_t)N * H * 4);
    float* h2 = (float*)take((size_t)N * H * 4);
    int* e32 = (int*)take((size_t)2 * E * 4);
    int* srcI = e32;
    int* dstI = e32 + E;
    int* col = (int*)take((size_t)E * 4);
    int* cnt = (int*)take((size_t)N * 4);
    int* row_ptr = (int*)take((size_t)(N + 1) * 4);
    int* fill = (int*)take((size_t)N * 4);
    int* bsum = (int*)take(256 * 4);
    _Float16* pW1 = (_Float16*)take((size_t)F * H * 2 * 2);
    _Float16* pW2 = (_Float16*)take((size_t)H * H * 2 * 2);
    _Float16* pW3 = (_Float16*)take((size_t)H * C * 2 * 2);
    (void)ws_size; (void)n_in; (void)out_size;

    const int nScanBlk = cdiv_i(N, 1024);

    // ---- edges + degrees + CSR (+ zero page for GEMM OOB rows) ----
    detect_fmt_kernel<<<1, 64, 0, stream>>>((const unsigned*)ei_raw, N, flag);
    edges_to_i32_kernel<<<cdiv_i(2L * E, 256), 256, 0, stream>>>(ei_raw, e32, 2 * E, flag);
    zero_i32_kernel<<<1, 64, 0, stream>>>((int*)zbuf, 16);
    zero_i32_kernel<<<cdiv_i(N, 256), 256, 0, stream>>>(cnt, N);
    hist_kernel<<<cdiv_i(E, 256), 256, 0, stream>>>(dstI, cnt, E);
    dinv_kernel<<<cdiv_i(N, 256), 256, 0, stream>>>(cnt, dinv, N);
    scan1_kernel<<<nScanBlk, 256, 0, stream>>>(cnt, row_ptr, bsum, N);
    scan2_kernel<<<1, 256, 0, stream>>>(bsum, nScanBlk);
    scan3_kernel<<<nScanBlk, 256, 0, stream>>>(row_ptr, bsum, N);
    set_int_kernel<<<1, 1, 0, stream>>>(row_ptr, N, E);
    zero_i32_kernel<<<cdiv_i(N, 256), 256, 0, stream>>>(fill, N);
    scatter_kernel<<<cdiv_i(E, 256), 256, 0, stream>>>(srcI, dstI, row_ptr, fill, col, E);

    // ---- pack weights (fragment-major fp16 hi/lo) ----
    const int tot1 = (H / 128) * (F / 32) * (128 / 16) * 64;
    const int tot2 = (H / 128) * (H / 32) * (128 / 16) * 64;
    const int tot3 = (C / 64) * (H / 32) * (64 / 16) * 64;
    pack_w_kernel<<<cdiv_i(tot1, 256), 256, 0, stream>>>(W1, pW1, F, H, 128, tot1);
    pack_w_kernel<<<cdiv_i(tot2, 256), 256, 0, stream>>>(W2, pW2, H, H, 128, tot2);
    pack_w_kernel<<<cdiv_i(tot3, 256), 256, 0, stream>>>(W3, pW3, H, C, 64, tot3);

    const int aggGridH = cdiv_i(N, 4);

    // ---- layer 1: h1 = elu(A_hat @ (x @ W1) + b1)
    gemm_mfma_kernel<128><<<dim3(H / 128, Mt), 256, 0, stream>>>(x, pW1, th, N, F, H, zbuf);
    agg_pull_kernel<0><<<aggGridH, 256, 0, stream>>>(row_ptr, col, dinv, th, b1,
                                                     nullptr, h1, N, H);

    // ---- layer 2: h2 = elu(A_hat @ (h1 @ W2) + b2 + h1)
    gemm_mfma_kernel<128><<<dim3(H / 128, Mt), 256, 0, stream>>>(h1, pW2, th, N, H, H, zbuf);
    agg_pull_kernel<1><<<aggGridH, 256, 0, stream>>>(row_ptr, col, dinv, th, b2,
                                                     h1, h2, N, H);

    // ---- layer 3: out = A_hat @ (h2 @ W3) + b3
    gemm_mfma_kernel<64><<<dim3(C / 64, Mt), 256, 0, stream>>>(h2, pW3, th, N, H, C, zbuf);
    agg_pull64_kernel<<<aggGridH, 256, 0, stream>>>(row_ptr, col, dinv, th, b3, out, N);
}

// Round 9
// 351.943 us; speedup vs baseline: 2.1118x; 1.0838x over previous
//
#include <hip/hip_runtime.h>
#include <cstdint>
#include <cstddef>

// ---------------------------------------------------------------------------
// GCN: 3 layers.  out = A_hat @ (h @ W) + b, A_hat = D^-1/2 (A+I) D^-1/2
// R8: A-side lo-term dropped (error ~1.5e-4): 2 MFMA/fragment, h1/h2 fp16.
//     GEMM pipeline: A triple-buffered (HBM latency, counted vmcnt waited 2
//     iters after issue), B double-buffered (L2 latency), stages issued
//     post-barrier. B keeps hi/lo split (precomputed in pack_w).
// ---------------------------------------------------------------------------

static inline int cdiv_i(long a, long b) { return (int)((a + b - 1) / b); }

using half2v = __attribute__((ext_vector_type(2))) _Float16;
using half8 = __attribute__((ext_vector_type(8))) _Float16;
using f32x4 = __attribute__((ext_vector_type(4))) float;

__device__ __forceinline__ void gload_lds16(const void* g, void* l) {
    __builtin_amdgcn_global_load_lds(
        (const __attribute__((address_space(1))) unsigned int*)g,
        (__attribute__((address_space(3))) unsigned int*)l, 16, 0, 0);
}

template <int N>
__device__ __forceinline__ void wait_vmcnt() {
    if constexpr (N == 0) asm volatile("s_waitcnt vmcnt(0)" ::: "memory");
    else if constexpr (N == 1) asm volatile("s_waitcnt vmcnt(1)" ::: "memory");
    else asm volatile("s_waitcnt vmcnt(2)" ::: "memory");
}

__global__ void detect_fmt_kernel(const unsigned int* __restrict__ raw, int n_nodes,
                                  int* __restrict__ flag) {
    if (blockIdx.x == 0 && threadIdx.x == 0) {
        int is64 = 1;
        for (int i = 0; i < 64; ++i) {
            unsigned lo = raw[2 * i], hi = raw[2 * i + 1];
            if (hi != 0u || lo >= (unsigned)n_nodes) { is64 = 0; break; }
        }
        *flag = is64;
    }
}

__global__ void edges_to_i32_kernel(const void* __restrict__ raw, int* __restrict__ out,
                                    int twoE, const int* __restrict__ flag) {
    const int f = *flag;
    for (long i = blockIdx.x * (long)blockDim.x + threadIdx.x; i < twoE;
         i += (long)gridDim.x * blockDim.x) {
        out[i] = f ? (int)(((const long long*)raw)[i]) : ((const int*)raw)[i];
    }
}

__global__ void zero_i32_kernel(int* __restrict__ p, int n) {
    for (long i = blockIdx.x * (long)blockDim.x + threadIdx.x; i < n;
         i += (long)gridDim.x * blockDim.x)
        p[i] = 0;
}

__global__ void hist_kernel(const int* __restrict__ dst, int* __restrict__ cnt, int E) {
    for (long i = blockIdx.x * (long)blockDim.x + threadIdx.x; i < E;
         i += (long)gridDim.x * blockDim.x)
        atomicAdd(&cnt[dst[i]], 1);
}

__global__ void dinv_kernel(const int* __restrict__ cnt, float* __restrict__ dinv, int n) {
    for (long i = blockIdx.x * (long)blockDim.x + threadIdx.x; i < n;
         i += (long)gridDim.x * blockDim.x)
        dinv[i] = rsqrtf((float)cnt[i] + 1.0f);  // +1 self-loop
}

// ---- exclusive scan over n ints: 1024 elems / block ----
__global__ __launch_bounds__(256) void scan1_kernel(const int* __restrict__ in,
                                                    int* __restrict__ out,
                                                    int* __restrict__ bsum, int n) {
    __shared__ int tsum[256];
    const int tid = threadIdx.x;
    const long base = (long)blockIdx.x * 1024 + (long)tid * 4;
    int v[4];
#pragma unroll
    for (int i = 0; i < 4; ++i) v[i] = (base + i < n) ? in[base + i] : 0;
    const int s = v[0] + v[1] + v[2] + v[3];
    tsum[tid] = s;
    __syncthreads();
    for (int off = 1; off < 256; off <<= 1) {
        int add = (tid >= off) ? tsum[tid - off] : 0;
        __syncthreads();
        tsum[tid] += add;
        __syncthreads();
    }
    int run = tsum[tid] - s;
#pragma unroll
    for (int i = 0; i < 4; ++i) {
        if (base + i < n) out[base + i] = run;
        run += v[i];
    }
    if (tid == 255) bsum[blockIdx.x] = tsum[255];
}

__global__ void scan2_kernel(int* __restrict__ bsum, int nb) {
    __shared__ int lds[256];
    const int tid = threadIdx.x;
    int v = (tid < nb) ? bsum[tid] : 0;
    lds[tid] = v;
    __syncthreads();
    for (int off = 1; off < 256; off <<= 1) {
        int add = (tid >= off) ? lds[tid - off] : 0;
        __syncthreads();
        lds[tid] += add;
        __syncthreads();
    }
    if (tid < nb) bsum[tid] = lds[tid] - v;
}

__global__ __launch_bounds__(256) void scan3_kernel(int* __restrict__ out,
                                                    const int* __restrict__ bsum, int n) {
    const long base = (long)blockIdx.x * 1024 + (long)threadIdx.x * 4;
    const int add = bsum[blockIdx.x];
#pragma unroll
    for (int i = 0; i < 4; ++i)
        if (base + i < n) out[base + i] += add;
}

__global__ void set_int_kernel(int* __restrict__ p, int idx, int val) {
    if (blockIdx.x == 0 && threadIdx.x == 0) p[idx] = val;
}

__global__ void scatter_kernel(const int* __restrict__ src, const int* __restrict__ dst,
                               const int* __restrict__ row_ptr, int* __restrict__ fill,
                               int* __restrict__ col, int E) {
    for (long i = blockIdx.x * (long)blockDim.x + threadIdx.x; i < E;
         i += (long)gridDim.x * blockDim.x) {
        int d = dst[i];
        int p = row_ptr[d] + atomicAdd(&fill[d], 1);
        col[p] = src[i];
    }
}

__device__ __forceinline__ void split8f(const float v[8], half8& hi, half8& lo) {
#pragma unroll
    for (int j = 0; j < 8; ++j) {
        _Float16 h = (_Float16)v[j];
        hi[j] = h;
        lo[j] = (_Float16)((v[j] - (float)h) * 4096.0f);
    }
}

// ---------------------------------------------------------------------------
// Pack W (fp32 [K][Nn]) into fragment-major fp16 hi/lo.
// Per (nt, ks) chunk: [split(2)][colgrp(BN/16)][lane(64)][8 halfs]
// lane l -> col = nt*BN + cg*16 + (l&15), k = ks*32 + (l>>4)*8 + j
// ---------------------------------------------------------------------------
__global__ void pack_w_kernel(const float* __restrict__ W, _Float16* __restrict__ P,
                              int K, int Nn, int BN, int total) {
    int id = blockIdx.x * 256 + threadIdx.x;
    if (id >= total) return;
    const int CG = BN / 16, KS = K >> 5;
    const int l = id & 63;
    int r = id >> 6;
    const int cg = r % CG; r /= CG;
    const int ks = r % KS;
    const int nt = r / KS;
    const int c = nt * BN + cg * 16 + (l & 15);
    const int kb = ks * 32 + (l >> 4) * 8;
    const size_t CHUNK = (size_t)2 * CG * 64 * 8;
    _Float16* base = P + (size_t)(nt * KS + ks) * CHUNK + (size_t)(cg * 64 + l) * 8;
    float v[8];
#pragma unroll
    for (int j = 0; j < 8; ++j) v[j] = W[(size_t)(kb + j) * Nn + c];
    half8 hi, lo;
    split8f(v, hi, lo);
    *(half8*)base = hi;
    *(half8*)(base + CHUNK / 2) = lo;
}

// ---------------------------------------------------------------------------
// Ch[M,Nn](fp16) = A[M,K] @ Bpacked, fp16 MFMA (A hi-only, B hi+lo).
// BM=64, BN in {128,64}, BK=32, 256 threads = 4 waves.
// A: 3-stage buffer (HBM, waited 2 iters after issue); B: 2-stage (L2).
// Steady-state wait: vmcnt(AL) (AL = A loads/stage) -- never 0 mid-loop.
// AF16=1: A is fp16 row-major (h1/h2). AF16=0: A is fp32 (x), cvt in loop.
// ---------------------------------------------------------------------------
template <int BN, int AF16>
__global__ __launch_bounds__(256) void gemm_mfma_kernel(
    const void* __restrict__ Araw, const _Float16* __restrict__ Bp,
    _Float16* __restrict__ Ch, int M, int K, int Nn,
    const float* __restrict__ zbuf) {
    constexpr int WC = BN / 64;              // wave cols: 2 or 1
    constexpr int WR = 4 / WC;               // wave rows: 2 or 4
    constexpr int MI = 64 / (WR * 16);       // 2 or 1
    constexpr int NI = 4;
    constexpr int BCH = 2 * (BN / 16) * 64 * 8;  // halfs per B stage
    constexpr int BU = BCH / 2048;           // B loads per thread (4 or 2)
    constexpr int AL = AF16 ? 1 : 2;         // A loads per thread
    constexpr int ABYTES = AF16 ? 4096 : 8192;
    constexpr int BBYTES = BCH * 2;
    constexpr int PIPEB = 3 * ABYTES + 2 * BBYTES;
    constexpr int EPIB = 64 * BN * 2;
    constexpr int SMB = (PIPEB > EPIB) ? PIPEB : EPIB;

    __shared__ __align__(16) char smraw[SMB];
    char* bufA0 = smraw;
    char* bufB0 = smraw + 3 * ABYTES;

    const int tid = threadIdx.x;
    const int lane = tid & 63;
    const int wid = __builtin_amdgcn_readfirstlane(tid >> 6);
    const int wr = wid / WC, wc = wid % WC;
    const int bm = blockIdx.y * 64, bn = blockIdx.x * BN;
    const int KS = K >> 5;
    const _Float16* bchunk = Bp + (size_t)blockIdx.x * KS * BCH;

    // ---- A stage source addressing ----
    const float* a32_1 = nullptr;
    const float* a32_2 = nullptr;
    const _Float16* a16_1 = nullptr;
    bool ok1 = false, ok2 = false;
    if constexpr (AF16) {
        const _Float16* A16 = (const _Float16*)Araw;
        const int r1 = wid * 16 + (lane & 15);
        const int kq = (lane >> 4) * 8;          // halfs
        const int gm = bm + r1;
        ok1 = gm < M;
        a16_1 = ok1 ? (A16 + (size_t)gm * K + kq) : nullptr;
    } else {
        const float* A32 = (const float*)Araw;
        const int r1 = (wid >> 1) * 16 + (lane & 15);
        const int kq = ((lane >> 4) << 3) + ((wid & 1) << 2);  // floats
        const int gm1 = bm + r1, gm2 = gm1 + 32;
        ok1 = gm1 < M; ok2 = gm2 < M;
        a32_1 = ok1 ? (A32 + (size_t)gm1 * K + kq) : nullptr;
        a32_2 = ok2 ? (A32 + (size_t)gm2 * K + kq) : nullptr;
    }

    f32x4 acc1[MI][NI] = {};
    f32x4 acc2[MI][NI] = {};

    auto stageA = [&](int b, int ks) {
        char* sA = bufA0 + b * ABYTES;
        if constexpr (AF16) {
            gload_lds16(ok1 ? (const void*)(a16_1 + ks * 32) : (const void*)zbuf,
                        sA + wid * 1024);
        } else {
            gload_lds16(ok1 ? (const void*)(a32_1 + ks * 32) : (const void*)zbuf,
                        sA + wid * 1024);
            gload_lds16(ok2 ? (const void*)(a32_2 + ks * 32) : (const void*)zbuf,
                        sA + (wid + 4) * 1024);
        }
    };
    auto stageB = [&](int b, int ks) {
        char* sB = bufB0 + b * BBYTES;
        const _Float16* bc = bchunk + (size_t)ks * BCH;
#pragma unroll
        for (int rr = 0; rr < BU; ++rr)
            gload_lds16(bc + (size_t)(((wid * BU + rr) * 64 + lane) << 3),
                        sB + ((wid * BU + rr) << 10));
    };

    // prologue: A(0), B(0), A(1) -- FIFO order matters for counted waits
    stageA(0, 0);
    stageB(0, 0);
    if (1 < KS) stageA(1, 1);

    for (int ks = 0; ks < KS; ++ks) {
        if (ks + 1 < KS) wait_vmcnt<AL>();  // A(ks), B(ks) landed; A(ks+1) flying
        else wait_vmcnt<0>();
        __builtin_amdgcn_s_barrier();
        if (ks + 1 < KS) stageB((ks + 1) & 1, ks + 1);
        if (ks + 2 < KS) stageA((ks + 2) % 3, ks + 2);

        const char* cA = bufA0 + (ks % 3) * ABYTES;
        const _Float16* smB = (const _Float16*)(bufB0 + (ks & 1) * BBYTES);

        half8 afh[MI];
        if constexpr (AF16) {
            const _Float16* smA16 = (const _Float16*)cA;
#pragma unroll
            for (int mi = 0; mi < MI; ++mi)
                afh[mi] = *(const half8*)(smA16 + (((wr * MI + mi) * 64 + lane) << 3));
        } else {
            const float* smA32 = (const float*)cA;
#pragma unroll
            for (int mi = 0; mi < MI; ++mi) {
                const int rg = wr * MI + mi;
                f32x4 vlo = *(const f32x4*)(smA32 + (((rg * 2 + 0) * 64 + lane) << 2));
                f32x4 vhi = *(const f32x4*)(smA32 + (((rg * 2 + 1) * 64 + lane) << 2));
                half8 h;
                h[0] = (_Float16)vlo[0]; h[1] = (_Float16)vlo[1];
                h[2] = (_Float16)vlo[2]; h[3] = (_Float16)vlo[3];
                h[4] = (_Float16)vhi[0]; h[5] = (_Float16)vhi[1];
                h[6] = (_Float16)vhi[2]; h[7] = (_Float16)vhi[3];
                afh[mi] = h;
            }
        }
#pragma unroll
        for (int ni = 0; ni < NI; ++ni) {
            const half8 bh = *(const half8*)(smB + (((wc * 4 + ni) * 64 + lane) << 3));
            const half8 bl = *(const half8*)(smB + BCH / 2 + (((wc * 4 + ni) * 64 + lane) << 3));
#pragma unroll
            for (int mi = 0; mi < MI; ++mi) {
                acc1[mi][ni] = __builtin_amdgcn_mfma_f32_16x16x32_f16(
                    afh[mi], bh, acc1[mi][ni], 0, 0, 0);
                acc2[mi][ni] = __builtin_amdgcn_mfma_f32_16x16x32_f16(
                    afh[mi], bl, acc2[mi][ni], 0, 0, 0);
            }
        }
    }

    // ---- epilogue: stage fp16 tile in LDS, store full coalesced lines ----
    __syncthreads();
    _Float16* smC = (_Float16*)smraw;
    const float inv = 1.0f / 4096.0f;
#pragma unroll
    for (int mi = 0; mi < MI; ++mi) {
#pragma unroll
        for (int ni = 0; ni < NI; ++ni) {
            const int row0 = wr * (MI * 16) + mi * 16 + ((lane >> 4) << 2);
            const int colx = wc * 64 + ni * 16 + (lane & 15);
#pragma unroll
            for (int i = 0; i < 4; ++i)
                smC[(row0 + i) * BN + colx] =
                    (_Float16)(acc1[mi][ni][i] + acc2[mi][ni][i] * inv);
        }
    }
    __syncthreads();
    constexpr int UPR = BN / 8;  // 16B units per row
#pragma unroll
    for (int r = 0; r < BN / 32; ++r) {
        const int u = r * 256 + tid;
        const int row = u / UPR, cu = u % UPR;
        const int grow = bm + row;
        if (grow < M)
            *(uint4*)(Ch + (size_t)grow * Nn + bn + cu * 8) =
                *(const uint4*)(smC + row * BN + cu * 8);
    }
}

__device__ __forceinline__ float elu1(float v) { return v > 0.f ? v : expm1f(v); }

// Pull aggregation over fp16 t (Hdim=256): one wave per node, 32 lanes x
// half8 (16B) per row, 2 edges per wave-iteration, 4-pair unroll.
// Output y fp16.  MODE 0: y=elu(conv)  MODE 1: y=elu(conv+res), res fp16.
template <int MODE>
__global__ __launch_bounds__(256) void agg_pull_kernel(
    const int* __restrict__ row_ptr, const int* __restrict__ col,
    const float* __restrict__ dinv, const _Float16* __restrict__ t,
    const float* __restrict__ bias, const _Float16* __restrict__ res,
    _Float16* __restrict__ y, int Nn, int Hdim) {
    const int node = blockIdx.x * (blockDim.x >> 6) + (threadIdx.x >> 6);
    if (node >= Nn) return;
    const int lane = threadIdx.x & 63;
    const int sub = lane >> 5;         // which edge of the pair
    const int f = (lane & 31) * 8;     // feature base (32 lanes x 8 = 256)

    float acc[8] = {0.f, 0.f, 0.f, 0.f, 0.f, 0.f, 0.f, 0.f};

    const int s0 = row_ptr[node], s1 = row_ptr[node + 1];
    int e = s0 + sub;
    for (; e + 7 < s1; e += 8) {
        int ss[4];
        float w[4];
        half8 v[4];
#pragma unroll
        for (int u = 0; u < 4; ++u) ss[u] = col[e + 2 * u];
#pragma unroll
        for (int u = 0; u < 4; ++u) w[u] = dinv[ss[u]];
#pragma unroll
        for (int u = 0; u < 4; ++u)
            v[u] = *(const half8*)(t + (size_t)ss[u] * Hdim + f);
#pragma unroll
        for (int u = 0; u < 4; ++u)
#pragma unroll
            for (int i = 0; i < 8; ++i)
                acc[i] = fmaf((float)v[u][i], w[u], acc[i]);
    }
    for (; e < s1; e += 2) {
        const int s = col[e];
        const float w = dinv[s];
        const half8 v = *(const half8*)(t + (size_t)s * Hdim + f);
#pragma unroll
        for (int i = 0; i < 8; ++i) acc[i] = fmaf((float)v[i], w, acc[i]);
    }

#pragma unroll
    for (int i = 0; i < 8; ++i) acc[i] += __shfl_xor(acc[i], 32);

    if (sub == 0) {
        const float dn = dinv[node];
        const half8 tn = *(const half8*)(t + (size_t)node * Hdim + f);
        float o[8];
#pragma unroll
        for (int i = 0; i < 8; ++i)
            o[i] = (acc[i] + (float)tn[i] * dn) * dn + bias[f + i];
        if (MODE == 1) {
            const half8 rv = *(const half8*)(res + (size_t)node * Hdim + f);
#pragma unroll
            for (int i = 0; i < 8; ++i) o[i] += (float)rv[i];
        }
        half8 ov;
#pragma unroll
        for (int i = 0; i < 8; ++i) ov[i] = (_Float16)elu1(o[i]);
        *(half8*)(y + (size_t)node * Hdim + f) = ov;
    }
}

// Layer-3 aggregation: Cdim=64 fp16 t, one wave/node, 2 edges per iteration
// (lane>>5 selects edge), 4-way unrolled, cross-half shfl reduce. y=conv+b (fp32).
__global__ __launch_bounds__(256) void agg_pull64_kernel(
    const int* __restrict__ row_ptr, const int* __restrict__ col,
    const float* __restrict__ dinv, const _Float16* __restrict__ t,
    const float* __restrict__ bias, float* __restrict__ y, int Nn) {
    const int node = blockIdx.x * (blockDim.x >> 6) + (threadIdx.x >> 6);
    if (node >= Nn) return;
    const int lane = threadIdx.x & 63;
    const int sub = lane >> 5;
    const int f = (lane & 31) * 2;

    float acc0 = 0.f, acc1 = 0.f;
    const int s0 = row_ptr[node], s1 = row_ptr[node + 1];
    int e = s0 + sub;
    for (; e + 6 < s1; e += 8) {
        int ss[4];
        float w[4];
        half2v v[4];
#pragma unroll
        for (int u = 0; u < 4; ++u) ss[u] = col[e + 2 * u];
#pragma unroll
        for (int u = 0; u < 4; ++u) w[u] = dinv[ss[u]];
#pragma unroll
        for (int u = 0; u < 4; ++u)
            v[u] = *(const half2v*)(t + (size_t)ss[u] * 64 + f);
#pragma unroll
        for (int u = 0; u < 4; ++u) {
            acc0 = fmaf((float)v[u][0], w[u], acc0);
            acc1 = fmaf((float)v[u][1], w[u], acc1);
        }
    }
    for (; e < s1; e += 2) {
        const int s = col[e];
        const float w = dinv[s];
        const half2v v = *(const half2v*)(t + (size_t)s * 64 + f);
        acc0 = fmaf((float)v[0], w, acc0);
        acc1 = fmaf((float)v[1], w, acc1);
    }

    acc0 += __shfl_xor(acc0, 32);
    acc1 += __shfl_xor(acc1, 32);

    const float dn = dinv[node];
    const half2v tn = *(const half2v*)(t + (size_t)node * 64 + f);
    const float o0 = (acc0 + (float)tn[0] * dn) * dn + bias[f];
    const float o1 = (acc1 + (float)tn[1] * dn) * dn + bias[f + 1];

    if (lane < 32) {
        float2 ov = make_float2(o0, o1);
        *(float2*)(y + (size_t)node * 64 + f) = ov;
    }
}

extern "C" void kernel_launch(void* const* d_in, const int* in_sizes, int n_in,
                              void* d_out, int out_size, void* d_ws, size_t ws_size,
                              hipStream_t stream) {
    const float* x = (const float*)d_in[0];
    const void* ei_raw = d_in[1];
    const float* W1 = (const float*)d_in[2];
    const float* b1 = (const float*)d_in[3];
    const float* W2 = (const float*)d_in[4];
    const float* b2 = (const float*)d_in[5];
    const float* W3 = (const float*)d_in[6];
    const float* b3 = (const float*)d_in[7];
    float* out = (float*)d_out;

    const int H = in_sizes[3];       // 256
    const int F = in_sizes[2] / H;   // 512
    const int N = in_sizes[0] / F;   // 50000
    const int C = in_sizes[7];       // 64
    const int E = in_sizes[1] / 2;   // 800000
    const int Mt = cdiv_i(N, 64);    // 782 row tiles

    // workspace layout
    char* ws = (char*)d_ws;
    size_t off = 0;
    auto take = [&](size_t bytes) -> char* {
        char* p = ws + off;
        off += (bytes + 255) & ~(size_t)255;
        return p;
    };
    float* dinv = (float*)take((size_t)N * 4);
    int* flag = (int*)take(4);
    float* zbuf = (float*)take(64);
    _Float16* th = (_Float16*)take((size_t)N * H * 2);   // GEMM output (fp16)
    _Float16* h1 = (_Float16*)take((size_t)N * H * 2);   // fp16 activations
    _Float16* h2 = (_Float16*)take((size_t)N * H * 2);
    int* e32 = (int*)take((size_t)2 * E * 4);
    int* srcI = e32;
    int* dstI = e32 + E;
    int* col = (int*)take((size_t)E * 4);
    int* cnt = (int*)take((size_t)N * 4);
    int* row_ptr = (int*)take((size_t)(N + 1) * 4);
    int* fill = (int*)take((size_t)N * 4);
    int* bsum = (int*)take(256 * 4);
    _Float16* pW1 = (_Float16*)take((size_t)F * H * 2 * 2);
    _Float16* pW2 = (_Float16*)take((size_t)H * H * 2 * 2);
    _Float16* pW3 = (_Float16*)take((size_t)H * C * 2 * 2);
    (void)ws_size; (void)n_in; (void)out_size;

    const int nScanBlk = cdiv_i(N, 1024);

    // ---- edges + degrees + CSR (+ zero page for GEMM OOB rows) ----
    detect_fmt_kernel<<<1, 64, 0, stream>>>((const unsigned*)ei_raw, N, flag);
    edges_to_i32_kernel<<<cdiv_i(2L * E, 256), 256, 0, stream>>>(ei_raw, e32, 2 * E, flag);
    zero_i32_kernel<<<1, 64, 0, stream>>>((int*)zbuf, 16);
    zero_i32_kernel<<<cdiv_i(N, 256), 256, 0, stream>>>(cnt, N);
    hist_kernel<<<cdiv_i(E, 256), 256, 0, stream>>>(dstI, cnt, E);
    dinv_kernel<<<cdiv_i(N, 256), 256, 0, stream>>>(cnt, dinv, N);
    scan1_kernel<<<nScanBlk, 256, 0, stream>>>(cnt, row_ptr, bsum, N);
    scan2_kernel<<<1, 256, 0, stream>>>(bsum, nScanBlk);
    scan3_kernel<<<nScanBlk, 256, 0, stream>>>(row_ptr, bsum, N);
    set_int_kernel<<<1, 1, 0, stream>>>(row_ptr, N, E);
    zero_i32_kernel<<<cdiv_i(N, 256), 256, 0, stream>>>(fill, N);
    scatter_kernel<<<cdiv_i(E, 256), 256, 0, stream>>>(srcI, dstI, row_ptr, fill, col, E);

    // ---- pack weights (fragment-major fp16 hi/lo) ----
    const int tot1 = (H / 128) * (F / 32) * (128 / 16) * 64;
    const int tot2 = (H / 128) * (H / 32) * (128 / 16) * 64;
    const int tot3 = (C / 64) * (H / 32) * (64 / 16) * 64;
    pack_w_kernel<<<cdiv_i(tot1, 256), 256, 0, stream>>>(W1, pW1, F, H, 128, tot1);
    pack_w_kernel<<<cdiv_i(tot2, 256), 256, 0, stream>>>(W2, pW2, H, H, 128, tot2);
    pack_w_kernel<<<cdiv_i(tot3, 256), 256, 0, stream>>>(W3, pW3, H, C, 64, tot3);

    const int aggGridH = cdiv_i(N, 4);

    // ---- layer 1: h1 = elu(A_hat @ (x @ W1) + b1)
    gemm_mfma_kernel<128, 0><<<dim3(H / 128, Mt), 256, 0, stream>>>(
        x, pW1, th, N, F, H, zbuf);
    agg_pull_kernel<0><<<aggGridH, 256, 0, stream>>>(row_ptr, col, dinv, th, b1,
                                                     nullptr, h1, N, H);

    // ---- layer 2: h2 = elu(A_hat @ (h1 @ W2) + b2 + h1)
    gemm_mfma_kernel<128, 1><<<dim3(H / 128, Mt), 256, 0, stream>>>(
        h1, pW2, th, N, H, H, zbuf);
    agg_pull_kernel<1><<<aggGridH, 256, 0, stream>>>(row_ptr, col, dinv, th, b2,
                                                     h1, h2, N, H);

    // ---- layer 3: out = A_hat @ (h2 @ W3) + b3
    gemm_mfma_kernel<64, 1><<<dim3(C / 64, Mt), 256, 0, stream>>>(
        h2, pW3, th, N, H, C, zbuf);
    agg_pull64_kernel<<<aggGridH, 256, 0, stream>>>(row_ptr, col, dinv, th, b3, out, N);
}

// Round 10
// 345.370 us; speedup vs baseline: 2.1520x; 1.0190x over previous
//
#include <hip/hip_runtime.h>
#include <cstdint>
#include <cstddef>

// ---------------------------------------------------------------------------
// GCN: 3 layers.  out = A_hat @ (h @ W) + b, A_hat = D^-1/2 (A+I) D^-1/2
// R9: A staged COALESCED (row-major, linear LDS dest) with XOR-swizzled
//     source chunks; fragment ds_reads apply the same XOR (2-way conflicts).
//     Pipeline: A 3-deep / B 2-deep, counted vmcnt (never 0 mid-loop).
//     A hi-only fp16 MFMA (2 MFMA/frag), B hi+lo packed. h1/h2 fp16.
// ---------------------------------------------------------------------------

static inline int cdiv_i(long a, long b) { return (int)((a + b - 1) / b); }

using half2v = __attribute__((ext_vector_type(2))) _Float16;
using half8 = __attribute__((ext_vector_type(8))) _Float16;
using f32x4 = __attribute__((ext_vector_type(4))) float;

__device__ __forceinline__ void gload_lds16(const void* g, void* l) {
    __builtin_amdgcn_global_load_lds(
        (const __attribute__((address_space(1))) unsigned int*)g,
        (__attribute__((address_space(3))) unsigned int*)l, 16, 0, 0);
}

template <int N>
__device__ __forceinline__ void wait_vmcnt() {
    if constexpr (N == 0) asm volatile("s_waitcnt vmcnt(0)" ::: "memory");
    else if constexpr (N == 1) asm volatile("s_waitcnt vmcnt(1)" ::: "memory");
    else asm volatile("s_waitcnt vmcnt(2)" ::: "memory");
}

__global__ void detect_fmt_kernel(const unsigned int* __restrict__ raw, int n_nodes,
                                  int* __restrict__ flag) {
    if (blockIdx.x == 0 && threadIdx.x == 0) {
        int is64 = 1;
        for (int i = 0; i < 64; ++i) {
            unsigned lo = raw[2 * i], hi = raw[2 * i + 1];
            if (hi != 0u || lo >= (unsigned)n_nodes) { is64 = 0; break; }
        }
        *flag = is64;
    }
}

__global__ void edges_to_i32_kernel(const void* __restrict__ raw, int* __restrict__ out,
                                    int twoE, const int* __restrict__ flag) {
    const int f = *flag;
    for (long i = blockIdx.x * (long)blockDim.x + threadIdx.x; i < twoE;
         i += (long)gridDim.x * blockDim.x) {
        out[i] = f ? (int)(((const long long*)raw)[i]) : ((const int*)raw)[i];
    }
}

__global__ void zero_i32_kernel(int* __restrict__ p, int n) {
    for (long i = blockIdx.x * (long)blockDim.x + threadIdx.x; i < n;
         i += (long)gridDim.x * blockDim.x)
        p[i] = 0;
}

__global__ void hist_kernel(const int* __restrict__ dst, int* __restrict__ cnt, int E) {
    for (long i = blockIdx.x * (long)blockDim.x + threadIdx.x; i < E;
         i += (long)gridDim.x * blockDim.x)
        atomicAdd(&cnt[dst[i]], 1);
}

__global__ void dinv_kernel(const int* __restrict__ cnt, float* __restrict__ dinv, int n) {
    for (long i = blockIdx.x * (long)blockDim.x + threadIdx.x; i < n;
         i += (long)gridDim.x * blockDim.x)
        dinv[i] = rsqrtf((float)cnt[i] + 1.0f);  // +1 self-loop
}

// ---- exclusive scan over n ints: 1024 elems / block ----
__global__ __launch_bounds__(256) void scan1_kernel(const int* __restrict__ in,
                                                    int* __restrict__ out,
                                                    int* __restrict__ bsum, int n) {
    __shared__ int tsum[256];
    const int tid = threadIdx.x;
    const long base = (long)blockIdx.x * 1024 + (long)tid * 4;
    int v[4];
#pragma unroll
    for (int i = 0; i < 4; ++i) v[i] = (base + i < n) ? in[base + i] : 0;
    const int s = v[0] + v[1] + v[2] + v[3];
    tsum[tid] = s;
    __syncthreads();
    for (int off = 1; off < 256; off <<= 1) {
        int add = (tid >= off) ? tsum[tid - off] : 0;
        __syncthreads();
        tsum[tid] += add;
        __syncthreads();
    }
    int run = tsum[tid] - s;
#pragma unroll
    for (int i = 0; i < 4; ++i) {
        if (base + i < n) out[base + i] = run;
        run += v[i];
    }
    if (tid == 255) bsum[blockIdx.x] = tsum[255];
}

__global__ void scan2_kernel(int* __restrict__ bsum, int nb) {
    __shared__ int lds[256];
    const int tid = threadIdx.x;
    int v = (tid < nb) ? bsum[tid] : 0;
    lds[tid] = v;
    __syncthreads();
    for (int off = 1; off < 256; off <<= 1) {
        int add = (tid >= off) ? lds[tid - off] : 0;
        __syncthreads();
        lds[tid] += add;
        __syncthreads();
    }
    if (tid < nb) bsum[tid] = lds[tid] - v;
}

__global__ __launch_bounds__(256) void scan3_kernel(int* __restrict__ out,
                                                    const int* __restrict__ bsum, int n) {
    const long base = (long)blockIdx.x * 1024 + (long)threadIdx.x * 4;
    const int add = bsum[blockIdx.x];
#pragma unroll
    for (int i = 0; i < 4; ++i)
        if (base + i < n) out[base + i] += add;
}

__global__ void set_int_kernel(int* __restrict__ p, int idx, int val) {
    if (blockIdx.x == 0 && threadIdx.x == 0) p[idx] = val;
}

__global__ void scatter_kernel(const int* __restrict__ src, const int* __restrict__ dst,
                               const int* __restrict__ row_ptr, int* __restrict__ fill,
                               int* __restrict__ col, int E) {
    for (long i = blockIdx.x * (long)blockDim.x + threadIdx.x; i < E;
         i += (long)gridDim.x * blockDim.x) {
        int d = dst[i];
        int p = row_ptr[d] + atomicAdd(&fill[d], 1);
        col[p] = src[i];
    }
}

__device__ __forceinline__ void split8f(const float v[8], half8& hi, half8& lo) {
#pragma unroll
    for (int j = 0; j < 8; ++j) {
        _Float16 h = (_Float16)v[j];
        hi[j] = h;
        lo[j] = (_Float16)((v[j] - (float)h) * 4096.0f);
    }
}

// ---------------------------------------------------------------------------
// Pack W (fp32 [K][Nn]) into fragment-major fp16 hi/lo.
// Per (nt, ks) chunk: [split(2)][colgrp(BN/16)][lane(64)][8 halfs]
// lane l -> col = nt*BN + cg*16 + (l&15), k = ks*32 + (l>>4)*8 + j
// ---------------------------------------------------------------------------
__global__ void pack_w_kernel(const float* __restrict__ W, _Float16* __restrict__ P,
                              int K, int Nn, int BN, int total) {
    int id = blockIdx.x * 256 + threadIdx.x;
    if (id >= total) return;
    const int CG = BN / 16, KS = K >> 5;
    const int l = id & 63;
    int r = id >> 6;
    const int cg = r % CG; r /= CG;
    const int ks = r % KS;
    const int nt = r / KS;
    const int c = nt * BN + cg * 16 + (l & 15);
    const int kb = ks * 32 + (l >> 4) * 8;
    const size_t CHUNK = (size_t)2 * CG * 64 * 8;
    _Float16* base = P + (size_t)(nt * KS + ks) * CHUNK + (size_t)(cg * 64 + l) * 8;
    float v[8];
#pragma unroll
    for (int j = 0; j < 8; ++j) v[j] = W[(size_t)(kb + j) * Nn + c];
    half8 hi, lo;
    split8f(v, hi, lo);
    *(half8*)base = hi;
    *(half8*)(base + CHUNK / 2) = lo;
}

// ---------------------------------------------------------------------------
// Ch[M,Nn](fp16) = A[M,K] @ Bpacked, fp16 MFMA (A hi-only, B hi+lo).
// BM=64, BN in {128,64}, BK=32, 256 threads = 4 waves.
// A staged COALESCED row-major with XOR-swizzled chunks:
//   fp32: LDS[row][c] = A[bm+row][ks*32 + (c^(row&7))*4 ..+4)   (c in 16B units)
//   fp16: LDS[row][c] = A[bm+row][ks*32 + (c^((row>>1)&3))*8 ..+8)
// LDS dest is linear (wave base + lane*16); source stays within the row's
// 128B line so coalescing is preserved. Fragment reads apply the same XOR.
// A: 3-stage (HBM, waited 2 iters after issue); B: 2-stage (L2).
// ---------------------------------------------------------------------------
template <int BN, int AF16>
__global__ __launch_bounds__(256) void gemm_mfma_kernel(
    const void* __restrict__ Araw, const _Float16* __restrict__ Bp,
    _Float16* __restrict__ Ch, int M, int K, int Nn,
    const float* __restrict__ zbuf) {
    constexpr int WC = BN / 64;              // wave cols: 2 or 1
    constexpr int WR = 4 / WC;               // wave rows: 2 or 4
    constexpr int MI = 64 / (WR * 16);       // 2 or 1
    constexpr int NI = 4;
    constexpr int BCH = 2 * (BN / 16) * 64 * 8;  // halfs per B stage
    constexpr int BU = BCH / 2048;           // B loads per thread (4 or 2)
    constexpr int AL = AF16 ? 1 : 2;         // A loads per thread
    constexpr int ABYTES = AF16 ? 4096 : 8192;
    constexpr int BBYTES = BCH * 2;
    constexpr int PIPEB = 3 * ABYTES + 2 * BBYTES;
    constexpr int EPIB = 64 * BN * 2;
    constexpr int SMB = (PIPEB > EPIB) ? PIPEB : EPIB;

    __shared__ __align__(16) char smraw[SMB];
    char* bufA0 = smraw;
    char* bufB0 = smraw + 3 * ABYTES;

    const int tid = threadIdx.x;
    const int lane = tid & 63;
    const int wid = __builtin_amdgcn_readfirstlane(tid >> 6);
    const int wr = wid / WC, wc = wid % WC;
    const int bm = blockIdx.y * 64, bn = blockIdx.x * BN;
    const int KS = K >> 5;
    const _Float16* bchunk = Bp + (size_t)blockIdx.x * KS * BCH;

    // ---- A stage source addressing (coalesced + chunk-swizzled) ----
    const float* a32s0 = nullptr;
    const float* a32s1 = nullptr;
    const _Float16* a16s = nullptr;
    if constexpr (AF16) {
        const _Float16* A16 = (const _Float16*)Araw;
        const int rl = wid * 16 + (lane >> 2);           // local row 0..63
        const int kc = (lane & 3) ^ ((rl >> 1) & 3);     // swizzled 16B chunk
        const int gm = bm + rl;
        a16s = (gm < M) ? (A16 + (size_t)gm * K + kc * 8)
                        : (const _Float16*)zbuf;
    } else {
        const float* A32 = (const float*)Araw;
        const int rl0 = wid * 8 + (lane >> 3);           // rows 0..31
        const int rl1 = 32 + rl0;                        // rows 32..63
        const int kc0 = (lane & 7) ^ (rl0 & 7);
        const int kc1 = (lane & 7) ^ (rl1 & 7);
        const int gm0 = bm + rl0, gm1 = bm + rl1;
        a32s0 = (gm0 < M) ? (A32 + (size_t)gm0 * K + kc0 * 4) : zbuf;
        a32s1 = (gm1 < M) ? (A32 + (size_t)gm1 * K + kc1 * 4) : zbuf;
    }

    f32x4 acc1[MI][NI] = {};
    f32x4 acc2[MI][NI] = {};

    auto stageA = [&](int b, int ks) {
        char* sA = bufA0 + b * ABYTES;
        if constexpr (AF16) {
            gload_lds16(a16s + ks * 32, sA + wid * 1024);
        } else {
            gload_lds16(a32s0 + ks * 32, sA + wid * 1024);
            gload_lds16(a32s1 + ks * 32, sA + 4096 + wid * 1024);
        }
    };
    auto stageB = [&](int b, int ks) {
        char* sB = bufB0 + b * BBYTES;
        const _Float16* bc = bchunk + (size_t)ks * BCH;
#pragma unroll
        for (int rr = 0; rr < BU; ++rr)
            gload_lds16(bc + (size_t)(((wid * BU + rr) * 64 + lane) << 3),
                        sB + ((wid * BU + rr) << 10));
    };

    // ---- fragment read addresses (per-thread invariant) ----
    int aoff0[MI], aoff1[MI];  // byte offsets within an A buffer
#pragma unroll
    for (int mi = 0; mi < MI; ++mi) {
        const int r = (wr * MI + mi) * 16 + (lane & 15);
        if constexpr (AF16) {
            const int c = r * 4 + ((lane >> 4) ^ ((r >> 1) & 3));
            aoff0[mi] = c * 16;
            aoff1[mi] = 0;
        } else {
            const int g0 = (lane >> 4) * 2;
            const int sw = r & 7;
            aoff0[mi] = (r * 8 + (g0 ^ sw)) * 16;
            aoff1[mi] = (r * 8 + ((g0 + 1) ^ sw)) * 16;
        }
    }

    // prologue: A(0), B(0), A(1) -- FIFO order matters for counted waits
    stageA(0, 0);
    stageB(0, 0);
    if (1 < KS) stageA(1, 1);

    for (int ks = 0; ks < KS; ++ks) {
        if (ks + 1 < KS) wait_vmcnt<AL>();  // A(ks), B(ks) landed; A(ks+1) flying
        else wait_vmcnt<0>();
        __builtin_amdgcn_s_barrier();
        if (ks + 1 < KS) stageB((ks + 1) & 1, ks + 1);
        if (ks + 2 < KS) stageA((ks + 2) % 3, ks + 2);

        const char* cA = bufA0 + (ks % 3) * ABYTES;
        const _Float16* smB = (const _Float16*)(bufB0 + (ks & 1) * BBYTES);

        half8 afh[MI];
        if constexpr (AF16) {
#pragma unroll
            for (int mi = 0; mi < MI; ++mi)
                afh[mi] = *(const half8*)(cA + aoff0[mi]);
        } else {
#pragma unroll
            for (int mi = 0; mi < MI; ++mi) {
                f32x4 vlo = *(const f32x4*)(cA + aoff0[mi]);
                f32x4 vhi = *(const f32x4*)(cA + aoff1[mi]);
                half8 h;
                h[0] = (_Float16)vlo[0]; h[1] = (_Float16)vlo[1];
                h[2] = (_Float16)vlo[2]; h[3] = (_Float16)vlo[3];
                h[4] = (_Float16)vhi[0]; h[5] = (_Float16)vhi[1];
                h[6] = (_Float16)vhi[2]; h[7] = (_Float16)vhi[3];
                afh[mi] = h;
            }
        }
#pragma unroll
        for (int ni = 0; ni < NI; ++ni) {
            const half8 bh = *(const half8*)(smB + (((wc * 4 + ni) * 64 + lane) << 3));
            const half8 bl = *(const half8*)(smB + BCH / 2 + (((wc * 4 + ni) * 64 + lane) << 3));
#pragma unroll
            for (int mi = 0; mi < MI; ++mi) {
                acc1[mi][ni] = __builtin_amdgcn_mfma_f32_16x16x32_f16(
                    afh[mi], bh, acc1[mi][ni], 0, 0, 0);
                acc2[mi][ni] = __builtin_amdgcn_mfma_f32_16x16x32_f16(
                    afh[mi], bl, acc2[mi][ni], 0, 0, 0);
            }
        }
    }

    // ---- epilogue: stage fp16 tile in LDS, store full coalesced lines ----
    __syncthreads();
    _Float16* smC = (_Float16*)smraw;
    const float inv = 1.0f / 4096.0f;
#pragma unroll
    for (int mi = 0; mi < MI; ++mi) {
#pragma unroll
        for (int ni = 0; ni < NI; ++ni) {
            const int row0 = wr * (MI * 16) + mi * 16 + ((lane >> 4) << 2);
            const int colx = wc * 64 + ni * 16 + (lane & 15);
#pragma unroll
            for (int i = 0; i < 4; ++i)
                smC[(row0 + i) * BN + colx] =
                    (_Float16)(acc1[mi][ni][i] + acc2[mi][ni][i] * inv);
        }
    }
    __syncthreads();
    constexpr int UPR = BN / 8;  // 16B units per row
#pragma unroll
    for (int r = 0; r < BN / 32; ++r) {
        const int u = r * 256 + tid;
        const int row = u / UPR, cu = u % UPR;
        const int grow = bm + row;
        if (grow < M)
            *(uint4*)(Ch + (size_t)grow * Nn + bn + cu * 8) =
                *(const uint4*)(smC + row * BN + cu * 8);
    }
}

__device__ __forceinline__ float elu1(float v) { return v > 0.f ? v : expm1f(v); }

// Pull aggregation over fp16 t (Hdim=256): one wave per node, 32 lanes x
// half8 (16B) per row, 2 edges per wave-iteration, 4-pair unroll.
// Output y fp16.  MODE 0: y=elu(conv)  MODE 1: y=elu(conv+res), res fp16.
template <int MODE>
__global__ __launch_bounds__(256) void agg_pull_kernel(
    const int* __restrict__ row_ptr, const int* __restrict__ col,
    const float* __restrict__ dinv, const _Float16* __restrict__ t,
    const float* __restrict__ bias, const _Float16* __restrict__ res,
    _Float16* __restrict__ y, int Nn, int Hdim) {
    const int node = blockIdx.x * (blockDim.x >> 6) + (threadIdx.x >> 6);
    if (node >= Nn) return;
    const int lane = threadIdx.x & 63;
    const int sub = lane >> 5;         // which edge of the pair
    const int f = (lane & 31) * 8;     // feature base (32 lanes x 8 = 256)

    float acc[8] = {0.f, 0.f, 0.f, 0.f, 0.f, 0.f, 0.f, 0.f};

    const int s0 = row_ptr[node], s1 = row_ptr[node + 1];
    int e = s0 + sub;
    for (; e + 7 < s1; e += 8) {
        int ss[4];
        float w[4];
        half8 v[4];
#pragma unroll
        for (int u = 0; u < 4; ++u) ss[u] = col[e + 2 * u];
#pragma unroll
        for (int u = 0; u < 4; ++u) w[u] = dinv[ss[u]];
#pragma unroll
        for (int u = 0; u < 4; ++u)
            v[u] = *(const half8*)(t + (size_t)ss[u] * Hdim + f);
#pragma unroll
        for (int u = 0; u < 4; ++u)
#pragma unroll
            for (int i = 0; i < 8; ++i)
                acc[i] = fmaf((float)v[u][i], w[u], acc[i]);
    }
    for (; e < s1; e += 2) {
        const int s = col[e];
        const float w = dinv[s];
        const half8 v = *(const half8*)(t + (size_t)s * Hdim + f);
#pragma unroll
        for (int i = 0; i < 8; ++i) acc[i] = fmaf((float)v[i], w, acc[i]);
    }

#pragma unroll
    for (int i = 0; i < 8; ++i) acc[i] += __shfl_xor(acc[i], 32);

    if (sub == 0) {
        const float dn = dinv[node];
        const half8 tn = *(const half8*)(t + (size_t)node * Hdim + f);
        float o[8];
#pragma unroll
        for (int i = 0; i < 8; ++i)
            o[i] = (acc[i] + (float)tn[i] * dn) * dn + bias[f + i];
        if (MODE == 1) {
            const half8 rv = *(const half8*)(res + (size_t)node * Hdim + f);
#pragma unroll
            for (int i = 0; i < 8; ++i) o[i] += (float)rv[i];
        }
        half8 ov;
#pragma unroll
        for (int i = 0; i < 8; ++i) ov[i] = (_Float16)elu1(o[i]);
        *(half8*)(y + (size_t)node * Hdim + f) = ov;
    }
}

// Layer-3 aggregation: Cdim=64 fp16 t, one wave/node, 2 edges per iteration
// (lane>>5 selects edge), 4-way unrolled, cross-half shfl reduce. y=conv+b (fp32).
__global__ __launch_bounds__(256) void agg_pull64_kernel(
    const int* __restrict__ row_ptr, const int* __restrict__ col,
    const float* __restrict__ dinv, const _Float16* __restrict__ t,
    const float* __restrict__ bias, float* __restrict__ y, int Nn) {
    const int node = blockIdx.x * (blockDim.x >> 6) + (threadIdx.x >> 6);
    if (node >= Nn) return;
    const int lane = threadIdx.x & 63;
    const int sub = lane >> 5;
    const int f = (lane & 31) * 2;

    float acc0 = 0.f, acc1 = 0.f;
    const int s0 = row_ptr[node], s1 = row_ptr[node + 1];
    int e = s0 + sub;
    for (; e + 6 < s1; e += 8) {
        int ss[4];
        float w[4];
        half2v v[4];
#pragma unroll
        for (int u = 0; u < 4; ++u) ss[u] = col[e + 2 * u];
#pragma unroll
        for (int u = 0; u < 4; ++u) w[u] = dinv[ss[u]];
#pragma unroll
        for (int u = 0; u < 4; ++u)
            v[u] = *(const half2v*)(t + (size_t)ss[u] * 64 + f);
#pragma unroll
        for (int u = 0; u < 4; ++u) {
            acc0 = fmaf((float)v[u][0], w[u], acc0);
            acc1 = fmaf((float)v[u][1], w[u], acc1);
        }
    }
    for (; e < s1; e += 2) {
        const int s = col[e];
        const float w = dinv[s];
        const half2v v = *(const half2v*)(t + (size_t)s * 64 + f);
        acc0 = fmaf((float)v[0], w, acc0);
        acc1 = fmaf((float)v[1], w, acc1);
    }

    acc0 += __shfl_xor(acc0, 32);
    acc1 += __shfl_xor(acc1, 32);

    const float dn = dinv[node];
    const half2v tn = *(const half2v*)(t + (size_t)node * 64 + f);
    const float o0 = (acc0 + (float)tn[0] * dn) * dn + bias[f];
    const float o1 = (acc1 + (float)tn[1] * dn) * dn + bias[f + 1];

    if (lane < 32) {
        float2 ov = make_float2(o0, o1);
        *(float2*)(y + (size_t)node * 64 + f) = ov;
    }
}

extern "C" void kernel_launch(void* const* d_in, const int* in_sizes, int n_in,
                              void* d_out, int out_size, void* d_ws, size_t ws_size,
                              hipStream_t stream) {
    const float* x = (const float*)d_in[0];
    const void* ei_raw = d_in[1];
    const float* W1 = (const float*)d_in[2];
    const float* b1 = (const float*)d_in[3];
    const float* W2 = (const float*)d_in[4];
    const float* b2 = (const float*)d_in[5];
    const float* W3 = (const float*)d_in[6];
    const float* b3 = (const float*)d_in[7];
    float* out = (float*)d_out;

    const int H = in_sizes[3];       // 256
    const int F = in_sizes[2] / H;   // 512
    const int N = in_sizes[0] / F;   // 50000
    const int C = in_sizes[7];       // 64
    const int E = in_sizes[1] / 2;   // 800000
    const int Mt = cdiv_i(N, 64);    // 782 row tiles

    // workspace layout
    char* ws = (char*)d_ws;
    size_t off = 0;
    auto take = [&](size_t bytes) -> char* {
        char* p = ws + off;
        off += (bytes + 255) & ~(size_t)255;
        return p;
    };
    float* dinv = (float*)take((size_t)N * 4);
    int* flag = (int*)take(4);
    float* zbuf = (float*)take(4096);                    // 4KB zero page
    _Float16* th = (_Float16*)take((size_t)N * H * 2);   // GEMM output (fp16)
    _Float16* h1 = (_Float16*)take((size_t)N * H * 2);   // fp16 activations
    _Float16* h2 = (_Float16*)take((size_t)N * H * 2);
    int* e32 = (int*)take((size_t)2 * E * 4);
    int* srcI = e32;
    int* dstI = e32 + E;
    int* col = (int*)take((size_t)E * 4);
    int* cnt = (int*)take((size_t)N * 4);
    int* row_ptr = (int*)take((size_t)(N + 1) * 4);
    int* fill = (int*)take((size_t)N * 4);
    int* bsum = (int*)take(256 * 4);
    _Float16* pW1 = (_Float16*)take((size_t)F * H * 2 * 2);
    _Float16* pW2 = (_Float16*)take((size_t)H * H * 2 * 2);
    _Float16* pW3 = (_Float16*)take((size_t)H * C * 2 * 2);
    (void)ws_size; (void)n_in; (void)out_size;

    const int nScanBlk = cdiv_i(N, 1024);

    // ---- edges + degrees + CSR (+ zero page for GEMM OOB rows) ----
    detect_fmt_kernel<<<1, 64, 0, stream>>>((const unsigned*)ei_raw, N, flag);
    edges_to_i32_kernel<<<cdiv_i(2L * E, 256), 256, 0, stream>>>(ei_raw, e32, 2 * E, flag);
    zero_i32_kernel<<<4, 256, 0, stream>>>((int*)zbuf, 1024);
    zero_i32_kernel<<<cdiv_i(N, 256), 256, 0, stream>>>(cnt, N);
    hist_kernel<<<cdiv_i(E, 256), 256, 0, stream>>>(dstI, cnt, E);
    dinv_kernel<<<cdiv_i(N, 256), 256, 0, stream>>>(cnt, dinv, N);
    scan1_kernel<<<nScanBlk, 256, 0, stream>>>(cnt, row_ptr, bsum, N);
    scan2_kernel<<<1, 256, 0, stream>>>(bsum, nScanBlk);
    scan3_kernel<<<nScanBlk, 256, 0, stream>>>(row_ptr, bsum, N);
    set_int_kernel<<<1, 1, 0, stream>>>(row_ptr, N, E);
    zero_i32_kernel<<<cdiv_i(N, 256), 256, 0, stream>>>(fill, N);
    scatter_kernel<<<cdiv_i(E, 256), 256, 0, stream>>>(srcI, dstI, row_ptr, fill, col, E);

    // ---- pack weights (fragment-major fp16 hi/lo) ----
    const int tot1 = (H / 128) * (F / 32) * (128 / 16) * 64;
    const int tot2 = (H / 128) * (H / 32) * (128 / 16) * 64;
    const int tot3 = (C / 64) * (H / 32) * (64 / 16) * 64;
    pack_w_kernel<<<cdiv_i(tot1, 256), 256, 0, stream>>>(W1, pW1, F, H, 128, tot1);
    pack_w_kernel<<<cdiv_i(tot2, 256), 256, 0, stream>>>(W2, pW2, H, H, 128, tot2);
    pack_w_kernel<<<cdiv_i(tot3, 256), 256, 0, stream>>>(W3, pW3, H, C, 64, tot3);

    const int aggGridH = cdiv_i(N, 4);

    // ---- layer 1: h1 = elu(A_hat @ (x @ W1) + b1)
    gemm_mfma_kernel<128, 0><<<dim3(H / 128, Mt), 256, 0, stream>>>(
        x, pW1, th, N, F, H, zbuf);
    agg_pull_kernel<0><<<aggGridH, 256, 0, stream>>>(row_ptr, col, dinv, th, b1,
                                                     nullptr, h1, N, H);

    // ---- layer 2: h2 = elu(A_hat @ (h1 @ W2) + b2 + h1)
    gemm_mfma_kernel<128, 1><<<dim3(H / 128, Mt), 256, 0, stream>>>(
        h1, pW2, th, N, H, H, zbuf);
    agg_pull_kernel<1><<<aggGridH, 256, 0, stream>>>(row_ptr, col, dinv, th, b2,
                                                     h1, h2, N, H);

    // ---- layer 3: out = A_hat @ (h2 @ W3) + b3
    gemm_mfma_kernel<64, 1><<<dim3(C / 64, Mt), 256, 0, stream>>>(
        h2, pW3, th, N, H, C, zbuf);
    agg_pull64_kernel<<<aggGridH, 256, 0, stream>>>(row_ptr, col, dinv, th, b3, out, N);
}

// Round 11
// 327.221 us; speedup vs baseline: 2.2714x; 1.0555x over previous
//
#include <hip/hip_runtime.h>
#include <cstdint>
#include <cstddef>

// ---------------------------------------------------------------------------
// GCN: 3 layers.  out = A_hat @ (h @ W) + b, A_hat = D^-1/2 (A+I) D^-1/2
// R10: GEMM BM=128 / 512 threads / 8 waves (2x MFMA per barrier interval,
//      2x waves per CU); A 3-deep + B 2-deep counted-vmcnt pipeline kept.
//      CSR prep fused (hist/scatter read raw edges; edges_to_i32 deleted).
// ---------------------------------------------------------------------------

static inline int cdiv_i(long a, long b) { return (int)((a + b - 1) / b); }

using half2v = __attribute__((ext_vector_type(2))) _Float16;
using half8 = __attribute__((ext_vector_type(8))) _Float16;
using f32x4 = __attribute__((ext_vector_type(4))) float;

__device__ __forceinline__ void gload_lds16(const void* g, void* l) {
    __builtin_amdgcn_global_load_lds(
        (const __attribute__((address_space(1))) unsigned int*)g,
        (__attribute__((address_space(3))) unsigned int*)l, 16, 0, 0);
}

template <int N>
__device__ __forceinline__ void wait_vmcnt() {
    if constexpr (N == 0) asm volatile("s_waitcnt vmcnt(0)" ::: "memory");
    else if constexpr (N == 1) asm volatile("s_waitcnt vmcnt(1)" ::: "memory");
    else asm volatile("s_waitcnt vmcnt(2)" ::: "memory");
}

__global__ void detect_fmt_kernel(const unsigned int* __restrict__ raw, int n_nodes,
                                  int* __restrict__ flag) {
    if (blockIdx.x == 0 && threadIdx.x == 0) {
        int is64 = 1;
        for (int i = 0; i < 64; ++i) {
            unsigned lo = raw[2 * i], hi = raw[2 * i + 1];
            if (hi != 0u || lo >= (unsigned)n_nodes) { is64 = 0; break; }
        }
        *flag = is64;
    }
}

__global__ void zero_i32_kernel(int* __restrict__ p, int n) {
    for (long i = blockIdx.x * (long)blockDim.x + threadIdx.x; i < n;
         i += (long)gridDim.x * blockDim.x)
        p[i] = 0;
}

// histogram of dst straight from the raw edge buffer
__global__ void hist_kernel(const void* __restrict__ raw, int* __restrict__ cnt,
                            int E, const int* __restrict__ flag) {
    const int f = *flag;
    for (long i = blockIdx.x * (long)blockDim.x + threadIdx.x; i < E;
         i += (long)gridDim.x * blockDim.x) {
        const int d = f ? (int)(((const long long*)raw)[E + i])
                        : ((const int*)raw)[E + i];
        atomicAdd(&cnt[d], 1);
    }
}

__global__ void dinv_kernel(const int* __restrict__ cnt, float* __restrict__ dinv, int n) {
    for (long i = blockIdx.x * (long)blockDim.x + threadIdx.x; i < n;
         i += (long)gridDim.x * blockDim.x)
        dinv[i] = rsqrtf((float)cnt[i] + 1.0f);  // +1 self-loop
}

// ---- exclusive scan over n ints: 1024 elems / block ----
__global__ __launch_bounds__(256) void scan1_kernel(const int* __restrict__ in,
                                                    int* __restrict__ out,
                                                    int* __restrict__ bsum, int n) {
    __shared__ int tsum[256];
    const int tid = threadIdx.x;
    const long base = (long)blockIdx.x * 1024 + (long)tid * 4;
    int v[4];
#pragma unroll
    for (int i = 0; i < 4; ++i) v[i] = (base + i < n) ? in[base + i] : 0;
    const int s = v[0] + v[1] + v[2] + v[3];
    tsum[tid] = s;
    __syncthreads();
    for (int off = 1; off < 256; off <<= 1) {
        int add = (tid >= off) ? tsum[tid - off] : 0;
        __syncthreads();
        tsum[tid] += add;
        __syncthreads();
    }
    int run = tsum[tid] - s;
#pragma unroll
    for (int i = 0; i < 4; ++i) {
        if (base + i < n) out[base + i] = run;
        run += v[i];
    }
    if (tid == 255) bsum[blockIdx.x] = tsum[255];
}

__global__ void scan2_kernel(int* __restrict__ bsum, int nb) {
    __shared__ int lds[256];
    const int tid = threadIdx.x;
    int v = (tid < nb) ? bsum[tid] : 0;
    lds[tid] = v;
    __syncthreads();
    for (int off = 1; off < 256; off <<= 1) {
        int add = (tid >= off) ? lds[tid - off] : 0;
        __syncthreads();
        lds[tid] += add;
        __syncthreads();
    }
    if (tid < nb) bsum[tid] = lds[tid] - v;
}

__global__ __launch_bounds__(256) void scan3_kernel(int* __restrict__ out,
                                                    const int* __restrict__ bsum, int n) {
    const long base = (long)blockIdx.x * 1024 + (long)threadIdx.x * 4;
    const int add = bsum[blockIdx.x];
#pragma unroll
    for (int i = 0; i < 4; ++i)
        if (base + i < n) out[base + i] += add;
}

__global__ void set_int_kernel(int* __restrict__ p, int idx, int val) {
    if (blockIdx.x == 0 && threadIdx.x == 0) p[idx] = val;
}

// scatter src into CSR col straight from the raw edge buffer
__global__ void scatter_kernel(const void* __restrict__ raw,
                               const int* __restrict__ row_ptr, int* __restrict__ fill,
                               int* __restrict__ col, int E,
                               const int* __restrict__ flag) {
    const int f = *flag;
    for (long i = blockIdx.x * (long)blockDim.x + threadIdx.x; i < E;
         i += (long)gridDim.x * blockDim.x) {
        int s, d;
        if (f) {
            s = (int)(((const long long*)raw)[i]);
            d = (int)(((const long long*)raw)[E + i]);
        } else {
            s = ((const int*)raw)[i];
            d = ((const int*)raw)[E + i];
        }
        int p = row_ptr[d] + atomicAdd(&fill[d], 1);
        col[p] = s;
    }
}

__device__ __forceinline__ void split8f(const float v[8], half8& hi, half8& lo) {
#pragma unroll
    for (int j = 0; j < 8; ++j) {
        _Float16 h = (_Float16)v[j];
        hi[j] = h;
        lo[j] = (_Float16)((v[j] - (float)h) * 4096.0f);
    }
}

// ---------------------------------------------------------------------------
// Pack W (fp32 [K][Nn]) into fragment-major fp16 hi/lo.
// Per (nt, ks) chunk: [split(2)][colgrp(BN/16)][lane(64)][8 halfs]
// lane l -> col = nt*BN + cg*16 + (l&15), k = ks*32 + (l>>4)*8 + j
// ---------------------------------------------------------------------------
__global__ void pack_w_kernel(const float* __restrict__ W, _Float16* __restrict__ P,
                              int K, int Nn, int BN, int total) {
    int id = blockIdx.x * 256 + threadIdx.x;
    if (id >= total) return;
    const int CG = BN / 16, KS = K >> 5;
    const int l = id & 63;
    int r = id >> 6;
    const int cg = r % CG; r /= CG;
    const int ks = r % KS;
    const int nt = r / KS;
    const int c = nt * BN + cg * 16 + (l & 15);
    const int kb = ks * 32 + (l >> 4) * 8;
    const size_t CHUNK = (size_t)2 * CG * 64 * 8;
    _Float16* base = P + (size_t)(nt * KS + ks) * CHUNK + (size_t)(cg * 64 + l) * 8;
    float v[8];
#pragma unroll
    for (int j = 0; j < 8; ++j) v[j] = W[(size_t)(kb + j) * Nn + c];
    half8 hi, lo;
    split8f(v, hi, lo);
    *(half8*)base = hi;
    *(half8*)(base + CHUNK / 2) = lo;
}

// ---------------------------------------------------------------------------
// Ch[M,Nn](fp16) = A[M,K] @ Bpacked, fp16 MFMA (A hi-only, B hi+lo).
// BM=128, BN in {128,64}, BK=32, 512 threads = 8 waves.
// Wave grid (8/WC)x(WC); wave tile (MI*16)x64; 16 MFMA/wave-step at BN=128.
// A staged coalesced row-major with XOR-swizzled 16B chunks (source-side),
// fragment ds_reads apply the same XOR. A 3-deep (HBM), B 2-deep (L2),
// counted vmcnt -- never drained to 0 mid-loop.
// ---------------------------------------------------------------------------
template <int BN, int AF16>
__global__ __launch_bounds__(512) void gemm_mfma_kernel(
    const void* __restrict__ Araw, const _Float16* __restrict__ Bp,
    _Float16* __restrict__ Ch, int M, int K, int Nn,
    const float* __restrict__ zbuf) {
    constexpr int WC = BN / 64;              // wave cols: 2 or 1
    constexpr int WR = 8 / WC;               // wave rows: 4 or 8
    constexpr int MI = 128 / (WR * 16);      // 2 or 1
    constexpr int NI = 4;
    constexpr int BCH = 2 * (BN / 16) * 64 * 8;  // halfs per B stage
    constexpr int BBYTES = BCH * 2;          // 16 KB or 8 KB
    constexpr int BU = BBYTES / 8192;        // B loads per thread (2 or 1)
    constexpr int AL = AF16 ? 1 : 2;         // A loads per thread
    constexpr int ABYTES = AF16 ? 8192 : 16384;
    constexpr int PIPEB = 3 * ABYTES + 2 * BBYTES;
    constexpr int EPIB = 128 * BN * 2;
    constexpr int SMB = (PIPEB > EPIB) ? PIPEB : EPIB;

    __shared__ __align__(16) char smraw[SMB];
    char* bufA0 = smraw;
    char* bufB0 = smraw + 3 * ABYTES;

    const int tid = threadIdx.x;
    const int lane = tid & 63;
    const int wid = __builtin_amdgcn_readfirstlane(tid >> 6);   // 0..7
    const int wr = wid / WC, wc = wid % WC;
    const int bm = blockIdx.y * 128, bn = blockIdx.x * BN;
    const int KS = K >> 5;
    const _Float16* bchunk = Bp + (size_t)blockIdx.x * KS * BCH;

    // ---- A stage source addressing (coalesced + chunk-swizzled) ----
    const float* a32s0 = nullptr;
    const float* a32s1 = nullptr;
    const _Float16* a16s = nullptr;
    if constexpr (AF16) {
        const _Float16* A16 = (const _Float16*)Araw;
        const int rl = wid * 16 + (lane >> 2);           // local row 0..127
        const int kc = (lane & 3) ^ ((rl >> 1) & 3);     // swizzled 16B chunk
        const int gm = bm + rl;
        a16s = (gm < M) ? (A16 + (size_t)gm * K + kc * 8)
                        : (const _Float16*)zbuf;
    } else {
        const float* A32 = (const float*)Araw;
        const int rl0 = wid * 16 + (lane >> 3);          // rows 0..127 (j=0)
        const int rl1 = rl0 + 8;                         // j=1
        const int kc0 = (lane & 7) ^ (rl0 & 7);
        const int kc1 = (lane & 7) ^ (rl1 & 7);
        const int gm0 = bm + rl0, gm1 = bm + rl1;
        a32s0 = (gm0 < M) ? (A32 + (size_t)gm0 * K + kc0 * 4) : zbuf;
        a32s1 = (gm1 < M) ? (A32 + (size_t)gm1 * K + kc1 * 4) : zbuf;
    }

    f32x4 acc1[MI][NI] = {};
    f32x4 acc2[MI][NI] = {};

    auto stageA = [&](int b, int ks) {
        char* sA = bufA0 + b * ABYTES;
        if constexpr (AF16) {
            gload_lds16(a16s + ks * 32, sA + wid * 1024);
        } else {
            gload_lds16(a32s0 + ks * 32, sA + (wid * 2 + 0) * 1024);
            gload_lds16(a32s1 + ks * 32, sA + (wid * 2 + 1) * 1024);
        }
    };
    auto stageB = [&](int b, int ks) {
        char* sB = bufB0 + b * BBYTES;
        const _Float16* bc = bchunk + (size_t)ks * BCH;
#pragma unroll
        for (int rr = 0; rr < BU; ++rr)
            gload_lds16(bc + (size_t)(((wid * BU + rr) * 64 + lane) << 3),
                        sB + ((wid * BU + rr) << 10));
    };

    // ---- fragment read addresses (per-thread invariant) ----
    int aoff0[MI], aoff1[MI];  // byte offsets within an A buffer
#pragma unroll
    for (int mi = 0; mi < MI; ++mi) {
        const int r = (wr * MI + mi) * 16 + (lane & 15);
        if constexpr (AF16) {
            const int c = r * 4 + ((lane >> 4) ^ ((r >> 1) & 3));
            aoff0[mi] = c * 16;
            aoff1[mi] = 0;
        } else {
            const int g0 = (lane >> 4) * 2;
            const int sw = r & 7;
            aoff0[mi] = (r * 8 + (g0 ^ sw)) * 16;
            aoff1[mi] = (r * 8 + ((g0 + 1) ^ sw)) * 16;
        }
    }

    // prologue: A(0), B(0), A(1) -- FIFO order matters for counted waits
    stageA(0, 0);
    stageB(0, 0);
    if (1 < KS) stageA(1, 1);

    for (int ks = 0; ks < KS; ++ks) {
        if (ks + 1 < KS) wait_vmcnt<AL>();  // A(ks), B(ks) landed; A(ks+1) flying
        else wait_vmcnt<0>();
        __builtin_amdgcn_s_barrier();
        if (ks + 1 < KS) stageB((ks + 1) & 1, ks + 1);
        if (ks + 2 < KS) stageA((ks + 2) % 3, ks + 2);

        const char* cA = bufA0 + (ks % 3) * ABYTES;
        const _Float16* smB = (const _Float16*)(bufB0 + (ks & 1) * BBYTES);

        half8 afh[MI];
        if constexpr (AF16) {
#pragma unroll
            for (int mi = 0; mi < MI; ++mi)
                afh[mi] = *(const half8*)(cA + aoff0[mi]);
        } else {
#pragma unroll
            for (int mi = 0; mi < MI; ++mi) {
                f32x4 vlo = *(const f32x4*)(cA + aoff0[mi]);
                f32x4 vhi = *(const f32x4*)(cA + aoff1[mi]);
                half8 h;
                h[0] = (_Float16)vlo[0]; h[1] = (_Float16)vlo[1];
                h[2] = (_Float16)vlo[2]; h[3] = (_Float16)vlo[3];
                h[4] = (_Float16)vhi[0]; h[5] = (_Float16)vhi[1];
                h[6] = (_Float16)vhi[2]; h[7] = (_Float16)vhi[3];
                afh[mi] = h;
            }
        }
#pragma unroll
        for (int ni = 0; ni < NI; ++ni) {
            const half8 bh = *(const half8*)(smB + (((wc * 4 + ni) * 64 + lane) << 3));
            const half8 bl = *(const half8*)(smB + BCH / 2 + (((wc * 4 + ni) * 64 + lane) << 3));
#pragma unroll
            for (int mi = 0; mi < MI; ++mi) {
                acc1[mi][ni] = __builtin_amdgcn_mfma_f32_16x16x32_f16(
                    afh[mi], bh, acc1[mi][ni], 0, 0, 0);
                acc2[mi][ni] = __builtin_amdgcn_mfma_f32_16x16x32_f16(
                    afh[mi], bl, acc2[mi][ni], 0, 0, 0);
            }
        }
    }

    // ---- epilogue: stage fp16 tile in LDS, store full coalesced lines ----
    __syncthreads();
    _Float16* smC = (_Float16*)smraw;
    const float inv = 1.0f / 4096.0f;
#pragma unroll
    for (int mi = 0; mi < MI; ++mi) {
#pragma unroll
        for (int ni = 0; ni < NI; ++ni) {
            const int row0 = (wr * MI + mi) * 16 + ((lane >> 4) << 2);
            const int colx = wc * 64 + ni * 16 + (lane & 15);
#pragma unroll
            for (int i = 0; i < 4; ++i)
                smC[(row0 + i) * BN + colx] =
                    (_Float16)(acc1[mi][ni][i] + acc2[mi][ni][i] * inv);
        }
    }
    __syncthreads();
    constexpr int UPR = BN / 8;               // 16B units per row
    constexpr int EPU = (128 * BN / 8) / 512; // units per thread (4 or 2)
#pragma unroll
    for (int r = 0; r < EPU; ++r) {
        const int u = r * 512 + tid;
        const int row = u / UPR, cu = u % UPR;
        const int grow = bm + row;
        if (grow < M)
            *(uint4*)(Ch + (size_t)grow * Nn + bn + cu * 8) =
                *(const uint4*)(smC + row * BN + cu * 8);
    }
}

__device__ __forceinline__ float elu1(float v) { return v > 0.f ? v : expm1f(v); }

// Pull aggregation over fp16 t (Hdim=256): one wave per node, 32 lanes x
// half8 (16B) per row, 2 edges per wave-iteration, 4-pair unroll.
// Output y fp16.  MODE 0: y=elu(conv)  MODE 1: y=elu(conv+res), res fp16.
template <int MODE>
__global__ __launch_bounds__(256) void agg_pull_kernel(
    const int* __restrict__ row_ptr, const int* __restrict__ col,
    const float* __restrict__ dinv, const _Float16* __restrict__ t,
    const float* __restrict__ bias, const _Float16* __restrict__ res,
    _Float16* __restrict__ y, int Nn, int Hdim) {
    const int node = blockIdx.x * (blockDim.x >> 6) + (threadIdx.x >> 6);
    if (node >= Nn) return;
    const int lane = threadIdx.x & 63;
    const int sub = lane >> 5;         // which edge of the pair
    const int f = (lane & 31) * 8;     // feature base (32 lanes x 8 = 256)

    float acc[8] = {0.f, 0.f, 0.f, 0.f, 0.f, 0.f, 0.f, 0.f};

    const int s0 = row_ptr[node], s1 = row_ptr[node + 1];
    int e = s0 + sub;
    for (; e + 7 < s1; e += 8) {
        int ss[4];
        float w[4];
        half8 v[4];
#pragma unroll
        for (int u = 0; u < 4; ++u) ss[u] = col[e + 2 * u];
#pragma unroll
        for (int u = 0; u < 4; ++u) w[u] = dinv[ss[u]];
#pragma unroll
        for (int u = 0; u < 4; ++u)
            v[u] = *(const half8*)(t + (size_t)ss[u] * Hdim + f);
#pragma unroll
        for (int u = 0; u < 4; ++u)
#pragma unroll
            for (int i = 0; i < 8; ++i)
                acc[i] = fmaf((float)v[u][i], w[u], acc[i]);
    }
    for (; e < s1; e += 2) {
        const int s = col[e];
        const float w = dinv[s];
        const half8 v = *(const half8*)(t + (size_t)s * Hdim + f);
#pragma unroll
        for (int i = 0; i < 8; ++i) acc[i] = fmaf((float)v[i], w, acc[i]);
    }

#pragma unroll
    for (int i = 0; i < 8; ++i) acc[i] += __shfl_xor(acc[i], 32);

    if (sub == 0) {
        const float dn = dinv[node];
        const half8 tn = *(const half8*)(t + (size_t)node * Hdim + f);
        float o[8];
#pragma unroll
        for (int i = 0; i < 8; ++i)
            o[i] = (acc[i] + (float)tn[i] * dn) * dn + bias[f + i];
        if (MODE == 1) {
            const half8 rv = *(const half8*)(res + (size_t)node * Hdim + f);
#pragma unroll
            for (int i = 0; i < 8; ++i) o[i] += (float)rv[i];
        }
        half8 ov;
#pragma unroll
        for (int i = 0; i < 8; ++i) ov[i] = (_Float16)elu1(o[i]);
        *(half8*)(y + (size_t)node * Hdim + f) = ov;
    }
}

// Layer-3 aggregation: Cdim=64 fp16 t, one wave/node, 2 edges per iteration
// (lane>>5 selects edge), 4-way unrolled, cross-half shfl reduce. y=conv+b (fp32).
__global__ __launch_bounds__(256) void agg_pull64_kernel(
    const int* __restrict__ row_ptr, const int* __restrict__ col,
    const float* __restrict__ dinv, const _Float16* __restrict__ t,
    const float* __restrict__ bias, float* __restrict__ y, int Nn) {
    const int node = blockIdx.x * (blockDim.x >> 6) + (threadIdx.x >> 6);
    if (node >= Nn) return;
    const int lane = threadIdx.x & 63;
    const int sub = lane >> 5;
    const int f = (lane & 31) * 2;

    float acc0 = 0.f, acc1 = 0.f;
    const int s0 = row_ptr[node], s1 = row_ptr[node + 1];
    int e = s0 + sub;
    for (; e + 6 < s1; e += 8) {
        int ss[4];
        float w[4];
        half2v v[4];
#pragma unroll
        for (int u = 0; u < 4; ++u) ss[u] = col[e + 2 * u];
#pragma unroll
        for (int u = 0; u < 4; ++u) w[u] = dinv[ss[u]];
#pragma unroll
        for (int u = 0; u < 4; ++u)
            v[u] = *(const half2v*)(t + (size_t)ss[u] * 64 + f);
#pragma unroll
        for (int u = 0; u < 4; ++u) {
            acc0 = fmaf((float)v[u][0], w[u], acc0);
            acc1 = fmaf((float)v[u][1], w[u], acc1);
        }
    }
    for (; e < s1; e += 2) {
        const int s = col[e];
        const float w = dinv[s];
        const half2v v = *(const half2v*)(t + (size_t)s * 64 + f);
        acc0 = fmaf((float)v[0], w, acc0);
        acc1 = fmaf((float)v[1], w, acc1);
    }

    acc0 += __shfl_xor(acc0, 32);
    acc1 += __shfl_xor(acc1, 32);

    const float dn = dinv[node];
    const half2v tn = *(const half2v*)(t + (size_t)node * 64 + f);
    const float o0 = (acc0 + (float)tn[0] * dn) * dn + bias[f];
    const float o1 = (acc1 + (float)tn[1] * dn) * dn + bias[f + 1];

    if (lane < 32) {
        float2 ov = make_float2(o0, o1);
        *(float2*)(y + (size_t)node * 64 + f) = ov;
    }
}

extern "C" void kernel_launch(void* const* d_in, const int* in_sizes, int n_in,
                              void* d_out, int out_size, void* d_ws, size_t ws_size,
                              hipStream_t stream) {
    const float* x = (const float*)d_in[0];
    const void* ei_raw = d_in[1];
    const float* W1 = (const float*)d_in[2];
    const float* b1 = (const float*)d_in[3];
    const float* W2 = (const float*)d_in[4];
    const float* b2 = (const float*)d_in[5];
    const float* W3 = (const float*)d_in[6];
    const float* b3 = (const float*)d_in[7];
    float* out = (float*)d_out;

    const int H = in_sizes[3];       // 256
    const int F = in_sizes[2] / H;   // 512
    const int N = in_sizes[0] / F;   // 50000
    const int C = in_sizes[7];       // 64
    const int E = in_sizes[1] / 2;   // 800000
    const int Mt = cdiv_i(N, 128);   // 391 row tiles

    // workspace layout
    char* ws = (char*)d_ws;
    size_t off = 0;
    auto take = [&](size_t bytes) -> char* {
        char* p = ws + off;
        off += (bytes + 255) & ~(size_t)255;
        return p;
    };
    float* dinv = (float*)take((size_t)N * 4);
    int* flag = (int*)take(4);
    float* zbuf = (float*)take(4096);                    // 4KB zero page
    _Float16* th = (_Float16*)take((size_t)N * H * 2);   // GEMM output (fp16)
    _Float16* h1 = (_Float16*)take((size_t)N * H * 2);   // fp16 activations
    _Float16* h2 = (_Float16*)take((size_t)N * H * 2);
    int* col = (int*)take((size_t)E * 4);
    int* cnt = (int*)take((size_t)N * 4);
    int* row_ptr = (int*)take((size_t)(N + 1) * 4);
    int* fill = (int*)take((size_t)N * 4);
    int* bsum = (int*)take(256 * 4);
    _Float16* pW1 = (_Float16*)take((size_t)F * H * 2 * 2);
    _Float16* pW2 = (_Float16*)take((size_t)H * H * 2 * 2);
    _Float16* pW3 = (_Float16*)take((size_t)H * C * 2 * 2);
    (void)ws_size; (void)n_in; (void)out_size;

    const int nScanBlk = cdiv_i(N, 1024);

    // ---- edges + degrees + CSR (+ zero page for GEMM OOB rows) ----
    detect_fmt_kernel<<<1, 64, 0, stream>>>((const unsigned*)ei_raw, N, flag);
    zero_i32_kernel<<<4, 256, 0, stream>>>((int*)zbuf, 1024);
    zero_i32_kernel<<<cdiv_i(N, 256), 256, 0, stream>>>(cnt, N);
    hist_kernel<<<cdiv_i(E, 256), 256, 0, stream>>>(ei_raw, cnt, E, flag);
    dinv_kernel<<<cdiv_i(N, 256), 256, 0, stream>>>(cnt, dinv, N);
    scan1_kernel<<<nScanBlk, 256, 0, stream>>>(cnt, row_ptr, bsum, N);
    scan2_kernel<<<1, 256, 0, stream>>>(bsum, nScanBlk);
    scan3_kernel<<<nScanBlk, 256, 0, stream>>>(row_ptr, bsum, N);
    set_int_kernel<<<1, 1, 0, stream>>>(row_ptr, N, E);
    zero_i32_kernel<<<cdiv_i(N, 256), 256, 0, stream>>>(fill, N);
    scatter_kernel<<<cdiv_i(E, 256), 256, 0, stream>>>(ei_raw, row_ptr, fill, col, E, flag);

    // ---- pack weights (fragment-major fp16 hi/lo) ----
    const int tot1 = (H / 128) * (F / 32) * (128 / 16) * 64;
    const int tot2 = (H / 128) * (H / 32) * (128 / 16) * 64;
    const int tot3 = (C / 64) * (H / 32) * (64 / 16) * 64;
    pack_w_kernel<<<cdiv_i(tot1, 256), 256, 0, stream>>>(W1, pW1, F, H, 128, tot1);
    pack_w_kernel<<<cdiv_i(tot2, 256), 256, 0, stream>>>(W2, pW2, H, H, 128, tot2);
    pack_w_kernel<<<cdiv_i(tot3, 256), 256, 0, stream>>>(W3, pW3, H, C, 64, tot3);

    const int aggGridH = cdiv_i(N, 4);

    // ---- layer 1: h1 = elu(A_hat @ (x @ W1) + b1)
    gemm_mfma_kernel<128, 0><<<dim3(H / 128, Mt), 512, 0, stream>>>(
        x, pW1, th, N, F, H, zbuf);
    agg_pull_kernel<0><<<aggGridH, 256, 0, stream>>>(row_ptr, col, dinv, th, b1,
                                                     nullptr, h1, N, H);

    // ---- layer 2: h2 = elu(A_hat @ (h1 @ W2) + b2 + h1)
    gemm_mfma_kernel<128, 1><<<dim3(H / 128, Mt), 512, 0, stream>>>(
        h1, pW2, th, N, H, H, zbuf);
    agg_pull_kernel<1><<<aggGridH, 256, 0, stream>>>(row_ptr, col, dinv, th, b2,
                                                     h1, h2, N, H);

    // ---- layer 3: out = A_hat @ (h2 @ W3) + b3
    gemm_mfma_kernel<64, 1><<<dim3(C / 64, Mt), 512, 0, stream>>>(
        h2, pW3, th, N, H, C, zbuf);
    agg_pull64_kernel<<<aggGridH, 256, 0, stream>>>(row_ptr, col, dinv, th, b3, out, N);
}